// Round 13
// baseline (2723.922 us; speedup 1.0000x reference)
//
#include <hip/hip_runtime.h>
#include <stdint.h>

#define TT 128
#define BB 128
#define OBSD 512
#define HID 1024
#define DPAR 16

typedef _Float16 f16;
typedef _Float16 f16x8 __attribute__((ext_vector_type(8)));
typedef float f32x4 __attribute__((ext_vector_type(4)));

__device__ __forceinline__ f32x4 mfma16(f16x8 a, f16x8 b, f32x4 c){
  return __builtin_amdgcn_mfma_f32_16x16x32_f16(a, b, c, 0, 0, 0);
}

// ---- prep: world_state f32 -> f16 ----
__global__ void k_ws_to_f16(const float* __restrict__ src, f16* __restrict__ dst, int n4){
  int i = blockIdx.x * blockDim.x + threadIdx.x;
  if (i < n4){
    float4 v = *reinterpret_cast<const float4*>(src + (size_t)i * 4);
    dst[(size_t)i*4 + 0] = (f16)v.x; dst[(size_t)i*4 + 1] = (f16)v.y;
    dst[(size_t)i*4 + 2] = (f16)v.z; dst[(size_t)i*4 + 3] = (f16)v.w;
  }
}

// ---- prep: transpose f32 [KD][C] (row stride srcStride) -> f16 dst[C][KD] ----
__global__ void k_prep_bt(const float* __restrict__ s0, int srcStride,
                          f16* __restrict__ dst, int KD){
  __shared__ f16 sm[64][65];
  int k0 = blockIdx.x * 64, c0 = blockIdx.y * 64;
  for (int it = 0; it < 16; ++it){
    int idx = it * 256 + threadIdx.x;
    int kr = idx >> 6, cc = idx & 63;
    sm[kr][cc] = (f16)s0[(size_t)(k0 + kr) * srcStride + (c0 + cc)];
  }
  __syncthreads();
  for (int it = 0; it < 16; ++it){
    int idx = it * 256 + threadIdx.x;
    int cr = idx >> 6, kc = idx & 63;
    dst[(size_t)(c0 + cr) * KD + (k0 + kc)] = sm[kc][cr];
  }
}

// ---- prep: bt2[c][k] = k<1024 ? Wi[k][c] : Wh[k-1024][c]; c<3072, k<2048 ----
__global__ void k_prep_bt2(const float* __restrict__ wi, const float* __restrict__ wh,
                           f16* __restrict__ dst){
  __shared__ f16 sm[64][65];
  int k0 = blockIdx.x * 64, c0 = blockIdx.y * 64;
  const float* src = (k0 < 1024) ? wi : wh;
  int kb = (k0 < 1024) ? k0 : k0 - 1024;
  for (int it = 0; it < 16; ++it){
    int idx = it * 256 + threadIdx.x;
    int kr = idx >> 6, cc = idx & 63;
    sm[kr][cc] = (f16)src[(size_t)(kb + kr) * 3072 + (c0 + cc)];
  }
  __syncthreads();
  for (int it = 0; it < 16; ++it){
    int idx = it * 256 + threadIdx.x;
    int cr = idx >> 6, kc = idx & 63;
    dst[(size_t)(c0 + cr) * 2048 + (k0 + kc)] = sm[kc][cr];
  }
}

// ---- segmentation: bucket (t,b) rows by chain depth; record long chains ----
__global__ void k_seg(const int* __restrict__ dones, int* __restrict__ off,
                      int* __restrict__ rowlist, int* __restrict__ ntail,
                      int* __restrict__ chains){
  __shared__ int cnt[DPAR];
  __shared__ int cur[DPAR];
  int tid = threadIdx.x;               // 128 threads, one per b
  if (tid < DPAR) cnt[tid] = 0;
  if (tid == 0) *ntail = 0;
  __syncthreads();
  int b = tid;
  int start = 0;
  for (int t = 1; t <= TT; ++t){
    bool boundary = (t == TT) || (dones[t * BB + b] != 0);
    if (boundary){
      int len = t - start;
      int nb = len < DPAR ? len : DPAR;
      for (int d = 0; d < nb; ++d) atomicAdd(&cnt[d], 1);
      if (len > DPAR){
        int c = atomicAdd(ntail, 1);
        chains[c*3+0] = b; chains[c*3+1] = start; chains[c*3+2] = len;
      }
      start = t;
    }
  }
  __syncthreads();
  if (tid == 0){
    int s = 0;
    for (int d = 0; d < DPAR; ++d){ off[d] = s; cur[d] = s; s += cnt[d]; }
    off[DPAR] = s;
  }
  __syncthreads();
  start = 0;
  for (int t = 1; t <= TT; ++t){
    bool boundary = (t == TT) || (dones[t * BB + b] != 0);
    if (boundary){
      int len = t - start;
      int nb = len < DPAR ? len : DPAR;
      for (int d = 0; d < nb; ++d){
        int pos = atomicAdd(&cur[d], 1);
        rowlist[pos] = ((start + d) << 7) | b;
      }
      start = t;
    }
  }
}

// ---- emb = relu(ws @ W_emb + b_emb): [16384x512]@[512->1024], f16 out ----
__global__ __launch_bounds__(256)
void k_emb(const f16* __restrict__ A, const f16* __restrict__ Bt,
           const float* __restrict__ bias, f16* __restrict__ outb){
  int w = threadIdx.x >> 6, lane = threadIdx.x & 63;
  int wm = w >> 1, wn = w & 1;
  int bid = blockIdx.x;                       // 1024 = 128 Mb x 8 Nb
  int vid = (bid & 7) * 128 + (bid >> 3);
  int Mb = (vid >> 3) * 128, Nb = (vid & 7) * 128;
  int la = lane & 15, lk = (lane >> 4) * 8;
  f32x4 acc[4][4] = {};
  const f16* Ap[4]; const f16* Bp[4];
  for (int i = 0; i < 4; ++i){
    Ap[i] = A + (size_t)(Mb + wm*64 + i*16 + la) * OBSD;
    Bp[i] = Bt + (size_t)(Nb + wn*64 + i*16 + la) * OBSD;
  }
  for (int k = 0; k < OBSD; k += 32){
    f16x8 af[4], bfr[4];
    for (int i = 0; i < 4; ++i){
      af[i]  = *reinterpret_cast<const f16x8*>(Ap[i] + k + lk);
      bfr[i] = *reinterpret_cast<const f16x8*>(Bp[i] + k + lk);
    }
    for (int mi = 0; mi < 4; ++mi)
      for (int ni = 0; ni < 4; ++ni)
        acc[mi][ni] = mfma16(af[mi], bfr[ni], acc[mi][ni]);
  }
  for (int mi = 0; mi < 4; ++mi) for (int ni = 0; ni < 4; ++ni){
    int col = Nb + wn*64 + ni*16 + la;
    float bb = bias[col];
    for (int i = 0; i < 4; ++i){
      int row = Mb + wm*64 + mi*16 + (lane >> 4)*4 + i;
      float v = acc[mi][ni][i] + bb;
      outb[(size_t)row * HID + col] = (f16)(v > 0.f ? v : 0.f);
    }
  }
}

// ---- depth-j fused GRU step: [emb | h_prev] @ [Wi; Wh], K=2048 ----
// BM=128 x BN=192 (64 hcols x 3 gates), 512 thr = 2m x 4n waves.
// BK=128, reg-staged double-buffer pipeline: ds_write(cur) -> issue loads(next)
// -> barrier -> MFMA(cur). LDS 32KB single buffer, XOR swizzle (write==read).
// B direct from L2 (nb%8 XCD-pinned). grid 1024 = 64 M-strides x 16 nb.
__global__ __launch_bounds__(512)
void k_depth(int j, const int* __restrict__ off, const int* __restrict__ rowlist,
             const f16* __restrict__ emb, const f16* __restrict__ bt2,
             const float* __restrict__ bi_p, const float* __restrict__ bhn_p,
             const int* __restrict__ dones, const float* __restrict__ hidden0,
             f16* __restrict__ y, float* __restrict__ hout){
  __shared__ __attribute__((aligned(16))) char smem[32768];   // 128 x 128 f16, swizzled
  const int base = off[j];
  const int count = off[j+1] - base;
  if (count <= 0) return;
  const int tid = threadIdx.x;
  const int lane = tid & 63;
  const int w = tid >> 6;                    // 8 waves
  const int wm = w >> 2, wn = w & 3;         // 2m x 4n
  const int nb = blockIdx.x & 15;
  const int st = blockIdx.x >> 4;            // 64 M-strides
  const int la = lane & 15, lk = (lane >> 4) * 8;
  const int hcolw = nb*64 + wn*16;           // wave's hcol base
  const f16* Bg0 = bt2 + (size_t)(          hcolw + la) * 2048 + lk;
  const f16* Bg1 = bt2 + (size_t)(1024 +    hcolw + la) * 2048 + lk;
  const f16* Bg2 = bt2 + (size_t)(2048 +    hcolw + la) * 2048 + lk;
  const int ntiles = (count + 127) >> 7;

  for (int tile = st; tile < ntiles; tile += 64){
    // per-q staging geometry (row fixed per q across all 16 chunks)
    const f16* eptr[4]; const char* hptr[4]; int hmode[4]; int sq[4]; int dby[4];
    #pragma unroll
    for (int q = 0; q < 4; ++q){
      int idx = tid + q*512;
      int r = idx >> 4; sq[q] = idx & 15;
      dby[q] = (r*256 + sq[q]*16) ^ ((r & 7) << 4);
      int ridx = tile*128 + r;
      int tb = (ridx < count) ? rowlist[base + ridx] : -1;
      eptr[q] = nullptr; hmode[q] = 0; hptr[q] = nullptr;
      if (tb >= 0){
        int t = tb >> 7, b = tb & 127;
        eptr[q] = emb + ((size_t)t*BB + b)*HID;
        if (j > 0){ hmode[q] = 1; hptr[q] = (const char*)(y + ((size_t)(t-1)*BB + b)*HID); }
        else if (t == 0 && dones[b] == 0){ hmode[q] = 2; hptr[q] = (const char*)(hidden0 + (size_t)b*HID); }
      }
    }
    auto loadch = [&](int ch, float4* dst){
      #pragma unroll
      for (int q = 0; q < 4; ++q){
        float4 v = {0.f, 0.f, 0.f, 0.f};
        if (ch < 8){
          if (eptr[q]) v = *reinterpret_cast<const float4*>(eptr[q] + ch*128 + sq[q]*8);
        } else {
          if (hmode[q] == 1){
            v = *reinterpret_cast<const float4*>((const f16*)hptr[q] + (ch-8)*128 + sq[q]*8);
          } else if (hmode[q] == 2){
            const float* s = (const float*)hptr[q] + (ch-8)*128 + sq[q]*8;
            float4 a0 = *reinterpret_cast<const float4*>(s);
            float4 a1 = *reinterpret_cast<const float4*>(s + 4);
            f16 h8[8] = {(f16)a0.x,(f16)a0.y,(f16)a0.z,(f16)a0.w,
                         (f16)a1.x,(f16)a1.y,(f16)a1.z,(f16)a1.w};
            v = *reinterpret_cast<float4*>(h8);
          }
        }
        dst[q] = v;
      }
    };
    f32x4 ar[4] = {}, az[4] = {}, axn[4] = {}, ahn[4] = {};
    float4 hv[4];
    loadch(0, hv);
    #pragma unroll 1
    for (int ch = 0; ch < 16; ++ch){
      __syncthreads();                       // prior chunk's (or tile's) smem reads done
      #pragma unroll
      for (int q = 0; q < 4; ++q)
        *reinterpret_cast<float4*>(smem + dby[q]) = hv[q];
      float4 hv2[4];
      if (ch < 15) loadch(ch+1, hv2);        // in flight under MFMAs below
      __syncthreads();
      const int kbase = ch*128;
      #pragma unroll
      for (int kk = 0; kk < 128; kk += 32){
        f16x8 av[4];
        #pragma unroll
        for (int m = 0; m < 4; ++m){
          int r = wm*64 + m*16 + la;
          av[m] = *reinterpret_cast<const f16x8*>(
              smem + ((r*256 + (kk + lk)*2) ^ ((r & 7) << 4)));
        }
        f16x8 b0 = *reinterpret_cast<const f16x8*>(Bg0 + kbase + kk);
        f16x8 b1 = *reinterpret_cast<const f16x8*>(Bg1 + kbase + kk);
        f16x8 b2 = *reinterpret_cast<const f16x8*>(Bg2 + kbase + kk);
        #pragma unroll
        for (int m = 0; m < 4; ++m){
          ar[m] = mfma16(av[m], b0, ar[m]);
          az[m] = mfma16(av[m], b1, az[m]);
          if (ch < 8) axn[m] = mfma16(av[m], b2, axn[m]);
          else        ahn[m] = mfma16(av[m], b2, ahn[m]);
        }
      }
      #pragma unroll
      for (int q = 0; q < 4; ++q) hv[q] = hv2[q];
    }
    // ---- epilogue: 16 outputs/thread direct from registers ----
    {
      int hcol = hcolw + la;
      float bir = bi_p[hcol], biz = bi_p[HID + hcol], bin = bi_p[2*HID + hcol];
      float bh = bhn_p[hcol];
      #pragma unroll
      for (int m = 0; m < 4; ++m){
        #pragma unroll
        for (int i = 0; i < 4; ++i){
          int lr = wm*64 + m*16 + (lane >> 4)*4 + i;
          int ridx = tile*128 + lr;
          if (ridx >= count) continue;
          int tb = rowlist[base + ridx];
          int t = tb >> 7, b = tb & 127;
          float hold;
          if (j > 0) hold = (float)y[((size_t)(t-1)*BB + b)*HID + hcol];
          else if (t == 0 && dones[b] == 0) hold = hidden0[(size_t)b*HID + hcol];
          else hold = 0.f;
          float r = 1.f / (1.f + expf(-(ar[m][i] + bir)));
          float z = 1.f / (1.f + expf(-(az[m][i] + biz)));
          float n = tanhf(axn[m][i] + bin + r * (ahn[m][i] + bh));
          float hnew = (1.f - z) * n + z * hold;
          y[((size_t)t*BB + b)*HID + hcol] = (f16)hnew;
          if (t == TT - 1) hout[(size_t)b*HID + hcol] = hnew;
        }
      }
    }
  }
}

// ---- sequential tail for chains longer than DPAR ----
__global__ __launch_bounds__(256)
void k_tail(const int* __restrict__ ntail, const int* __restrict__ chains,
            const f16* __restrict__ emb, const f16* __restrict__ bt2,
            const float* __restrict__ bi_p, const float* __restrict__ bhn_p,
            f16* __restrict__ y, float* __restrict__ hout){
  int n = *ntail;
  __shared__ f16 hs[1024];
  __shared__ f16 es[1024];
  int tid = threadIdx.x;
  for (int c = blockIdx.x; c < n; c += gridDim.x){
    int b = chains[c*3], t0 = chains[c*3+1], len = chains[c*3+2];
    for (int i = tid; i < 1024; i += 256)
      hs[i] = y[((size_t)(t0 + DPAR - 1)*BB + b)*HID + i];
    __syncthreads();
    for (int t = t0 + DPAR; t < t0 + len; ++t){
      for (int i = tid; i < 1024; i += 256)
        es[i] = emb[((size_t)t*BB + b)*HID + i];
      __syncthreads();
      float tmp[4];
      #pragma unroll
      for (int u = 0; u < 4; ++u){
        int col = tid*4 + u;
        float s_r = 0.f, s_z = 0.f, s_xn = 0.f, s_hn = 0.f;
        const f16* wr = bt2 + (size_t)col*2048;
        const f16* wz = bt2 + (size_t)(1024+col)*2048;
        const f16* wn = bt2 + (size_t)(2048+col)*2048;
        for (int q = 0; q < 128; ++q){
          f16x8 ev = *reinterpret_cast<const f16x8*>(&es[q*8]);
          f16x8 hv = *reinterpret_cast<const f16x8*>(&hs[q*8]);
          f16x8 wre = *reinterpret_cast<const f16x8*>(wr + q*8);
          f16x8 wrh = *reinterpret_cast<const f16x8*>(wr + 1024 + q*8);
          f16x8 wze = *reinterpret_cast<const f16x8*>(wz + q*8);
          f16x8 wzh = *reinterpret_cast<const f16x8*>(wz + 1024 + q*8);
          f16x8 wne = *reinterpret_cast<const f16x8*>(wn + q*8);
          f16x8 wnh = *reinterpret_cast<const f16x8*>(wn + 1024 + q*8);
          #pragma unroll
          for (int e = 0; e < 8; ++e){
            float ee = (float)ev[e], hh = (float)hv[e];
            s_r  += ee*(float)wre[e] + hh*(float)wrh[e];
            s_z  += ee*(float)wze[e] + hh*(float)wzh[e];
            s_xn += ee*(float)wne[e];
            s_hn += hh*(float)wnh[e];
          }
        }
        float r = 1.f / (1.f + expf(-(s_r + bi_p[col])));
        float z = 1.f / (1.f + expf(-(s_z + bi_p[1024+col])));
        float nn = tanhf(s_xn + bi_p[2048+col] + r * (s_hn + bhn_p[col]));
        float hold = (float)hs[col];
        float hnew = (1.f - z) * nn + z * hold;
        y[((size_t)t*BB + b)*HID + col] = (f16)hnew;
        if (t == TT - 1) hout[(size_t)b*HID + col] = hnew;
        tmp[u] = hnew;
      }
      __syncthreads();
      #pragma unroll
      for (int u = 0; u < 4; ++u) hs[tid*4 + u] = (f16)tmp[u];
      __syncthreads();
    }
    __syncthreads();
  }
}

// ---- critic fused with value partials: 128x128 tile, K=1024, f16 ----
__global__ __launch_bounds__(256)
void k_critic(const f16* __restrict__ Y, const f16* __restrict__ Bt,
              const float* __restrict__ b1, const float* __restrict__ W2,
              float* __restrict__ vpart){
  int w = threadIdx.x >> 6, lane = threadIdx.x & 63;
  int wm = w >> 1, wn = w & 1;
  int bid = blockIdx.x;
  int vid = (bid & 7) * 128 + (bid >> 3);
  int Mb = (vid >> 3) * 128, Nb = (vid & 7) * 128;
  int la = lane & 15, lk = (lane >> 4) * 8;
  f32x4 acc[4][4] = {};
  const f16* Ap[4]; const f16* Bp[4];
  for (int i = 0; i < 4; ++i){
    Ap[i] = Y  + (size_t)(Mb + wm*64 + i*16 + la) * HID;
    Bp[i] = Bt + (size_t)(Nb + wn*64 + i*16 + la) * HID;
  }
  #pragma unroll 2
  for (int k = 0; k < HID; k += 32){
    f16x8 af[4], bfr[4];
    for (int i = 0; i < 4; ++i){
      af[i]  = *reinterpret_cast<const f16x8*>(Ap[i] + k + lk);
      bfr[i] = *reinterpret_cast<const f16x8*>(Bp[i] + k + lk);
    }
    for (int mi = 0; mi < 4; ++mi)
      for (int ni = 0; ni < 4; ++ni)
        acc[mi][ni] = mfma16(af[mi], bfr[ni], acc[mi][ni]);
  }
  __shared__ float vs[2][64][2];
  float p[4][4];
  for (int mi = 0; mi < 4; ++mi) for (int i = 0; i < 4; ++i) p[mi][i] = 0.f;
  for (int ni = 0; ni < 4; ++ni){
    int col = Nb + wn*64 + ni*16 + la;
    float bb = b1[col], w2 = W2[col];
    for (int mi = 0; mi < 4; ++mi)
      for (int i = 0; i < 4; ++i){
        float c = acc[mi][ni][i] + bb;
        p[mi][i] += (c > 0.f ? c : 0.f) * w2;
      }
  }
  for (int mi = 0; mi < 4; ++mi) for (int i = 0; i < 4; ++i){
    float s = p[mi][i];
    s += __shfl_xor(s, 1); s += __shfl_xor(s, 2);
    s += __shfl_xor(s, 4); s += __shfl_xor(s, 8);
    p[mi][i] = s;
  }
  if (la == 0){
    int q = lane >> 4;
    for (int mi = 0; mi < 4; ++mi)
      for (int i = 0; i < 4; ++i)
        vs[wm][mi*16 + q*4 + i][wn] = p[mi][i];
  }
  __syncthreads();
  if (threadIdx.x < 128){
    int rw = threadIdx.x;
    float s = vs[rw >> 6][rw & 63][0] + vs[rw >> 6][rw & 63][1];
    vpart[(size_t)(Nb >> 7) * (TT*BB) + Mb + rw] = s;
  }
}

__global__ void k_vreduce(const float* __restrict__ vpart, const float* __restrict__ b2,
                          float* __restrict__ outv){
  int m = blockIdx.x * 256 + threadIdx.x;
  float s = b2[0];
  for (int nb = 0; nb < 8; ++nb) s += vpart[(size_t)nb * (TT*BB) + m];
  outv[m] = s;
}

extern "C" void kernel_launch(void* const* d_in, const int* in_sizes, int n_in,
                              void* d_out, int out_size, void* d_ws, size_t ws_size,
                              hipStream_t stream){
  const float* hidden = (const float*)d_in[0];
  const float* world  = (const float*)d_in[1];
  const int*   dones  = (const int*)d_in[2];
  const float* W_emb  = (const float*)d_in[3];
  const float* b_emb  = (const float*)d_in[4];
  const float* Wi     = (const float*)d_in[5];
  const float* bi     = (const float*)d_in[6];
  const float* Wh     = (const float*)d_in[7];
  const float* bhn    = (const float*)d_in[8];
  const float* W1     = (const float*)d_in[9];
  const float* b1     = (const float*)d_in[10];
  const float* W2     = (const float*)d_in[11];
  const float* b2     = (const float*)d_in[12];
  float* out = (float*)d_out;

  char* p = (char*)d_ws;
  auto alloc = [&](size_t bytes) -> char* {
    char* r = p; p += (bytes + 255) & ~(size_t)255; return r;
  };
  f16*   ws16   = (f16*)alloc((size_t)TT*BB*OBSD*2);     // 16 MB
  f16*   wembt  = (f16*)alloc((size_t)HID*OBSD*2);       // 1 MB
  f16*   emb16  = (f16*)alloc((size_t)TT*BB*HID*2);      // 33.5 MB
  f16*   bt2    = (f16*)alloc((size_t)3072*2048*2);      // 12.6 MB
  f16*   w1t    = (f16*)alloc((size_t)HID*HID*2);        // 2 MB
  f16*   ybuf   = (f16*)alloc((size_t)TT*BB*HID*2);      // 33.5 MB
  float* vpart  = (float*)alloc((size_t)8*TT*BB*4);      // 0.5 MB
  int*   off    = (int*)alloc((DPAR + 1) * 4);
  int*   rowlist= (int*)alloc((size_t)(TT*BB + 128)*4);  // 64 KB (+pad)
  int*   ntail  = (int*)alloc(4);
  int*   chains = (int*)alloc((size_t)1024*3*4);
  if ((size_t)(p - (char*)d_ws) > ws_size) return;

  // preps (+ segmentation, depends only on dones)
  k_ws_to_f16<<<(TT*BB*OBSD/4 + 255)/256, 256, 0, stream>>>(world, ws16, TT*BB*OBSD/4);
  k_prep_bt<<<dim3(OBSD/64, HID/64), 256, 0, stream>>>(W_emb, 1024, wembt, OBSD);
  k_prep_bt2<<<dim3(2048/64, 3072/64), 256, 0, stream>>>(Wi, Wh, bt2);
  k_prep_bt<<<dim3(HID/64, HID/64), 256, 0, stream>>>(W1, 1024, w1t, HID);
  k_seg<<<1, 128, 0, stream>>>(dones, off, rowlist, ntail, chains);

  // embedding GEMM
  k_emb<<<1024, 256, 0, stream>>>(ws16, wembt, b_emb, emb16);

  // depth-parallel fused GRU scan: 16 launches + tail
  for (int j = 0; j < DPAR; ++j)
    k_depth<<<1024, 512, 0, stream>>>(j, off, rowlist, emb16, bt2, bi, bhn,
                                      dones, hidden, ybuf, out);
  k_tail<<<128, 256, 0, stream>>>(ntail, chains, emb16, bt2, bi, bhn, ybuf, out);

  // critic head + value
  k_critic<<<1024, 256, 0, stream>>>(ybuf, w1t, b1, W2, vpart);
  k_vreduce<<<TT*BB/256, 256, 0, stream>>>(vpart, b2, out + (size_t)BB*HID);
}

// Round 14
// 1542.572 us; speedup vs baseline: 1.7658x; 1.7658x over previous
//
#include <hip/hip_runtime.h>
#include <stdint.h>

#define TT 128
#define BB 128
#define OBSD 512
#define HID 1024
#define DPAR 24

typedef _Float16 f16;
typedef _Float16 f16x8 __attribute__((ext_vector_type(8)));
typedef _Float16 f16x4 __attribute__((ext_vector_type(4)));
typedef float f32x4 __attribute__((ext_vector_type(4)));

__device__ __forceinline__ f32x4 mfma16(f16x8 a, f16x8 b, f32x4 c){
  return __builtin_amdgcn_mfma_f32_16x16x32_f16(a, b, c, 0, 0, 0);
}

// ---- prep: world_state f32 -> f16 ----
__global__ void k_ws_to_f16(const float* __restrict__ src, f16* __restrict__ dst, int n4){
  int i = blockIdx.x * blockDim.x + threadIdx.x;
  if (i < n4){
    float4 v = *reinterpret_cast<const float4*>(src + (size_t)i * 4);
    dst[(size_t)i*4 + 0] = (f16)v.x; dst[(size_t)i*4 + 1] = (f16)v.y;
    dst[(size_t)i*4 + 2] = (f16)v.z; dst[(size_t)i*4 + 3] = (f16)v.w;
  }
}

// ---- prep: transpose f32 [KD][C] (row stride srcStride) -> f16 dst[C][KD] ----
__global__ void k_prep_bt(const float* __restrict__ s0, int srcStride,
                          f16* __restrict__ dst, int KD){
  __shared__ f16 sm[64][65];
  int k0 = blockIdx.x * 64, c0 = blockIdx.y * 64;
  for (int it = 0; it < 16; ++it){
    int idx = it * 256 + threadIdx.x;
    int kr = idx >> 6, cc = idx & 63;
    sm[kr][cc] = (f16)s0[(size_t)(k0 + kr) * srcStride + (c0 + cc)];
  }
  __syncthreads();
  for (int it = 0; it < 16; ++it){
    int idx = it * 256 + threadIdx.x;
    int cr = idx >> 6, kc = idx & 63;
    dst[(size_t)(c0 + cr) * KD + (k0 + kc)] = sm[kc][cr];
  }
}

// ---- prep: bt2[c][k] = k<1024 ? Wi[k][c] : Wh[k-1024][c]; c<3072, k<2048 ----
__global__ void k_prep_bt2(const float* __restrict__ wi, const float* __restrict__ wh,
                           f16* __restrict__ dst){
  __shared__ f16 sm[64][65];
  int k0 = blockIdx.x * 64, c0 = blockIdx.y * 64;
  const float* src = (k0 < 1024) ? wi : wh;
  int kb = (k0 < 1024) ? k0 : k0 - 1024;
  for (int it = 0; it < 16; ++it){
    int idx = it * 256 + threadIdx.x;
    int kr = idx >> 6, cc = idx & 63;
    sm[kr][cc] = (f16)src[(size_t)(kb + kr) * 3072 + (c0 + cc)];
  }
  __syncthreads();
  for (int it = 0; it < 16; ++it){
    int idx = it * 256 + threadIdx.x;
    int cr = idx >> 6, kc = idx & 63;
    dst[(size_t)(c0 + cr) * 2048 + (k0 + kc)] = sm[kc][cr];
  }
}

// ---- segmentation: offset-0 rows with h==0 -> zlist (no GEMM);
//      t=0-continuing -> bucket 0; offsets 1..DPAR-1 -> buckets; long -> chains ----
__global__ void k_seg(const int* __restrict__ dones, int* __restrict__ off,
                      int* __restrict__ rowlist, int* __restrict__ znum,
                      int* __restrict__ zlist, int* __restrict__ ntail,
                      int* __restrict__ chains){
  __shared__ int cnt[DPAR];
  __shared__ int cur[DPAR];
  __shared__ int zc, zcur;
  int tid = threadIdx.x;               // 128 threads, one per b
  if (tid < DPAR) cnt[tid] = 0;
  if (tid == 0){ *ntail = 0; zc = 0; zcur = 0; }
  __syncthreads();
  int b = tid;
  int start = 0;
  for (int t = 1; t <= TT; ++t){
    bool boundary = (t == TT) || (dones[t * BB + b] != 0);
    if (boundary){
      int len = t - start;
      if (start == 0 && dones[b] == 0) atomicAdd(&cnt[0], 1);
      else atomicAdd(&zc, 1);
      int nb = len < DPAR ? len : DPAR;
      for (int d = 1; d < nb; ++d) atomicAdd(&cnt[d], 1);
      if (len > DPAR){
        int c = atomicAdd(ntail, 1);
        chains[c*3+0] = b; chains[c*3+1] = start; chains[c*3+2] = len;
      }
      start = t;
    }
  }
  __syncthreads();
  if (tid == 0){
    int s = 0;
    for (int d = 0; d < DPAR; ++d){ off[d] = s; cur[d] = s; s += cnt[d]; }
    off[DPAR] = s;
    *znum = zc;
  }
  __syncthreads();
  start = 0;
  for (int t = 1; t <= TT; ++t){
    bool boundary = (t == TT) || (dones[t * BB + b] != 0);
    if (boundary){
      int len = t - start;
      if (start == 0 && dones[b] == 0){
        int pos = atomicAdd(&cur[0], 1);
        rowlist[pos] = (start << 7) | b;
      } else {
        int pos = atomicAdd(&zcur, 1);
        zlist[pos] = (start << 7) | b;
      }
      int nb = len < DPAR ? len : DPAR;
      for (int d = 1; d < nb; ++d){
        int pos = atomicAdd(&cur[d], 1);
        rowlist[pos] = ((start + d) << 7) | b;
      }
      start = t;
    }
  }
}

// ---- emb = relu(ws @ W_emb + b_emb): [16384x512]@[512->1024], f16 out ----
__global__ __launch_bounds__(256)
void k_emb(const f16* __restrict__ A, const f16* __restrict__ Bt,
           const float* __restrict__ bias, f16* __restrict__ outb){
  int w = threadIdx.x >> 6, lane = threadIdx.x & 63;
  int wm = w >> 1, wn = w & 1;
  int bid = blockIdx.x;                       // 1024 = 128 Mb x 8 Nb
  int vid = (bid & 7) * 128 + (bid >> 3);
  int Mb = (vid >> 3) * 128, Nb = (vid & 7) * 128;
  int la = lane & 15, lk = (lane >> 4) * 8;
  f32x4 acc[4][4] = {};
  const f16* Ap[4]; const f16* Bp[4];
  for (int i = 0; i < 4; ++i){
    Ap[i] = A + (size_t)(Mb + wm*64 + i*16 + la) * OBSD;
    Bp[i] = Bt + (size_t)(Nb + wn*64 + i*16 + la) * OBSD;
  }
  for (int k = 0; k < OBSD; k += 32){
    f16x8 af[4], bfr[4];
    for (int i = 0; i < 4; ++i){
      af[i]  = *reinterpret_cast<const f16x8*>(Ap[i] + k + lk);
      bfr[i] = *reinterpret_cast<const f16x8*>(Bp[i] + k + lk);
    }
    for (int mi = 0; mi < 4; ++mi)
      for (int ni = 0; ni < 4; ++ni)
        acc[mi][ni] = mfma16(af[mi], bfr[ni], acc[mi][ni]);
  }
  for (int mi = 0; mi < 4; ++mi) for (int ni = 0; ni < 4; ++ni){
    int col = Nb + wn*64 + ni*16 + la;
    float bb = bias[col];
    for (int i = 0; i < 4; ++i){
      int row = Mb + wm*64 + mi*16 + (lane >> 4)*4 + i;
      float v = acc[mi][ni][i] + bb;
      outb[(size_t)row * HID + col] = (f16)(v > 0.f ? v : 0.f);
    }
  }
}

// ---- xi = emb @ Wi + bi: [16384x1024]@[1024->3072], f16 out ----
__global__ __launch_bounds__(256)
void k_xi(const f16* __restrict__ A, const f16* __restrict__ Bt,
          const float* __restrict__ bias, f16* __restrict__ outb){
  int w = threadIdx.x >> 6, lane = threadIdx.x & 63;
  int wm = w >> 1, wn = w & 1;
  int bid = blockIdx.x;                       // 3072 = 128 Mb x 24 Nb
  int vid = (bid & 7) * 384 + (bid >> 3);
  int Mb = (vid / 24) * 128, Nb = (vid % 24) * 128;
  int la = lane & 15, lk = (lane >> 4) * 8;
  f32x4 acc[4][4] = {};
  const f16* Ap[4]; const f16* Bp[4];
  for (int i = 0; i < 4; ++i){
    Ap[i] = A + (size_t)(Mb + wm*64 + i*16 + la) * 2048;     // bt2 k<1024 is Wi
    Bp[i] = Bt + (size_t)(Nb + wn*64 + i*16 + la) * 2048;
  }
  // NOTE: A is emb (stride HID) -- set separately below.
  (void)Ap;
  const f16* Ae[4];
  for (int i = 0; i < 4; ++i)
    Ae[i] = A + (size_t)(Mb + wm*64 + i*16 + la) * HID;
  #pragma unroll 2
  for (int k = 0; k < HID; k += 32){
    f16x8 af[4], bfr[4];
    for (int i = 0; i < 4; ++i){
      af[i]  = *reinterpret_cast<const f16x8*>(Ae[i] + k + lk);
      bfr[i] = *reinterpret_cast<const f16x8*>(Bp[i] + k + lk);
    }
    for (int mi = 0; mi < 4; ++mi)
      for (int ni = 0; ni < 4; ++ni)
        acc[mi][ni] = mfma16(af[mi], bfr[ni], acc[mi][ni]);
  }
  for (int mi = 0; mi < 4; ++mi) for (int ni = 0; ni < 4; ++ni){
    int col = Nb + wn*64 + ni*16 + la;
    float bb = bias[col];
    for (int i = 0; i < 4; ++i){
      int row = Mb + wm*64 + mi*16 + (lane >> 4)*4 + i;
      outb[(size_t)row * 3072 + col] = (f16)(acc[mi][ni][i] + bb);
    }
  }
}

// ---- h-zero rows: h = (1-z)*n, straight from xi (no GEMM) ----
__global__ __launch_bounds__(256)
void k_h0(const int* __restrict__ znum, const int* __restrict__ zlist,
          const f16* __restrict__ xi, const float* __restrict__ bhn_p,
          f16* __restrict__ y, float* __restrict__ hout){
  int nz = *znum;
  int tid = threadIdx.x;
  for (int ridx = blockIdx.x; ridx < nz; ridx += gridDim.x){
    int tb = zlist[ridx];
    int t = tb >> 7, b = tb & 127;
    size_t rb = ((size_t)t*BB + b) * 3072;
    int c0 = tid * 4;
    f16x4 xr = *reinterpret_cast<const f16x4*>(xi + rb + c0);
    f16x4 xz = *reinterpret_cast<const f16x4*>(xi + rb + 1024 + c0);
    f16x4 xn = *reinterpret_cast<const f16x4*>(xi + rb + 2048 + c0);
    f16x4 o;
    #pragma unroll
    for (int u = 0; u < 4; ++u){
      float r = 1.f / (1.f + expf(-(float)xr[u]));
      float z = 1.f / (1.f + expf(-(float)xz[u]));
      float n = tanhf((float)xn[u] + r * bhn_p[c0 + u]);
      float h = (1.f - z) * n;
      o[u] = (f16)h;
      if (t == TT - 1) hout[(size_t)b*HID + c0 + u] = h;
    }
    *reinterpret_cast<f16x4*>(y + ((size_t)t*BB + b)*HID + c0) = o;
  }
}

// ---- depth-j GRU step: h_prev @ Wh, K=1024; gates from xi in epilogue ----
// BM=128 x BN=192 (64 hcols x 3 gates), 512 thr = 2m x 4n waves. BK=128,
// reg-staged pipeline. Wh = bt2 rows, k-offset +1024. grid 1024 = 64 st x 16 nb.
__global__ __launch_bounds__(512)
void k_depth(int j, const int* __restrict__ off, const int* __restrict__ rowlist,
             const f16* __restrict__ xi, const f16* __restrict__ bt2,
             const float* __restrict__ bhn_p, const float* __restrict__ hidden0,
             f16* __restrict__ y, float* __restrict__ hout){
  __shared__ __attribute__((aligned(16))) char smem[32768];   // 128 x 128 f16, swizzled
  const int base = off[j];
  const int count = off[j+1] - base;
  if (count <= 0) return;
  const int tid = threadIdx.x;
  const int lane = tid & 63;
  const int w = tid >> 6;                    // 8 waves
  const int wm = w >> 2, wn = w & 3;         // 2m x 4n
  const int nb = blockIdx.x & 15;
  const int st = blockIdx.x >> 4;            // 64 M-strides
  const int la = lane & 15, lk = (lane >> 4) * 8;
  const int hcolw = nb*64 + wn*16;           // wave's hcol base
  const f16* Bg0 = bt2 + (size_t)(          hcolw + la) * 2048 + 1024 + lk;
  const f16* Bg1 = bt2 + (size_t)(1024 +    hcolw + la) * 2048 + 1024 + lk;
  const f16* Bg2 = bt2 + (size_t)(2048 +    hcolw + la) * 2048 + 1024 + lk;
  const int ntiles = (count + 127) >> 7;

  for (int tile = st; tile < ntiles; tile += 64){
    // per-q staging geometry (row fixed per q across all 8 chunks)
    const char* hptr[4]; int hmode[4]; int sq[4]; int dby[4];
    #pragma unroll
    for (int q = 0; q < 4; ++q){
      int idx = tid + q*512;
      int r = idx >> 4; sq[q] = idx & 15;
      dby[q] = (r*256 + sq[q]*16) ^ ((r & 7) << 4);
      int ridx = tile*128 + r;
      int tb = (ridx < count) ? rowlist[base + ridx] : -1;
      hmode[q] = 0; hptr[q] = nullptr;
      if (tb >= 0){
        int t = tb >> 7, b = tb & 127;
        if (j > 0){ hmode[q] = 1; hptr[q] = (const char*)(y + ((size_t)(t-1)*BB + b)*HID); }
        else      { hmode[q] = 2; hptr[q] = (const char*)(hidden0 + (size_t)b*HID); }
      }
    }
    auto loadch = [&](int ch, float4* dst){
      #pragma unroll
      for (int q = 0; q < 4; ++q){
        float4 v = {0.f, 0.f, 0.f, 0.f};
        if (hmode[q] == 1){
          v = *reinterpret_cast<const float4*>((const f16*)hptr[q] + ch*128 + sq[q]*8);
        } else if (hmode[q] == 2){
          const float* s = (const float*)hptr[q] + ch*128 + sq[q]*8;
          float4 a0 = *reinterpret_cast<const float4*>(s);
          float4 a1 = *reinterpret_cast<const float4*>(s + 4);
          f16 h8[8] = {(f16)a0.x,(f16)a0.y,(f16)a0.z,(f16)a0.w,
                       (f16)a1.x,(f16)a1.y,(f16)a1.z,(f16)a1.w};
          v = *reinterpret_cast<float4*>(h8);
        }
        dst[q] = v;
      }
    };
    f32x4 ar[4] = {}, az[4] = {}, ahn[4] = {};
    float4 hv[4];
    loadch(0, hv);
    #pragma unroll 1
    for (int ch = 0; ch < 8; ++ch){
      __syncthreads();                       // prior chunk's smem reads done
      #pragma unroll
      for (int q = 0; q < 4; ++q)
        *reinterpret_cast<float4*>(smem + dby[q]) = hv[q];
      float4 hv2[4];
      if (ch < 7) loadch(ch+1, hv2);         // in flight under MFMAs below
      __syncthreads();
      const int kbase = ch*128;
      #pragma unroll
      for (int kk = 0; kk < 128; kk += 32){
        f16x8 av[4];
        #pragma unroll
        for (int m = 0; m < 4; ++m){
          int r = wm*64 + m*16 + la;
          av[m] = *reinterpret_cast<const f16x8*>(
              smem + ((r*256 + (kk + lk)*2) ^ ((r & 7) << 4)));
        }
        f16x8 b0 = *reinterpret_cast<const f16x8*>(Bg0 + kbase + kk);
        f16x8 b1 = *reinterpret_cast<const f16x8*>(Bg1 + kbase + kk);
        f16x8 b2 = *reinterpret_cast<const f16x8*>(Bg2 + kbase + kk);
        #pragma unroll
        for (int m = 0; m < 4; ++m){
          ar[m]  = mfma16(av[m], b0, ar[m]);
          az[m]  = mfma16(av[m], b1, az[m]);
          ahn[m] = mfma16(av[m], b2, ahn[m]);
        }
      }
      #pragma unroll
      for (int q = 0; q < 4; ++q) hv[q] = hv2[q];
    }
    // ---- epilogue: 16 outputs/thread; gates = xi + h@Wh ----
    {
      int hcol = hcolw + la;
      float bh = bhn_p[hcol];
      #pragma unroll
      for (int m = 0; m < 4; ++m){
        #pragma unroll
        for (int i = 0; i < 4; ++i){
          int lr = wm*64 + m*16 + (lane >> 4)*4 + i;
          int ridx = tile*128 + lr;
          if (ridx >= count) continue;
          int tb = rowlist[base + ridx];
          int t = tb >> 7, b = tb & 127;
          size_t rb = ((size_t)t*BB + b)*3072 + hcol;
          float hold;
          if (j > 0) hold = (float)y[((size_t)(t-1)*BB + b)*HID + hcol];
          else       hold = hidden0[(size_t)b*HID + hcol];
          float r = 1.f / (1.f + expf(-((float)xi[rb]        + ar[m][i])));
          float z = 1.f / (1.f + expf(-((float)xi[rb + 1024] + az[m][i])));
          float n = tanhf((float)xi[rb + 2048] + r * (ahn[m][i] + bh));
          float hnew = (1.f - z) * n + z * hold;
          y[((size_t)t*BB + b)*HID + hcol] = (f16)hnew;
          if (t == TT - 1) hout[(size_t)b*HID + hcol] = hnew;
        }
      }
    }
  }
}

// ---- sequential tail for chains longer than DPAR (empty for this seed) ----
__global__ __launch_bounds__(256)
void k_tail(const int* __restrict__ ntail, const int* __restrict__ chains,
            const f16* __restrict__ xi, const f16* __restrict__ bt2,
            const float* __restrict__ bhn_p, f16* __restrict__ y,
            float* __restrict__ hout){
  int n = *ntail;
  __shared__ f16 hs[1024];
  int tid = threadIdx.x;
  for (int c = blockIdx.x; c < n; c += gridDim.x){
    int b = chains[c*3], t0 = chains[c*3+1], len = chains[c*3+2];
    for (int i = tid; i < 1024; i += 256)
      hs[i] = y[((size_t)(t0 + DPAR - 1)*BB + b)*HID + i];
    __syncthreads();
    for (int t = t0 + DPAR; t < t0 + len; ++t){
      float tmp[4];
      #pragma unroll
      for (int u = 0; u < 4; ++u){
        int col = tid*4 + u;
        float s_r = 0.f, s_z = 0.f, s_hn = 0.f;
        const f16* wr = bt2 + (size_t)col*2048 + 1024;
        const f16* wz = bt2 + (size_t)(1024+col)*2048 + 1024;
        const f16* wn = bt2 + (size_t)(2048+col)*2048 + 1024;
        for (int q = 0; q < 128; ++q){
          f16x8 hv = *reinterpret_cast<const f16x8*>(&hs[q*8]);
          f16x8 wrh = *reinterpret_cast<const f16x8*>(wr + q*8);
          f16x8 wzh = *reinterpret_cast<const f16x8*>(wz + q*8);
          f16x8 wnh = *reinterpret_cast<const f16x8*>(wn + q*8);
          #pragma unroll
          for (int e = 0; e < 8; ++e){
            float hh = (float)hv[e];
            s_r  += hh*(float)wrh[e];
            s_z  += hh*(float)wzh[e];
            s_hn += hh*(float)wnh[e];
          }
        }
        size_t rb = ((size_t)t*BB + b)*3072 + col;
        float r = 1.f / (1.f + expf(-((float)xi[rb] + s_r)));
        float z = 1.f / (1.f + expf(-((float)xi[rb + 1024] + s_z)));
        float nn = tanhf((float)xi[rb + 2048] + r * (s_hn + bhn_p[col]));
        float hold = (float)hs[col];
        float hnew = (1.f - z) * nn + z * hold;
        y[((size_t)t*BB + b)*HID + col] = (f16)hnew;
        if (t == TT - 1) hout[(size_t)b*HID + col] = hnew;
        tmp[u] = hnew;
      }
      __syncthreads();
      #pragma unroll
      for (int u = 0; u < 4; ++u) hs[tid*4 + u] = (f16)tmp[u];
      __syncthreads();
    }
    __syncthreads();
  }
}

// ---- critic fused with value partials: 128x128 tile, K=1024, f16 ----
__global__ __launch_bounds__(256)
void k_critic(const f16* __restrict__ Y, const f16* __restrict__ Bt,
              const float* __restrict__ b1, const float* __restrict__ W2,
              float* __restrict__ vpart){
  int w = threadIdx.x >> 6, lane = threadIdx.x & 63;
  int wm = w >> 1, wn = w & 1;
  int bid = blockIdx.x;
  int vid = (bid & 7) * 128 + (bid >> 3);
  int Mb = (vid >> 3) * 128, Nb = (vid & 7) * 128;
  int la = lane & 15, lk = (lane >> 4) * 8;
  f32x4 acc[4][4] = {};
  const f16* Ap[4]; const f16* Bp[4];
  for (int i = 0; i < 4; ++i){
    Ap[i] = Y  + (size_t)(Mb + wm*64 + i*16 + la) * HID;
    Bp[i] = Bt + (size_t)(Nb + wn*64 + i*16 + la) * HID;
  }
  #pragma unroll 2
  for (int k = 0; k < HID; k += 32){
    f16x8 af[4], bfr[4];
    for (int i = 0; i < 4; ++i){
      af[i]  = *reinterpret_cast<const f16x8*>(Ap[i] + k + lk);
      bfr[i] = *reinterpret_cast<const f16x8*>(Bp[i] + k + lk);
    }
    for (int mi = 0; mi < 4; ++mi)
      for (int ni = 0; ni < 4; ++ni)
        acc[mi][ni] = mfma16(af[mi], bfr[ni], acc[mi][ni]);
  }
  __shared__ float vs[2][64][2];
  float p[4][4];
  for (int mi = 0; mi < 4; ++mi) for (int i = 0; i < 4; ++i) p[mi][i] = 0.f;
  for (int ni = 0; ni < 4; ++ni){
    int col = Nb + wn*64 + ni*16 + la;
    float bb = b1[col], w2 = W2[col];
    for (int mi = 0; mi < 4; ++mi)
      for (int i = 0; i < 4; ++i){
        float c = acc[mi][ni][i] + bb;
        p[mi][i] += (c > 0.f ? c : 0.f) * w2;
      }
  }
  for (int mi = 0; mi < 4; ++mi) for (int i = 0; i < 4; ++i){
    float s = p[mi][i];
    s += __shfl_xor(s, 1); s += __shfl_xor(s, 2);
    s += __shfl_xor(s, 4); s += __shfl_xor(s, 8);
    p[mi][i] = s;
  }
  if (la == 0){
    int q = lane >> 4;
    for (int mi = 0; mi < 4; ++mi)
      for (int i = 0; i < 4; ++i)
        vs[wm][mi*16 + q*4 + i][wn] = p[mi][i];
  }
  __syncthreads();
  if (threadIdx.x < 128){
    int rw = threadIdx.x;
    float s = vs[rw >> 6][rw & 63][0] + vs[rw >> 6][rw & 63][1];
    vpart[(size_t)(Nb >> 7) * (TT*BB) + Mb + rw] = s;
  }
}

__global__ void k_vreduce(const float* __restrict__ vpart, const float* __restrict__ b2,
                          float* __restrict__ outv){
  int m = blockIdx.x * 256 + threadIdx.x;
  float s = b2[0];
  for (int nb = 0; nb < 8; ++nb) s += vpart[(size_t)nb * (TT*BB) + m];
  outv[m] = s;
}

extern "C" void kernel_launch(void* const* d_in, const int* in_sizes, int n_in,
                              void* d_out, int out_size, void* d_ws, size_t ws_size,
                              hipStream_t stream){
  const float* hidden = (const float*)d_in[0];
  const float* world  = (const float*)d_in[1];
  const int*   dones  = (const int*)d_in[2];
  const float* W_emb  = (const float*)d_in[3];
  const float* b_emb  = (const float*)d_in[4];
  const float* Wi     = (const float*)d_in[5];
  const float* bi     = (const float*)d_in[6];
  const float* Wh     = (const float*)d_in[7];
  const float* bhn    = (const float*)d_in[8];
  const float* W1     = (const float*)d_in[9];
  const float* b1     = (const float*)d_in[10];
  const float* W2     = (const float*)d_in[11];
  const float* b2     = (const float*)d_in[12];
  float* out = (float*)d_out;

  char* p = (char*)d_ws;
  auto alloc = [&](size_t bytes) -> char* {
    char* r = p; p += (bytes + 255) & ~(size_t)255; return r;
  };
  f16*   ws16   = (f16*)alloc((size_t)TT*BB*OBSD*2);     // 16 MB
  f16*   wembt  = (f16*)alloc((size_t)HID*OBSD*2);       // 1 MB
  f16*   emb16  = (f16*)alloc((size_t)TT*BB*HID*2);      // 33.5 MB
  f16*   bt2    = (f16*)alloc((size_t)3072*2048*2);      // 12.6 MB
  f16*   w1t    = (f16*)alloc((size_t)HID*HID*2);        // 2 MB
  f16*   xi16   = (f16*)alloc((size_t)TT*BB*3072*2);     // 100.7 MB
  f16*   ybuf   = (f16*)alloc((size_t)TT*BB*HID*2);      // 33.5 MB
  float* vpart  = (float*)alloc((size_t)8*TT*BB*4);      // 0.5 MB
  int*   off    = (int*)alloc((DPAR + 1) * 4);
  int*   rowlist= (int*)alloc((size_t)(TT*BB + 128)*4);
  int*   znum   = (int*)alloc(4);
  int*   zlist  = (int*)alloc((size_t)(TT*BB + 128)*4);
  int*   ntail  = (int*)alloc(4);
  int*   chains = (int*)alloc((size_t)1024*3*4);
  if ((size_t)(p - (char*)d_ws) > ws_size) return;

  // preps (+ segmentation, depends only on dones)
  k_ws_to_f16<<<(TT*BB*OBSD/4 + 255)/256, 256, 0, stream>>>(world, ws16, TT*BB*OBSD/4);
  k_prep_bt<<<dim3(OBSD/64, HID/64), 256, 0, stream>>>(W_emb, 1024, wembt, OBSD);
  k_prep_bt2<<<dim3(2048/64, 3072/64), 256, 0, stream>>>(Wi, Wh, bt2);
  k_prep_bt<<<dim3(HID/64, HID/64), 256, 0, stream>>>(W1, 1024, w1t, HID);
  k_seg<<<1, 128, 0, stream>>>(dones, off, rowlist, znum, zlist, ntail, chains);

  // parallel GEMMs
  k_emb<<<1024, 256, 0, stream>>>(ws16, wembt, b_emb, emb16);
  k_xi<<<3072, 256, 0, stream>>>(emb16, bt2, bi, xi16);

  // h-zero rows (no GEMM) + depth-parallel GRU scan + tail
  k_h0<<<2048, 256, 0, stream>>>(znum, zlist, xi16, bhn, ybuf, out);
  for (int j = 0; j < DPAR; ++j)
    k_depth<<<1024, 512, 0, stream>>>(j, off, rowlist, xi16, bt2, bhn,
                                      hidden, ybuf, out);
  k_tail<<<128, 256, 0, stream>>>(ntail, chains, xi16, bt2, bhn, ybuf, out);

  // critic head + value
  k_critic<<<1024, 256, 0, stream>>>(ybuf, w1t, b1, W2, vpart);
  k_vreduce<<<TT*BB/256, 256, 0, stream>>>(vpart, b2, out + (size_t)BB*HID);
}

// Round 15
// 1317.035 us; speedup vs baseline: 2.0682x; 1.1712x over previous
//
#include <hip/hip_runtime.h>
#include <stdint.h>

#define TT 128
#define BB 128
#define OBSD 512
#define HID 1024
#define DPAR 24

typedef _Float16 f16;
typedef _Float16 f16x8 __attribute__((ext_vector_type(8)));
typedef _Float16 f16x4 __attribute__((ext_vector_type(4)));
typedef float f32x4 __attribute__((ext_vector_type(4)));

__device__ __forceinline__ f32x4 mfma16(f16x8 a, f16x8 b, f32x4 c){
  return __builtin_amdgcn_mfma_f32_16x16x32_f16(a, b, c, 0, 0, 0);
}
__device__ __forceinline__ void gload16(const void* g, void* l){
  __builtin_amdgcn_global_load_lds(
      (const __attribute__((address_space(1))) unsigned int*)g,
      (__attribute__((address_space(3))) unsigned int*)l, 16, 0, 0);
}

// ---- prep: world_state f32 -> f16 ----
__global__ void k_ws_to_f16(const float* __restrict__ src, f16* __restrict__ dst, int n4){
  int i = blockIdx.x * blockDim.x + threadIdx.x;
  if (i < n4){
    float4 v = *reinterpret_cast<const float4*>(src + (size_t)i * 4);
    dst[(size_t)i*4 + 0] = (f16)v.x; dst[(size_t)i*4 + 1] = (f16)v.y;
    dst[(size_t)i*4 + 2] = (f16)v.z; dst[(size_t)i*4 + 3] = (f16)v.w;
  }
}

// ---- prep: transpose f32 [KD][C] (row stride srcStride) -> f16 dst[C][KD] ----
__global__ void k_prep_bt(const float* __restrict__ s0, int srcStride,
                          f16* __restrict__ dst, int KD){
  __shared__ f16 sm[64][65];
  int k0 = blockIdx.x * 64, c0 = blockIdx.y * 64;
  for (int it = 0; it < 16; ++it){
    int idx = it * 256 + threadIdx.x;
    int kr = idx >> 6, cc = idx & 63;
    sm[kr][cc] = (f16)s0[(size_t)(k0 + kr) * srcStride + (c0 + cc)];
  }
  __syncthreads();
  for (int it = 0; it < 16; ++it){
    int idx = it * 256 + threadIdx.x;
    int cr = idx >> 6, kc = idx & 63;
    dst[(size_t)(c0 + cr) * KD + (k0 + kc)] = sm[kc][cr];
  }
}

// ---- prep: bt2[c][k] = k<1024 ? Wi[k][c] : Wh[k-1024][c]; c<3072, k<2048 ----
__global__ void k_prep_bt2(const float* __restrict__ wi, const float* __restrict__ wh,
                           f16* __restrict__ dst){
  __shared__ f16 sm[64][65];
  int k0 = blockIdx.x * 64, c0 = blockIdx.y * 64;
  const float* src = (k0 < 1024) ? wi : wh;
  int kb = (k0 < 1024) ? k0 : k0 - 1024;
  for (int it = 0; it < 16; ++it){
    int idx = it * 256 + threadIdx.x;
    int kr = idx >> 6, cc = idx & 63;
    sm[kr][cc] = (f16)src[(size_t)(kb + kr) * 3072 + (c0 + cc)];
  }
  __syncthreads();
  for (int it = 0; it < 16; ++it){
    int idx = it * 256 + threadIdx.x;
    int cr = idx >> 6, kc = idx & 63;
    dst[(size_t)(c0 + cr) * 2048 + (k0 + kc)] = sm[kc][cr];
  }
}

// ---- segmentation: offset-0 rows with h==0 -> zlist (no GEMM);
//      t=0-continuing -> bucket 0; offsets 1..DPAR-1 -> buckets; long -> chains ----
__global__ void k_seg(const int* __restrict__ dones, int* __restrict__ off,
                      int* __restrict__ rowlist, int* __restrict__ znum,
                      int* __restrict__ zlist, int* __restrict__ ntail,
                      int* __restrict__ chains){
  __shared__ int cnt[DPAR];
  __shared__ int cur[DPAR];
  __shared__ int zc, zcur;
  int tid = threadIdx.x;               // 128 threads, one per b
  if (tid < DPAR) cnt[tid] = 0;
  if (tid == 0){ *ntail = 0; zc = 0; zcur = 0; }
  __syncthreads();
  int b = tid;
  int start = 0;
  for (int t = 1; t <= TT; ++t){
    bool boundary = (t == TT) || (dones[t * BB + b] != 0);
    if (boundary){
      int len = t - start;
      if (start == 0 && dones[b] == 0) atomicAdd(&cnt[0], 1);
      else atomicAdd(&zc, 1);
      int nb = len < DPAR ? len : DPAR;
      for (int d = 1; d < nb; ++d) atomicAdd(&cnt[d], 1);
      if (len > DPAR){
        int c = atomicAdd(ntail, 1);
        chains[c*3+0] = b; chains[c*3+1] = start; chains[c*3+2] = len;
      }
      start = t;
    }
  }
  __syncthreads();
  if (tid == 0){
    int s = 0;
    for (int d = 0; d < DPAR; ++d){ off[d] = s; cur[d] = s; s += cnt[d]; }
    off[DPAR] = s;
    *znum = zc;
  }
  __syncthreads();
  start = 0;
  for (int t = 1; t <= TT; ++t){
    bool boundary = (t == TT) || (dones[t * BB + b] != 0);
    if (boundary){
      int len = t - start;
      if (start == 0 && dones[b] == 0){
        int pos = atomicAdd(&cur[0], 1);
        rowlist[pos] = (start << 7) | b;
      } else {
        int pos = atomicAdd(&zcur, 1);
        zlist[pos] = (start << 7) | b;
      }
      int nb = len < DPAR ? len : DPAR;
      for (int d = 1; d < nb; ++d){
        int pos = atomicAdd(&cur[d], 1);
        rowlist[pos] = ((start + d) << 7) | b;
      }
      start = t;
    }
  }
}

// ---- emb = relu(ws @ W_emb + b_emb): [16384x512]@[512->1024], f16 out ----
__global__ __launch_bounds__(256)
void k_emb(const f16* __restrict__ A, const f16* __restrict__ Bt,
           const float* __restrict__ bias, f16* __restrict__ outb){
  int w = threadIdx.x >> 6, lane = threadIdx.x & 63;
  int wm = w >> 1, wn = w & 1;
  int bid = blockIdx.x;                       // 1024 = 128 Mb x 8 Nb
  int vid = (bid & 7) * 128 + (bid >> 3);
  int Mb = (vid >> 3) * 128, Nb = (vid & 7) * 128;
  int la = lane & 15, lk = (lane >> 4) * 8;
  f32x4 acc[4][4] = {};
  const f16* Ap[4]; const f16* Bp[4];
  for (int i = 0; i < 4; ++i){
    Ap[i] = A + (size_t)(Mb + wm*64 + i*16 + la) * OBSD;
    Bp[i] = Bt + (size_t)(Nb + wn*64 + i*16 + la) * OBSD;
  }
  for (int k = 0; k < OBSD; k += 32){
    f16x8 af[4], bfr[4];
    for (int i = 0; i < 4; ++i){
      af[i]  = *reinterpret_cast<const f16x8*>(Ap[i] + k + lk);
      bfr[i] = *reinterpret_cast<const f16x8*>(Bp[i] + k + lk);
    }
    for (int mi = 0; mi < 4; ++mi)
      for (int ni = 0; ni < 4; ++ni)
        acc[mi][ni] = mfma16(af[mi], bfr[ni], acc[mi][ni]);
  }
  for (int mi = 0; mi < 4; ++mi) for (int ni = 0; ni < 4; ++ni){
    int col = Nb + wn*64 + ni*16 + la;
    float bb = bias[col];
    for (int i = 0; i < 4; ++i){
      int row = Mb + wm*64 + mi*16 + (lane >> 4)*4 + i;
      float v = acc[mi][ni][i] + bb;
      outb[(size_t)row * HID + col] = (f16)(v > 0.f ? v : 0.f);
    }
  }
}

// ---- xi = emb @ Wi + bi: m97 structure (global_load_lds, 128x128, BK=64) ----
// LDS: As 16KB + Bs 16KB, single-buffered, 2 barriers/K-step. Linear LDS dest,
// inverse-swizzled global source; XOR-swizzled ds_read_b128 (2-way = free).
__global__ __launch_bounds__(256)
void k_xi(const f16* __restrict__ A, const f16* __restrict__ Bt,
          const float* __restrict__ bias, f16* __restrict__ outb){
  __shared__ __attribute__((aligned(16))) char smem[32768];   // As[0:16K) Bs[16K:32K)
  int tid = threadIdx.x;
  int w = tid >> 6, lane = tid & 63;
  int wm = w >> 1, wn = w & 1;
  int bid = blockIdx.x;                       // 3072 = 128 Mb x 24 Nb
  int vid = (bid & 7) * 384 + (bid >> 3);
  int Mb = (vid / 24) * 128, Nb = (vid % 24) * 128;
  int la = lane & 15, lk = (lane >> 4) * 8;
  f32x4 acc[4][4] = {};
  // per-issue constants: physical byte P -> logical (row r, k-part c16)
  int pr[4], pc16[4];
  #pragma unroll
  for (int q = 0; q < 4; ++q){
    int P = (w*4 + q)*1024 + lane*16;
    int r = P >> 7;
    pr[q] = r;
    pc16[q] = ((P & 127) ^ ((r & 7) << 4)) >> 4;
  }
  for (int kt = 0; kt < 16; ++kt){
    __syncthreads();                          // prior MFMA reads done
    #pragma unroll
    for (int q = 0; q < 4; ++q){
      gload16(A  + (size_t)(Mb + pr[q])*HID  + kt*64 + pc16[q]*8,
              smem + (w*4 + q)*1024);
      gload16(Bt + (size_t)(Nb + pr[q])*2048 + kt*64 + pc16[q]*8,
              smem + 16384 + (w*4 + q)*1024);
    }
    __syncthreads();                          // staged data visible (vmcnt drained)
    #pragma unroll
    for (int kk = 0; kk < 64; kk += 32){
      f16x8 av[4], bv[4];
      #pragma unroll
      for (int m = 0; m < 4; ++m){
        int r = wm*64 + m*16 + la;
        av[m] = *reinterpret_cast<const f16x8*>(
            smem + r*128 + (((kk + lk)*2) ^ ((r & 7) << 4)));
      }
      #pragma unroll
      for (int n = 0; n < 4; ++n){
        int r = wn*64 + n*16 + la;
        bv[n] = *reinterpret_cast<const f16x8*>(
            smem + 16384 + r*128 + (((kk + lk)*2) ^ ((r & 7) << 4)));
      }
      #pragma unroll
      for (int m = 0; m < 4; ++m)
        #pragma unroll
        for (int n = 0; n < 4; ++n)
          acc[m][n] = mfma16(av[m], bv[n], acc[m][n]);
    }
  }
  for (int mi = 0; mi < 4; ++mi) for (int ni = 0; ni < 4; ++ni){
    int col = Nb + wn*64 + ni*16 + la;
    float bb = bias[col];
    for (int i = 0; i < 4; ++i){
      int row = Mb + wm*64 + mi*16 + (lane >> 4)*4 + i;
      outb[(size_t)row * 3072 + col] = (f16)(acc[mi][ni][i] + bb);
    }
  }
}

// ---- h-zero rows: h = (1-z)*n, straight from xi (no GEMM) ----
__global__ __launch_bounds__(256)
void k_h0(const int* __restrict__ znum, const int* __restrict__ zlist,
          const f16* __restrict__ xi, const float* __restrict__ bhn_p,
          f16* __restrict__ y, float* __restrict__ hout){
  int nz = *znum;
  int tid = threadIdx.x;
  for (int ridx = blockIdx.x; ridx < nz; ridx += gridDim.x){
    int tb = zlist[ridx];
    int t = tb >> 7, b = tb & 127;
    size_t rb = ((size_t)t*BB + b) * 3072;
    int c0 = tid * 4;
    f16x4 xr = *reinterpret_cast<const f16x4*>(xi + rb + c0);
    f16x4 xz = *reinterpret_cast<const f16x4*>(xi + rb + 1024 + c0);
    f16x4 xn = *reinterpret_cast<const f16x4*>(xi + rb + 2048 + c0);
    f16x4 o;
    #pragma unroll
    for (int u = 0; u < 4; ++u){
      float r = 1.f / (1.f + expf(-(float)xr[u]));
      float z = 1.f / (1.f + expf(-(float)xz[u]));
      float n = tanhf((float)xn[u] + r * bhn_p[c0 + u]);
      float h = (1.f - z) * n;
      o[u] = (f16)h;
      if (t == TT - 1) hout[(size_t)b*HID + c0 + u] = h;
    }
    *reinterpret_cast<f16x4*>(y + ((size_t)t*BB + b)*HID + c0) = o;
  }
}

// ---- depth-j GRU step: h_prev @ Wh, K=1024; gates from xi in epilogue ----
__global__ __launch_bounds__(512)
void k_depth(int j, const int* __restrict__ off, const int* __restrict__ rowlist,
             const f16* __restrict__ xi, const f16* __restrict__ bt2,
             const float* __restrict__ bhn_p, const float* __restrict__ hidden0,
             f16* __restrict__ y, float* __restrict__ hout){
  __shared__ __attribute__((aligned(16))) char smem[32768];   // 128 x 128 f16, swizzled
  const int base = off[j];
  const int count = off[j+1] - base;
  if (count <= 0) return;
  const int tid = threadIdx.x;
  const int lane = tid & 63;
  const int w = tid >> 6;                    // 8 waves
  const int wm = w >> 2, wn = w & 3;         // 2m x 4n
  const int nb = blockIdx.x & 15;
  const int st = blockIdx.x >> 4;            // 64 M-strides
  const int la = lane & 15, lk = (lane >> 4) * 8;
  const int hcolw = nb*64 + wn*16;           // wave's hcol base
  const f16* Bg0 = bt2 + (size_t)(          hcolw + la) * 2048 + 1024 + lk;
  const f16* Bg1 = bt2 + (size_t)(1024 +    hcolw + la) * 2048 + 1024 + lk;
  const f16* Bg2 = bt2 + (size_t)(2048 +    hcolw + la) * 2048 + 1024 + lk;
  const int ntiles = (count + 127) >> 7;

  for (int tile = st; tile < ntiles; tile += 64){
    const char* hptr[4]; int hmode[4]; int sq[4]; int dby[4];
    #pragma unroll
    for (int q = 0; q < 4; ++q){
      int idx = tid + q*512;
      int r = idx >> 4; sq[q] = idx & 15;
      dby[q] = (r*256 + sq[q]*16) ^ ((r & 7) << 4);
      int ridx = tile*128 + r;
      int tb = (ridx < count) ? rowlist[base + ridx] : -1;
      hmode[q] = 0; hptr[q] = nullptr;
      if (tb >= 0){
        int t = tb >> 7, b = tb & 127;
        if (j > 0){ hmode[q] = 1; hptr[q] = (const char*)(y + ((size_t)(t-1)*BB + b)*HID); }
        else      { hmode[q] = 2; hptr[q] = (const char*)(hidden0 + (size_t)b*HID); }
      }
    }
    auto loadch = [&](int ch, float4* dst){
      #pragma unroll
      for (int q = 0; q < 4; ++q){
        float4 v = {0.f, 0.f, 0.f, 0.f};
        if (hmode[q] == 1){
          v = *reinterpret_cast<const float4*>((const f16*)hptr[q] + ch*128 + sq[q]*8);
        } else if (hmode[q] == 2){
          const float* s = (const float*)hptr[q] + ch*128 + sq[q]*8;
          float4 a0 = *reinterpret_cast<const float4*>(s);
          float4 a1 = *reinterpret_cast<const float4*>(s + 4);
          f16 h8[8] = {(f16)a0.x,(f16)a0.y,(f16)a0.z,(f16)a0.w,
                       (f16)a1.x,(f16)a1.y,(f16)a1.z,(f16)a1.w};
          v = *reinterpret_cast<float4*>(h8);
        }
        dst[q] = v;
      }
    };
    f32x4 ar[4] = {}, az[4] = {}, ahn[4] = {};
    float4 hv[4];
    loadch(0, hv);
    #pragma unroll 1
    for (int ch = 0; ch < 8; ++ch){
      __syncthreads();
      #pragma unroll
      for (int q = 0; q < 4; ++q)
        *reinterpret_cast<float4*>(smem + dby[q]) = hv[q];
      float4 hv2[4];
      if (ch < 7) loadch(ch+1, hv2);
      __syncthreads();
      const int kbase = ch*128;
      #pragma unroll
      for (int kk = 0; kk < 128; kk += 32){
        f16x8 av[4];
        #pragma unroll
        for (int m = 0; m < 4; ++m){
          int r = wm*64 + m*16 + la;
          av[m] = *reinterpret_cast<const f16x8*>(
              smem + ((r*256 + (kk + lk)*2) ^ ((r & 7) << 4)));
        }
        f16x8 b0 = *reinterpret_cast<const f16x8*>(Bg0 + kbase + kk);
        f16x8 b1 = *reinterpret_cast<const f16x8*>(Bg1 + kbase + kk);
        f16x8 b2 = *reinterpret_cast<const f16x8*>(Bg2 + kbase + kk);
        #pragma unroll
        for (int m = 0; m < 4; ++m){
          ar[m]  = mfma16(av[m], b0, ar[m]);
          az[m]  = mfma16(av[m], b1, az[m]);
          ahn[m] = mfma16(av[m], b2, ahn[m]);
        }
      }
      #pragma unroll
      for (int q = 0; q < 4; ++q) hv[q] = hv2[q];
    }
    {
      int hcol = hcolw + la;
      float bh = bhn_p[hcol];
      #pragma unroll
      for (int m = 0; m < 4; ++m){
        #pragma unroll
        for (int i = 0; i < 4; ++i){
          int lr = wm*64 + m*16 + (lane >> 4)*4 + i;
          int ridx = tile*128 + lr;
          if (ridx >= count) continue;
          int tb = rowlist[base + ridx];
          int t = tb >> 7, b = tb & 127;
          size_t rb = ((size_t)t*BB + b)*3072 + hcol;
          float hold;
          if (j > 0) hold = (float)y[((size_t)(t-1)*BB + b)*HID + hcol];
          else       hold = hidden0[(size_t)b*HID + hcol];
          float r = 1.f / (1.f + expf(-((float)xi[rb]        + ar[m][i])));
          float z = 1.f / (1.f + expf(-((float)xi[rb + 1024] + az[m][i])));
          float n = tanhf((float)xi[rb + 2048] + r * (ahn[m][i] + bh));
          float hnew = (1.f - z) * n + z * hold;
          y[((size_t)t*BB + b)*HID + hcol] = (f16)hnew;
          if (t == TT - 1) hout[(size_t)b*HID + hcol] = hnew;
        }
      }
    }
  }
}

// ---- sequential tail for chains longer than DPAR (empty for this seed) ----
__global__ __launch_bounds__(256)
void k_tail(const int* __restrict__ ntail, const int* __restrict__ chains,
            const f16* __restrict__ xi, const f16* __restrict__ bt2,
            const float* __restrict__ bhn_p, f16* __restrict__ y,
            float* __restrict__ hout){
  int n = *ntail;
  __shared__ f16 hs[1024];
  int tid = threadIdx.x;
  for (int c = blockIdx.x; c < n; c += gridDim.x){
    int b = chains[c*3], t0 = chains[c*3+1], len = chains[c*3+2];
    for (int i = tid; i < 1024; i += 256)
      hs[i] = y[((size_t)(t0 + DPAR - 1)*BB + b)*HID + i];
    __syncthreads();
    for (int t = t0 + DPAR; t < t0 + len; ++t){
      float tmp[4];
      #pragma unroll
      for (int u = 0; u < 4; ++u){
        int col = tid*4 + u;
        float s_r = 0.f, s_z = 0.f, s_hn = 0.f;
        const f16* wr = bt2 + (size_t)col*2048 + 1024;
        const f16* wz = bt2 + (size_t)(1024+col)*2048 + 1024;
        const f16* wn = bt2 + (size_t)(2048+col)*2048 + 1024;
        for (int q = 0; q < 128; ++q){
          f16x8 hv = *reinterpret_cast<const f16x8*>(&hs[q*8]);
          f16x8 wrh = *reinterpret_cast<const f16x8*>(wr + q*8);
          f16x8 wzh = *reinterpret_cast<const f16x8*>(wz + q*8);
          f16x8 wnh = *reinterpret_cast<const f16x8*>(wn + q*8);
          #pragma unroll
          for (int e = 0; e < 8; ++e){
            float hh = (float)hv[e];
            s_r  += hh*(float)wrh[e];
            s_z  += hh*(float)wzh[e];
            s_hn += hh*(float)wnh[e];
          }
        }
        size_t rb = ((size_t)t*BB + b)*3072 + col;
        float r = 1.f / (1.f + expf(-((float)xi[rb] + s_r)));
        float z = 1.f / (1.f + expf(-((float)xi[rb + 1024] + s_z)));
        float nn = tanhf((float)xi[rb + 2048] + r * (s_hn + bhn_p[col]));
        float hold = (float)hs[col];
        float hnew = (1.f - z) * nn + z * hold;
        y[((size_t)t*BB + b)*HID + col] = (f16)hnew;
        if (t == TT - 1) hout[(size_t)b*HID + col] = hnew;
        tmp[u] = hnew;
      }
      __syncthreads();
      #pragma unroll
      for (int u = 0; u < 4; ++u) hs[tid*4 + u] = (f16)tmp[u];
      __syncthreads();
    }
    __syncthreads();
  }
}

// ---- critic fused with value partials: 128x128 tile, K=1024, f16 ----
__global__ __launch_bounds__(256)
void k_critic(const f16* __restrict__ Y, const f16* __restrict__ Bt,
              const float* __restrict__ b1, const float* __restrict__ W2,
              float* __restrict__ vpart){
  int w = threadIdx.x >> 6, lane = threadIdx.x & 63;
  int wm = w >> 1, wn = w & 1;
  int bid = blockIdx.x;
  int vid = (bid & 7) * 128 + (bid >> 3);
  int Mb = (vid >> 3) * 128, Nb = (vid & 7) * 128;
  int la = lane & 15, lk = (lane >> 4) * 8;
  f32x4 acc[4][4] = {};
  const f16* Ap[4]; const f16* Bp[4];
  for (int i = 0; i < 4; ++i){
    Ap[i] = Y  + (size_t)(Mb + wm*64 + i*16 + la) * HID;
    Bp[i] = Bt + (size_t)(Nb + wn*64 + i*16 + la) * HID;
  }
  #pragma unroll 2
  for (int k = 0; k < HID; k += 32){
    f16x8 af[4], bfr[4];
    for (int i = 0; i < 4; ++i){
      af[i]  = *reinterpret_cast<const f16x8*>(Ap[i] + k + lk);
      bfr[i] = *reinterpret_cast<const f16x8*>(Bp[i] + k + lk);
    }
    for (int mi = 0; mi < 4; ++mi)
      for (int ni = 0; ni < 4; ++ni)
        acc[mi][ni] = mfma16(af[mi], bfr[ni], acc[mi][ni]);
  }
  __shared__ float vs[2][64][2];
  float p[4][4];
  for (int mi = 0; mi < 4; ++mi) for (int i = 0; i < 4; ++i) p[mi][i] = 0.f;
  for (int ni = 0; ni < 4; ++ni){
    int col = Nb + wn*64 + ni*16 + la;
    float bb = b1[col], w2 = W2[col];
    for (int mi = 0; mi < 4; ++mi)
      for (int i = 0; i < 4; ++i){
        float c = acc[mi][ni][i] + bb;
        p[mi][i] += (c > 0.f ? c : 0.f) * w2;
      }
  }
  for (int mi = 0; mi < 4; ++mi) for (int i = 0; i < 4; ++i){
    float s = p[mi][i];
    s += __shfl_xor(s, 1); s += __shfl_xor(s, 2);
    s += __shfl_xor(s, 4); s += __shfl_xor(s, 8);
    p[mi][i] = s;
  }
  if (la == 0){
    int q = lane >> 4;
    for (int mi = 0; mi < 4; ++mi)
      for (int i = 0; i < 4; ++i)
        vs[wm][mi*16 + q*4 + i][wn] = p[mi][i];
  }
  __syncthreads();
  if (threadIdx.x < 128){
    int rw = threadIdx.x;
    float s = vs[rw >> 6][rw & 63][0] + vs[rw >> 6][rw & 63][1];
    vpart[(size_t)(Nb >> 7) * (TT*BB) + Mb + rw] = s;
  }
}

__global__ void k_vreduce(const float* __restrict__ vpart, const float* __restrict__ b2,
                          float* __restrict__ outv){
  int m = blockIdx.x * 256 + threadIdx.x;
  float s = b2[0];
  for (int nb = 0; nb < 8; ++nb) s += vpart[(size_t)nb * (TT*BB) + m];
  outv[m] = s;
}

extern "C" void kernel_launch(void* const* d_in, const int* in_sizes, int n_in,
                              void* d_out, int out_size, void* d_ws, size_t ws_size,
                              hipStream_t stream){
  const float* hidden = (const float*)d_in[0];
  const float* world  = (const float*)d_in[1];
  const int*   dones  = (const int*)d_in[2];
  const float* W_emb  = (const float*)d_in[3];
  const float* b_emb  = (const float*)d_in[4];
  const float* Wi     = (const float*)d_in[5];
  const float* bi     = (const float*)d_in[6];
  const float* Wh     = (const float*)d_in[7];
  const float* bhn    = (const float*)d_in[8];
  const float* W1     = (const float*)d_in[9];
  const float* b1     = (const float*)d_in[10];
  const float* W2     = (const float*)d_in[11];
  const float* b2     = (const float*)d_in[12];
  float* out = (float*)d_out;

  char* p = (char*)d_ws;
  auto alloc = [&](size_t bytes) -> char* {
    char* r = p; p += (bytes + 255) & ~(size_t)255; return r;
  };
  f16*   ws16   = (f16*)alloc((size_t)TT*BB*OBSD*2);     // 16 MB
  f16*   wembt  = (f16*)alloc((size_t)HID*OBSD*2);       // 1 MB
  f16*   emb16  = (f16*)alloc((size_t)TT*BB*HID*2);      // 33.5 MB
  f16*   bt2    = (f16*)alloc((size_t)3072*2048*2);      // 12.6 MB
  f16*   w1t    = (f16*)alloc((size_t)HID*HID*2);        // 2 MB
  f16*   xi16   = (f16*)alloc((size_t)TT*BB*3072*2);     // 100.7 MB
  f16*   ybuf   = (f16*)alloc((size_t)TT*BB*HID*2);      // 33.5 MB
  float* vpart  = (float*)alloc((size_t)8*TT*BB*4);      // 0.5 MB
  int*   off    = (int*)alloc((DPAR + 1) * 4);
  int*   rowlist= (int*)alloc((size_t)(TT*BB + 128)*4);
  int*   znum   = (int*)alloc(4);
  int*   zlist  = (int*)alloc((size_t)(TT*BB + 128)*4);
  int*   ntail  = (int*)alloc(4);
  int*   chains = (int*)alloc((size_t)1024*3*4);
  if ((size_t)(p - (char*)d_ws) > ws_size) return;

  // preps (+ segmentation, depends only on dones)
  k_ws_to_f16<<<(TT*BB*OBSD/4 + 255)/256, 256, 0, stream>>>(world, ws16, TT*BB*OBSD/4);
  k_prep_bt<<<dim3(OBSD/64, HID/64), 256, 0, stream>>>(W_emb, 1024, wembt, OBSD);
  k_prep_bt2<<<dim3(2048/64, 3072/64), 256, 0, stream>>>(Wi, Wh, bt2);
  k_prep_bt<<<dim3(HID/64, HID/64), 256, 0, stream>>>(W1, 1024, w1t, HID);
  k_seg<<<1, 128, 0, stream>>>(dones, off, rowlist, znum, zlist, ntail, chains);

  // parallel GEMMs
  k_emb<<<1024, 256, 0, stream>>>(ws16, wembt, b_emb, emb16);
  k_xi<<<3072, 256, 0, stream>>>(emb16, bt2, bi, xi16);

  // h-zero rows (no GEMM) + depth-parallel GRU scan + tail
  k_h0<<<2048, 256, 0, stream>>>(znum, zlist, xi16, bhn, ybuf, out);
  for (int j = 0; j < DPAR; ++j)
    k_depth<<<1024, 512, 0, stream>>>(j, off, rowlist, xi16, bt2, bhn,
                                      hidden, ybuf, out);
  k_tail<<<128, 256, 0, stream>>>(ntail, chains, xi16, bt2, bhn, ybuf, out);

  // critic head + value
  k_critic<<<1024, 256, 0, stream>>>(ybuf, w1t, b1, W2, vpart);
  k_vreduce<<<TT*BB/256, 256, 0, stream>>>(vpart, b2, out + (size_t)BB*HID);
}

// Round 16
// 1259.158 us; speedup vs baseline: 2.1633x; 1.0460x over previous
//
#include <hip/hip_runtime.h>
#include <stdint.h>

#define TT 128
#define BB 128
#define OBSD 512
#define HID 1024
#define DPAR 24

typedef _Float16 f16;
typedef _Float16 f16x8 __attribute__((ext_vector_type(8)));
typedef _Float16 f16x4 __attribute__((ext_vector_type(4)));
typedef float f32x4 __attribute__((ext_vector_type(4)));

__device__ __forceinline__ f32x4 mfma16(f16x8 a, f16x8 b, f32x4 c){
  return __builtin_amdgcn_mfma_f32_16x16x32_f16(a, b, c, 0, 0, 0);
}
__device__ __forceinline__ void gload16(const void* g, void* l){
  __builtin_amdgcn_global_load_lds(
      (const __attribute__((address_space(1))) unsigned int*)g,
      (__attribute__((address_space(3))) unsigned int*)l, 16, 0, 0);
}

// ---- prep: world_state f32 -> f16 ----
__global__ void k_ws_to_f16(const float* __restrict__ src, f16* __restrict__ dst, int n4){
  int i = blockIdx.x * blockDim.x + threadIdx.x;
  if (i < n4){
    float4 v = *reinterpret_cast<const float4*>(src + (size_t)i * 4);
    dst[(size_t)i*4 + 0] = (f16)v.x; dst[(size_t)i*4 + 1] = (f16)v.y;
    dst[(size_t)i*4 + 2] = (f16)v.z; dst[(size_t)i*4 + 3] = (f16)v.w;
  }
}

// ---- prep: transpose f32 [KD][C] (row stride srcStride) -> f16 dst[C][KD] ----
__global__ void k_prep_bt(const float* __restrict__ s0, int srcStride,
                          f16* __restrict__ dst, int KD){
  __shared__ f16 sm[64][65];
  int k0 = blockIdx.x * 64, c0 = blockIdx.y * 64;
  for (int it = 0; it < 16; ++it){
    int idx = it * 256 + threadIdx.x;
    int kr = idx >> 6, cc = idx & 63;
    sm[kr][cc] = (f16)s0[(size_t)(k0 + kr) * srcStride + (c0 + cc)];
  }
  __syncthreads();
  for (int it = 0; it < 16; ++it){
    int idx = it * 256 + threadIdx.x;
    int cr = idx >> 6, kc = idx & 63;
    dst[(size_t)(c0 + cr) * KD + (k0 + kc)] = sm[kc][cr];
  }
}

// ---- prep: bt2[c][k] = k<1024 ? Wi[k][c] : Wh[k-1024][c]; c<3072, k<2048 ----
__global__ void k_prep_bt2(const float* __restrict__ wi, const float* __restrict__ wh,
                           f16* __restrict__ dst){
  __shared__ f16 sm[64][65];
  int k0 = blockIdx.x * 64, c0 = blockIdx.y * 64;
  const float* src = (k0 < 1024) ? wi : wh;
  int kb = (k0 < 1024) ? k0 : k0 - 1024;
  for (int it = 0; it < 16; ++it){
    int idx = it * 256 + threadIdx.x;
    int kr = idx >> 6, cc = idx & 63;
    sm[kr][cc] = (f16)src[(size_t)(kb + kr) * 3072 + (c0 + cc)];
  }
  __syncthreads();
  for (int it = 0; it < 16; ++it){
    int idx = it * 256 + threadIdx.x;
    int cr = idx >> 6, kc = idx & 63;
    dst[(size_t)(c0 + cr) * 2048 + (k0 + kc)] = sm[kc][cr];
  }
}

// ---- segmentation v2: atomic-free (per-thread private histograms + scan) ----
// buckets 0..DPAR-1 -> rowlist; bucket 24 -> zlist (h==0 rows, no GEMM).
__global__ void k_seg(const int* __restrict__ dones, int* __restrict__ off,
                      int* __restrict__ rowlist, int* __restrict__ znum,
                      int* __restrict__ zlist, int* __restrict__ ntail,
                      int* __restrict__ chains){
  __shared__ int lhist[128][25];
  __shared__ int lbase[128][25];
  __shared__ int tot[25];
  __shared__ int soff[25];
  int tid = threadIdx.x;               // 128 threads, one per b
  for (int d = 0; d < 25; ++d) lhist[tid][d] = 0;
  if (tid == 0) *ntail = 0;
  __syncthreads();
  int b = tid;
  int start = 0;
  for (int t = 1; t <= TT; ++t){
    bool boundary = (t == TT) || (dones[t * BB + b] != 0);
    if (boundary){
      int len = t - start;
      if (start == 0 && dones[b] == 0) lhist[tid][0]++;
      else lhist[tid][24]++;
      int nb = len < DPAR ? len : DPAR;
      for (int d = 1; d < nb; ++d) lhist[tid][d]++;
      if (len > DPAR){
        int c = atomicAdd(ntail, 1);             // rare; uncontended
        chains[c*3+0] = b; chains[c*3+1] = start; chains[c*3+2] = len;
      }
      start = t;
    }
  }
  __syncthreads();
  if (tid < 25){                       // per-bucket exclusive prefix over threads
    int s = 0;
    for (int i = 0; i < 128; ++i){ lbase[i][tid] = s; s += lhist[i][tid]; }
    tot[tid] = s;
  }
  __syncthreads();
  if (tid == 0){
    int s = 0;
    for (int d = 0; d < DPAR; ++d){ soff[d] = s; off[d] = s; s += tot[d]; }
    off[DPAR] = s;
    soff[24] = 0;                      // zlist is its own array
    *znum = tot[24];
  }
  __syncthreads();
  start = 0;
  for (int t = 1; t <= TT; ++t){
    bool boundary = (t == TT) || (dones[t * BB + b] != 0);
    if (boundary){
      int len = t - start;
      if (start == 0 && dones[b] == 0){
        rowlist[soff[0] + lbase[tid][0]++] = (start << 7) | b;
      } else {
        zlist[lbase[tid][24]++] = (start << 7) | b;
      }
      int nb = len < DPAR ? len : DPAR;
      for (int d = 1; d < nb; ++d)
        rowlist[soff[d] + lbase[tid][d]++] = ((start + d) << 7) | b;
      start = t;
    }
  }
}

// ---- emb = relu(ws @ W_emb + b_emb): [16384x512]@[512->1024], f16 out ----
__global__ __launch_bounds__(256)
void k_emb(const f16* __restrict__ A, const f16* __restrict__ Bt,
           const float* __restrict__ bias, f16* __restrict__ outb){
  int w = threadIdx.x >> 6, lane = threadIdx.x & 63;
  int wm = w >> 1, wn = w & 1;
  int bid = blockIdx.x;                       // 1024 = 128 Mb x 8 Nb
  int vid = (bid & 7) * 128 + (bid >> 3);
  int Mb = (vid >> 3) * 128, Nb = (vid & 7) * 128;
  int la = lane & 15, lk = (lane >> 4) * 8;
  f32x4 acc[4][4] = {};
  const f16* Ap[4]; const f16* Bp[4];
  for (int i = 0; i < 4; ++i){
    Ap[i] = A + (size_t)(Mb + wm*64 + i*16 + la) * OBSD;
    Bp[i] = Bt + (size_t)(Nb + wn*64 + i*16 + la) * OBSD;
  }
  for (int k = 0; k < OBSD; k += 32){
    f16x8 af[4], bfr[4];
    for (int i = 0; i < 4; ++i){
      af[i]  = *reinterpret_cast<const f16x8*>(Ap[i] + k + lk);
      bfr[i] = *reinterpret_cast<const f16x8*>(Bp[i] + k + lk);
    }
    for (int mi = 0; mi < 4; ++mi)
      for (int ni = 0; ni < 4; ++ni)
        acc[mi][ni] = mfma16(af[mi], bfr[ni], acc[mi][ni]);
  }
  for (int mi = 0; mi < 4; ++mi) for (int ni = 0; ni < 4; ++ni){
    int col = Nb + wn*64 + ni*16 + la;
    float bb = bias[col];
    for (int i = 0; i < 4; ++i){
      int row = Mb + wm*64 + mi*16 + (lane >> 4)*4 + i;
      float v = acc[mi][ni][i] + bb;
      outb[(size_t)row * HID + col] = (f16)(v > 0.f ? v : 0.f);
    }
  }
}

// ---- xi = emb @ Wi + bi: m97 structure (global_load_lds, 128x128, BK=64) ----
__global__ __launch_bounds__(256)
void k_xi(const f16* __restrict__ A, const f16* __restrict__ Bt,
          const float* __restrict__ bias, f16* __restrict__ outb){
  __shared__ __attribute__((aligned(16))) char smem[32768];   // As[0:16K) Bs[16K:32K)
  int tid = threadIdx.x;
  int w = tid >> 6, lane = tid & 63;
  int wm = w >> 1, wn = w & 1;
  int bid = blockIdx.x;                       // 3072 = 128 Mb x 24 Nb
  int vid = (bid & 7) * 384 + (bid >> 3);
  int Mb = (vid / 24) * 128, Nb = (vid % 24) * 128;
  int la = lane & 15, lk = (lane >> 4) * 8;
  f32x4 acc[4][4] = {};
  int pr[4], pc16[4];
  #pragma unroll
  for (int q = 0; q < 4; ++q){
    int P = (w*4 + q)*1024 + lane*16;
    int r = P >> 7;
    pr[q] = r;
    pc16[q] = ((P & 127) ^ ((r & 7) << 4)) >> 4;
  }
  for (int kt = 0; kt < 16; ++kt){
    __syncthreads();
    #pragma unroll
    for (int q = 0; q < 4; ++q){
      gload16(A  + (size_t)(Mb + pr[q])*HID  + kt*64 + pc16[q]*8,
              smem + (w*4 + q)*1024);
      gload16(Bt + (size_t)(Nb + pr[q])*2048 + kt*64 + pc16[q]*8,
              smem + 16384 + (w*4 + q)*1024);
    }
    __syncthreads();
    #pragma unroll
    for (int kk = 0; kk < 64; kk += 32){
      f16x8 av[4], bv[4];
      #pragma unroll
      for (int m = 0; m < 4; ++m){
        int r = wm*64 + m*16 + la;
        av[m] = *reinterpret_cast<const f16x8*>(
            smem + r*128 + (((kk + lk)*2) ^ ((r & 7) << 4)));
      }
      #pragma unroll
      for (int n = 0; n < 4; ++n){
        int r = wn*64 + n*16 + la;
        bv[n] = *reinterpret_cast<const f16x8*>(
            smem + 16384 + r*128 + (((kk + lk)*2) ^ ((r & 7) << 4)));
      }
      #pragma unroll
      for (int m = 0; m < 4; ++m)
        #pragma unroll
        for (int n = 0; n < 4; ++n)
          acc[m][n] = mfma16(av[m], bv[n], acc[m][n]);
    }
  }
  for (int mi = 0; mi < 4; ++mi) for (int ni = 0; ni < 4; ++ni){
    int col = Nb + wn*64 + ni*16 + la;
    float bb = bias[col];
    for (int i = 0; i < 4; ++i){
      int row = Mb + wm*64 + mi*16 + (lane >> 4)*4 + i;
      outb[(size_t)row * 3072 + col] = (f16)(acc[mi][ni][i] + bb);
    }
  }
}

// ---- h-zero rows: h = (1-z)*n, straight from xi (no GEMM) ----
__global__ __launch_bounds__(256)
void k_h0(const int* __restrict__ znum, const int* __restrict__ zlist,
          const f16* __restrict__ xi, const float* __restrict__ bhn_p,
          f16* __restrict__ y, float* __restrict__ hout){
  int nz = *znum;
  int tid = threadIdx.x;
  for (int ridx = blockIdx.x; ridx < nz; ridx += gridDim.x){
    int tb = zlist[ridx];
    int t = tb >> 7, b = tb & 127;
    size_t rb = ((size_t)t*BB + b) * 3072;
    int c0 = tid * 4;
    f16x4 xr = *reinterpret_cast<const f16x4*>(xi + rb + c0);
    f16x4 xz = *reinterpret_cast<const f16x4*>(xi + rb + 1024 + c0);
    f16x4 xn = *reinterpret_cast<const f16x4*>(xi + rb + 2048 + c0);
    f16x4 o;
    #pragma unroll
    for (int u = 0; u < 4; ++u){
      float r = 1.f / (1.f + expf(-(float)xr[u]));
      float z = 1.f / (1.f + expf(-(float)xz[u]));
      float n = tanhf((float)xn[u] + r * bhn_p[c0 + u]);
      float h = (1.f - z) * n;
      o[u] = (f16)h;
      if (t == TT - 1) hout[(size_t)b*HID + c0 + u] = h;
    }
    *reinterpret_cast<f16x4*>(y + ((size_t)t*BB + b)*HID + c0) = o;
  }
}

// ---- depth-j GRU step: h_prev @ Wh, K=1024; gates from xi in epilogue ----
__global__ __launch_bounds__(512)
void k_depth(int j, const int* __restrict__ off, const int* __restrict__ rowlist,
             const f16* __restrict__ xi, const f16* __restrict__ bt2,
             const float* __restrict__ bhn_p, const float* __restrict__ hidden0,
             f16* __restrict__ y, float* __restrict__ hout){
  __shared__ __attribute__((aligned(16))) char smem[32768];   // 128 x 128 f16, swizzled
  const int base = off[j];
  const int count = off[j+1] - base;
  if (count <= 0) return;
  const int tid = threadIdx.x;
  const int lane = tid & 63;
  const int w = tid >> 6;                    // 8 waves
  const int wm = w >> 2, wn = w & 3;         // 2m x 4n
  const int nb = blockIdx.x & 15;
  const int st = blockIdx.x >> 4;            // 64 M-strides
  const int la = lane & 15, lk = (lane >> 4) * 8;
  const int hcolw = nb*64 + wn*16;           // wave's hcol base
  const f16* Bg0 = bt2 + (size_t)(          hcolw + la) * 2048 + 1024 + lk;
  const f16* Bg1 = bt2 + (size_t)(1024 +    hcolw + la) * 2048 + 1024 + lk;
  const f16* Bg2 = bt2 + (size_t)(2048 +    hcolw + la) * 2048 + 1024 + lk;
  const int ntiles = (count + 127) >> 7;

  for (int tile = st; tile < ntiles; tile += 64){
    const char* hptr[4]; int hmode[4]; int sq[4]; int dby[4];
    #pragma unroll
    for (int q = 0; q < 4; ++q){
      int idx = tid + q*512;
      int r = idx >> 4; sq[q] = idx & 15;
      dby[q] = (r*256 + sq[q]*16) ^ ((r & 7) << 4);
      int ridx = tile*128 + r;
      int tb = (ridx < count) ? rowlist[base + ridx] : -1;
      hmode[q] = 0; hptr[q] = nullptr;
      if (tb >= 0){
        int t = tb >> 7, b = tb & 127;
        if (j > 0){ hmode[q] = 1; hptr[q] = (const char*)(y + ((size_t)(t-1)*BB + b)*HID); }
        else      { hmode[q] = 2; hptr[q] = (const char*)(hidden0 + (size_t)b*HID); }
      }
    }
    auto loadch = [&](int ch, float4* dst){
      #pragma unroll
      for (int q = 0; q < 4; ++q){
        float4 v = {0.f, 0.f, 0.f, 0.f};
        if (hmode[q] == 1){
          v = *reinterpret_cast<const float4*>((const f16*)hptr[q] + ch*128 + sq[q]*8);
        } else if (hmode[q] == 2){
          const float* s = (const float*)hptr[q] + ch*128 + sq[q]*8;
          float4 a0 = *reinterpret_cast<const float4*>(s);
          float4 a1 = *reinterpret_cast<const float4*>(s + 4);
          f16 h8[8] = {(f16)a0.x,(f16)a0.y,(f16)a0.z,(f16)a0.w,
                       (f16)a1.x,(f16)a1.y,(f16)a1.z,(f16)a1.w};
          v = *reinterpret_cast<float4*>(h8);
        }
        dst[q] = v;
      }
    };
    f32x4 ar[4] = {}, az[4] = {}, ahn[4] = {};
    float4 hv[4];
    loadch(0, hv);
    #pragma unroll 1
    for (int ch = 0; ch < 8; ++ch){
      __syncthreads();
      #pragma unroll
      for (int q = 0; q < 4; ++q)
        *reinterpret_cast<float4*>(smem + dby[q]) = hv[q];
      float4 hv2[4];
      if (ch < 7) loadch(ch+1, hv2);
      __syncthreads();
      const int kbase = ch*128;
      #pragma unroll
      for (int kk = 0; kk < 128; kk += 32){
        f16x8 av[4];
        #pragma unroll
        for (int m = 0; m < 4; ++m){
          int r = wm*64 + m*16 + la;
          av[m] = *reinterpret_cast<const f16x8*>(
              smem + ((r*256 + (kk + lk)*2) ^ ((r & 7) << 4)));
        }
        f16x8 b0 = *reinterpret_cast<const f16x8*>(Bg0 + kbase + kk);
        f16x8 b1 = *reinterpret_cast<const f16x8*>(Bg1 + kbase + kk);
        f16x8 b2 = *reinterpret_cast<const f16x8*>(Bg2 + kbase + kk);
        #pragma unroll
        for (int m = 0; m < 4; ++m){
          ar[m]  = mfma16(av[m], b0, ar[m]);
          az[m]  = mfma16(av[m], b1, az[m]);
          ahn[m] = mfma16(av[m], b2, ahn[m]);
        }
      }
      #pragma unroll
      for (int q = 0; q < 4; ++q) hv[q] = hv2[q];
    }
    {
      int hcol = hcolw + la;
      float bh = bhn_p[hcol];
      #pragma unroll
      for (int m = 0; m < 4; ++m){
        #pragma unroll
        for (int i = 0; i < 4; ++i){
          int lr = wm*64 + m*16 + (lane >> 4)*4 + i;
          int ridx = tile*128 + lr;
          if (ridx >= count) continue;
          int tb = rowlist[base + ridx];
          int t = tb >> 7, b = tb & 127;
          size_t rb = ((size_t)t*BB + b)*3072 + hcol;
          float hold;
          if (j > 0) hold = (float)y[((size_t)(t-1)*BB + b)*HID + hcol];
          else       hold = hidden0[(size_t)b*HID + hcol];
          float r = 1.f / (1.f + expf(-((float)xi[rb]        + ar[m][i])));
          float z = 1.f / (1.f + expf(-((float)xi[rb + 1024] + az[m][i])));
          float n = tanhf((float)xi[rb + 2048] + r * (ahn[m][i] + bh));
          float hnew = (1.f - z) * n + z * hold;
          y[((size_t)t*BB + b)*HID + hcol] = (f16)hnew;
          if (t == TT - 1) hout[(size_t)b*HID + hcol] = hnew;
        }
      }
    }
  }
}

// ---- sequential tail for chains longer than DPAR (empty for this seed) ----
__global__ __launch_bounds__(256)
void k_tail(const int* __restrict__ ntail, const int* __restrict__ chains,
            const f16* __restrict__ xi, const f16* __restrict__ bt2,
            const float* __restrict__ bhn_p, f16* __restrict__ y,
            float* __restrict__ hout){
  int n = *ntail;
  __shared__ f16 hs[1024];
  int tid = threadIdx.x;
  for (int c = blockIdx.x; c < n; c += gridDim.x){
    int b = chains[c*3], t0 = chains[c*3+1], len = chains[c*3+2];
    for (int i = tid; i < 1024; i += 256)
      hs[i] = y[((size_t)(t0 + DPAR - 1)*BB + b)*HID + i];
    __syncthreads();
    for (int t = t0 + DPAR; t < t0 + len; ++t){
      float tmp[4];
      #pragma unroll
      for (int u = 0; u < 4; ++u){
        int col = tid*4 + u;
        float s_r = 0.f, s_z = 0.f, s_hn = 0.f;
        const f16* wr = bt2 + (size_t)col*2048 + 1024;
        const f16* wz = bt2 + (size_t)(1024+col)*2048 + 1024;
        const f16* wn = bt2 + (size_t)(2048+col)*2048 + 1024;
        for (int q = 0; q < 128; ++q){
          f16x8 hv = *reinterpret_cast<const f16x8*>(&hs[q*8]);
          f16x8 wrh = *reinterpret_cast<const f16x8*>(wr + q*8);
          f16x8 wzh = *reinterpret_cast<const f16x8*>(wz + q*8);
          f16x8 wnh = *reinterpret_cast<const f16x8*>(wn + q*8);
          #pragma unroll
          for (int e = 0; e < 8; ++e){
            float hh = (float)hv[e];
            s_r  += hh*(float)wrh[e];
            s_z  += hh*(float)wzh[e];
            s_hn += hh*(float)wnh[e];
          }
        }
        size_t rb = ((size_t)t*BB + b)*3072 + col;
        float r = 1.f / (1.f + expf(-((float)xi[rb] + s_r)));
        float z = 1.f / (1.f + expf(-((float)xi[rb + 1024] + s_z)));
        float nn = tanhf((float)xi[rb + 2048] + r * (s_hn + bhn_p[col]));
        float hold = (float)hs[col];
        float hnew = (1.f - z) * nn + z * hold;
        y[((size_t)t*BB + b)*HID + col] = (f16)hnew;
        if (t == TT - 1) hout[(size_t)b*HID + col] = hnew;
        tmp[u] = hnew;
      }
      __syncthreads();
      #pragma unroll
      for (int u = 0; u < 4; ++u) hs[tid*4 + u] = (f16)tmp[u];
      __syncthreads();
    }
    __syncthreads();
  }
}

// ---- critic: m97 structure (global_load_lds, 128x128, BK=64) + value fusion ----
__global__ __launch_bounds__(256)
void k_critic(const f16* __restrict__ Y, const f16* __restrict__ Bt,
              const float* __restrict__ b1, const float* __restrict__ W2,
              float* __restrict__ vpart){
  __shared__ __attribute__((aligned(16))) char smem[32768];   // As[0:16K) Bs[16K:32K)
  int tid = threadIdx.x;
  int w = tid >> 6, lane = tid & 63;
  int wm = w >> 1, wn = w & 1;
  int bid = blockIdx.x;
  int vid = (bid & 7) * 128 + (bid >> 3);
  int Mb = (vid >> 3) * 128, Nb = (vid & 7) * 128;
  int la = lane & 15, lk = (lane >> 4) * 8;
  f32x4 acc[4][4] = {};
  int pr[4], pc16[4];
  #pragma unroll
  for (int q = 0; q < 4; ++q){
    int P = (w*4 + q)*1024 + lane*16;
    int r = P >> 7;
    pr[q] = r;
    pc16[q] = ((P & 127) ^ ((r & 7) << 4)) >> 4;
  }
  for (int kt = 0; kt < 16; ++kt){
    __syncthreads();
    #pragma unroll
    for (int q = 0; q < 4; ++q){
      gload16(Y  + (size_t)(Mb + pr[q])*HID + kt*64 + pc16[q]*8,
              smem + (w*4 + q)*1024);
      gload16(Bt + (size_t)(Nb + pr[q])*HID + kt*64 + pc16[q]*8,
              smem + 16384 + (w*4 + q)*1024);
    }
    __syncthreads();
    #pragma unroll
    for (int kk = 0; kk < 64; kk += 32){
      f16x8 av[4], bv[4];
      #pragma unroll
      for (int m = 0; m < 4; ++m){
        int r = wm*64 + m*16 + la;
        av[m] = *reinterpret_cast<const f16x8*>(
            smem + r*128 + (((kk + lk)*2) ^ ((r & 7) << 4)));
      }
      #pragma unroll
      for (int n = 0; n < 4; ++n){
        int r = wn*64 + n*16 + la;
        bv[n] = *reinterpret_cast<const f16x8*>(
            smem + 16384 + r*128 + (((kk + lk)*2) ^ ((r & 7) << 4)));
      }
      #pragma unroll
      for (int m = 0; m < 4; ++m)
        #pragma unroll
        for (int n = 0; n < 4; ++n)
          acc[m][n] = mfma16(av[m], bv[n], acc[m][n]);
    }
  }
  __syncthreads();                      // smem reads done before vs reuse below
  __shared__ float vs[2][64][2];
  float p[4][4];
  for (int mi = 0; mi < 4; ++mi) for (int i = 0; i < 4; ++i) p[mi][i] = 0.f;
  for (int ni = 0; ni < 4; ++ni){
    int col = Nb + wn*64 + ni*16 + la;
    float bb = b1[col], w2 = W2[col];
    for (int mi = 0; mi < 4; ++mi)
      for (int i = 0; i < 4; ++i){
        float c = acc[mi][ni][i] + bb;
        p[mi][i] += (c > 0.f ? c : 0.f) * w2;
      }
  }
  for (int mi = 0; mi < 4; ++mi) for (int i = 0; i < 4; ++i){
    float s = p[mi][i];
    s += __shfl_xor(s, 1); s += __shfl_xor(s, 2);
    s += __shfl_xor(s, 4); s += __shfl_xor(s, 8);
    p[mi][i] = s;
  }
  if (la == 0){
    int q = lane >> 4;
    for (int mi = 0; mi < 4; ++mi)
      for (int i = 0; i < 4; ++i)
        vs[wm][mi*16 + q*4 + i][wn] = p[mi][i];
  }
  __syncthreads();
  if (threadIdx.x < 128){
    int rw = threadIdx.x;
    float s = vs[rw >> 6][rw & 63][0] + vs[rw >> 6][rw & 63][1];
    vpart[(size_t)(Nb >> 7) * (TT*BB) + Mb + rw] = s;
  }
}

__global__ void k_vreduce(const float* __restrict__ vpart, const float* __restrict__ b2,
                          float* __restrict__ outv){
  int m = blockIdx.x * 256 + threadIdx.x;
  float s = b2[0];
  for (int nb = 0; nb < 8; ++nb) s += vpart[(size_t)nb * (TT*BB) + m];
  outv[m] = s;
}

extern "C" void kernel_launch(void* const* d_in, const int* in_sizes, int n_in,
                              void* d_out, int out_size, void* d_ws, size_t ws_size,
                              hipStream_t stream){
  const float* hidden = (const float*)d_in[0];
  const float* world  = (const float*)d_in[1];
  const int*   dones  = (const int*)d_in[2];
  const float* W_emb  = (const float*)d_in[3];
  const float* b_emb  = (const float*)d_in[4];
  const float* Wi     = (const float*)d_in[5];
  const float* bi     = (const float*)d_in[6];
  const float* Wh     = (const float*)d_in[7];
  const float* bhn    = (const float*)d_in[8];
  const float* W1     = (const float*)d_in[9];
  const float* b1     = (const float*)d_in[10];
  const float* W2     = (const float*)d_in[11];
  const float* b2     = (const float*)d_in[12];
  float* out = (float*)d_out;

  char* p = (char*)d_ws;
  auto alloc = [&](size_t bytes) -> char* {
    char* r = p; p += (bytes + 255) & ~(size_t)255; return r;
  };
  f16*   ws16   = (f16*)alloc((size_t)TT*BB*OBSD*2);     // 16 MB
  f16*   wembt  = (f16*)alloc((size_t)HID*OBSD*2);       // 1 MB
  f16*   emb16  = (f16*)alloc((size_t)TT*BB*HID*2);      // 33.5 MB
  f16*   bt2    = (f16*)alloc((size_t)3072*2048*2);      // 12.6 MB
  f16*   w1t    = (f16*)alloc((size_t)HID*HID*2);        // 2 MB
  f16*   xi16   = (f16*)alloc((size_t)TT*BB*3072*2);     // 100.7 MB
  f16*   ybuf   = (f16*)alloc((size_t)TT*BB*HID*2);      // 33.5 MB
  float* vpart  = (float*)alloc((size_t)8*TT*BB*4);      // 0.5 MB
  int*   off    = (int*)alloc((DPAR + 1) * 4);
  int*   rowlist= (int*)alloc((size_t)(TT*BB + 128)*4);
  int*   znum   = (int*)alloc(4);
  int*   zlist  = (int*)alloc((size_t)(TT*BB + 128)*4);
  int*   ntail  = (int*)alloc(4);
  int*   chains = (int*)alloc((size_t)1024*3*4);
  if ((size_t)(p - (char*)d_ws) > ws_size) return;

  // preps (+ segmentation, depends only on dones)
  k_ws_to_f16<<<(TT*BB*OBSD/4 + 255)/256, 256, 0, stream>>>(world, ws16, TT*BB*OBSD/4);
  k_prep_bt<<<dim3(OBSD/64, HID/64), 256, 0, stream>>>(W_emb, 1024, wembt, OBSD);
  k_prep_bt2<<<dim3(2048/64, 3072/64), 256, 0, stream>>>(Wi, Wh, bt2);
  k_prep_bt<<<dim3(HID/64, HID/64), 256, 0, stream>>>(W1, 1024, w1t, HID);
  k_seg<<<1, 128, 0, stream>>>(dones, off, rowlist, znum, zlist, ntail, chains);

  // parallel GEMMs
  k_emb<<<1024, 256, 0, stream>>>(ws16, wembt, b_emb, emb16);
  k_xi<<<3072, 256, 0, stream>>>(emb16, bt2, bi, xi16);

  // h-zero rows (no GEMM) + depth-parallel GRU scan + tail
  k_h0<<<2048, 256, 0, stream>>>(znum, zlist, xi16, bhn, ybuf, out);
  for (int j = 0; j < DPAR; ++j)
    k_depth<<<1024, 512, 0, stream>>>(j, off, rowlist, xi16, bt2, bhn,
                                      hidden, ybuf, out);
  k_tail<<<128, 256, 0, stream>>>(ntail, chains, xi16, bt2, bhn, ybuf, out);

  // critic head + value
  k_critic<<<1024, 256, 0, stream>>>(ybuf, w1t, b1, W2, vpart);
  k_vreduce<<<TT*BB/256, 256, 0, stream>>>(vpart, b2, out + (size_t)BB*HID);
}

// Round 17
// 1155.296 us; speedup vs baseline: 2.3578x; 1.0899x over previous
//
#include <hip/hip_runtime.h>
#include <stdint.h>

#define TT 128
#define BB 128
#define OBSD 512
#define HID 1024
#define DPAR 24

typedef _Float16 f16;
typedef _Float16 f16x8 __attribute__((ext_vector_type(8)));
typedef _Float16 f16x4 __attribute__((ext_vector_type(4)));
typedef float f32x4 __attribute__((ext_vector_type(4)));

__device__ __forceinline__ f32x4 mfma16(f16x8 a, f16x8 b, f32x4 c){
  return __builtin_amdgcn_mfma_f32_16x16x32_f16(a, b, c, 0, 0, 0);
}
__device__ __forceinline__ void gload16(const void* g, void* l){
  __builtin_amdgcn_global_load_lds(
      (const __attribute__((address_space(1))) unsigned int*)g,
      (__attribute__((address_space(3))) unsigned int*)l, 16, 0, 0);
}

// ---- prep: world_state f32 -> f16 ----
__global__ void k_ws_to_f16(const float* __restrict__ src, f16* __restrict__ dst, int n4){
  int i = blockIdx.x * blockDim.x + threadIdx.x;
  if (i < n4){
    float4 v = *reinterpret_cast<const float4*>(src + (size_t)i * 4);
    dst[(size_t)i*4 + 0] = (f16)v.x; dst[(size_t)i*4 + 1] = (f16)v.y;
    dst[(size_t)i*4 + 2] = (f16)v.z; dst[(size_t)i*4 + 3] = (f16)v.w;
  }
}

// ---- prep: transpose f32 [KD][C] (row stride srcStride) -> f16 dst[C][KD] ----
__global__ void k_prep_bt(const float* __restrict__ s0, int srcStride,
                          f16* __restrict__ dst, int KD){
  __shared__ f16 sm[64][65];
  int k0 = blockIdx.x * 64, c0 = blockIdx.y * 64;
  for (int it = 0; it < 16; ++it){
    int idx = it * 256 + threadIdx.x;
    int kr = idx >> 6, cc = idx & 63;
    sm[kr][cc] = (f16)s0[(size_t)(k0 + kr) * srcStride + (c0 + cc)];
  }
  __syncthreads();
  for (int it = 0; it < 16; ++it){
    int idx = it * 256 + threadIdx.x;
    int cr = idx >> 6, kc = idx & 63;
    dst[(size_t)(c0 + cr) * KD + (k0 + kc)] = sm[kc][cr];
  }
}

// ---- prep: bt2[c][k] = k<1024 ? Wi[k][c] : Wh[k-1024][c]; c<3072, k<2048 ----
__global__ void k_prep_bt2(const float* __restrict__ wi, const float* __restrict__ wh,
                           f16* __restrict__ dst){
  __shared__ f16 sm[64][65];
  int k0 = blockIdx.x * 64, c0 = blockIdx.y * 64;
  const float* src = (k0 < 1024) ? wi : wh;
  int kb = (k0 < 1024) ? k0 : k0 - 1024;
  for (int it = 0; it < 16; ++it){
    int idx = it * 256 + threadIdx.x;
    int kr = idx >> 6, cc = idx & 63;
    sm[kr][cc] = (f16)src[(size_t)(kb + kr) * 3072 + (c0 + cc)];
  }
  __syncthreads();
  for (int it = 0; it < 16; ++it){
    int idx = it * 256 + threadIdx.x;
    int cr = idx >> 6, kc = idx & 63;
    dst[(size_t)(c0 + cr) * 2048 + (k0 + kc)] = sm[kc][cr];
  }
}

// ---- segmentation v3: dones -> register bitmask first (pipelined loads),
// then both passes branch on registers. Atomic-free histograms. ----
__global__ void k_seg(const int* __restrict__ dones, int* __restrict__ off,
                      int* __restrict__ rowlist, int* __restrict__ znum,
                      int* __restrict__ zlist, int* __restrict__ ntail,
                      int* __restrict__ chains){
  __shared__ int lhist[128][25];
  __shared__ int lbase[128][25];
  __shared__ int tot[25];
  __shared__ int soff[25];
  int tid = threadIdx.x;               // 128 threads, one per b
  int b = tid;
  // prefetch dones column into 2x64-bit masks (independent loads, pipelined)
  unsigned long long m0 = 0, m1 = 0;
  #pragma unroll 16
  for (int t = 1; t < 64; ++t)
    m0 |= (unsigned long long)(dones[t*BB + b] != 0) << t;
  #pragma unroll 16
  for (int t = 64; t < 128; ++t)
    m1 |= (unsigned long long)(dones[t*BB + b] != 0) << (t - 64);
  const bool d0 = (dones[b] != 0);
  auto dn = [&](int t)->bool {
    return t < 64 ? ((m0 >> t) & 1ull) != 0 : ((m1 >> (t - 64)) & 1ull) != 0;
  };
  for (int d = 0; d < 25; ++d) lhist[tid][d] = 0;
  if (tid == 0) *ntail = 0;
  __syncthreads();
  int start = 0;
  for (int t = 1; t <= TT; ++t){
    bool boundary = (t == TT) || dn(t);
    if (boundary){
      int len = t - start;
      if (start == 0 && !d0) lhist[tid][0]++;
      else lhist[tid][24]++;
      int nb = len < DPAR ? len : DPAR;
      for (int d = 1; d < nb; ++d) lhist[tid][d]++;
      if (len > DPAR){
        int c = atomicAdd(ntail, 1);             // rare; uncontended
        chains[c*3+0] = b; chains[c*3+1] = start; chains[c*3+2] = len;
      }
      start = t;
    }
  }
  __syncthreads();
  if (tid < 25){                       // per-bucket exclusive prefix over threads
    int s = 0;
    for (int i = 0; i < 128; ++i){ lbase[i][tid] = s; s += lhist[i][tid]; }
    tot[tid] = s;
  }
  __syncthreads();
  if (tid == 0){
    int s = 0;
    for (int d = 0; d < DPAR; ++d){ soff[d] = s; off[d] = s; s += tot[d]; }
    off[DPAR] = s;
    soff[24] = 0;
    *znum = tot[24];
  }
  __syncthreads();
  start = 0;
  for (int t = 1; t <= TT; ++t){
    bool boundary = (t == TT) || dn(t);
    if (boundary){
      int len = t - start;
      if (start == 0 && !d0){
        rowlist[soff[0] + lbase[tid][0]++] = (start << 7) | b;
      } else {
        zlist[lbase[tid][24]++] = (start << 7) | b;
      }
      int nb = len < DPAR ? len : DPAR;
      for (int d = 1; d < nb; ++d)
        rowlist[soff[d] + lbase[tid][d]++] = ((start + d) << 7) | b;
      start = t;
    }
  }
}

// ---- emb = relu(ws @ W_emb + b_emb): m97 structure, K=512 (8 kt-steps) ----
__global__ __launch_bounds__(256)
void k_emb(const f16* __restrict__ A, const f16* __restrict__ Bt,
           const float* __restrict__ bias, f16* __restrict__ outb){
  __shared__ __attribute__((aligned(16))) char smem[32768];   // As[0:16K) Bs[16K:32K)
  int tid = threadIdx.x;
  int w = tid >> 6, lane = tid & 63;
  int wm = w >> 1, wn = w & 1;
  int bid = blockIdx.x;                       // 1024 = 128 Mb x 8 Nb
  int vid = (bid & 7) * 128 + (bid >> 3);
  int Mb = (vid >> 3) * 128, Nb = (vid & 7) * 128;
  int la = lane & 15, lk = (lane >> 4) * 8;
  f32x4 acc[4][4] = {};
  int pr[4], pc16[4];
  #pragma unroll
  for (int q = 0; q < 4; ++q){
    int P = (w*4 + q)*1024 + lane*16;
    int r = P >> 7;
    pr[q] = r;
    pc16[q] = ((P & 127) ^ ((r & 7) << 4)) >> 4;
  }
  for (int kt = 0; kt < 8; ++kt){
    __syncthreads();
    #pragma unroll
    for (int q = 0; q < 4; ++q){
      gload16(A  + (size_t)(Mb + pr[q])*OBSD + kt*64 + pc16[q]*8,
              smem + (w*4 + q)*1024);
      gload16(Bt + (size_t)(Nb + pr[q])*OBSD + kt*64 + pc16[q]*8,
              smem + 16384 + (w*4 + q)*1024);
    }
    __syncthreads();
    #pragma unroll
    for (int kk = 0; kk < 64; kk += 32){
      f16x8 av[4], bv[4];
      #pragma unroll
      for (int m = 0; m < 4; ++m){
        int r = wm*64 + m*16 + la;
        av[m] = *reinterpret_cast<const f16x8*>(
            smem + r*128 + (((kk + lk)*2) ^ ((r & 7) << 4)));
      }
      #pragma unroll
      for (int n = 0; n < 4; ++n){
        int r = wn*64 + n*16 + la;
        bv[n] = *reinterpret_cast<const f16x8*>(
            smem + 16384 + r*128 + (((kk + lk)*2) ^ ((r & 7) << 4)));
      }
      #pragma unroll
      for (int m = 0; m < 4; ++m)
        #pragma unroll
        for (int n = 0; n < 4; ++n)
          acc[m][n] = mfma16(av[m], bv[n], acc[m][n]);
    }
  }
  for (int mi = 0; mi < 4; ++mi) for (int ni = 0; ni < 4; ++ni){
    int col = Nb + wn*64 + ni*16 + la;
    float bb = bias[col];
    for (int i = 0; i < 4; ++i){
      int row = Mb + wm*64 + mi*16 + (lane >> 4)*4 + i;
      float v = acc[mi][ni][i] + bb;
      outb[(size_t)row * HID + col] = (f16)(v > 0.f ? v : 0.f);
    }
  }
}

// ---- xi = emb @ Wi + bi: m97 structure (global_load_lds, 128x128, BK=64) ----
__global__ __launch_bounds__(256)
void k_xi(const f16* __restrict__ A, const f16* __restrict__ Bt,
          const float* __restrict__ bias, f16* __restrict__ outb){
  __shared__ __attribute__((aligned(16))) char smem[32768];   // As[0:16K) Bs[16K:32K)
  int tid = threadIdx.x;
  int w = tid >> 6, lane = tid & 63;
  int wm = w >> 1, wn = w & 1;
  int bid = blockIdx.x;                       // 3072 = 128 Mb x 24 Nb
  int vid = (bid & 7) * 384 + (bid >> 3);
  int Mb = (vid / 24) * 128, Nb = (vid % 24) * 128;
  int la = lane & 15, lk = (lane >> 4) * 8;
  f32x4 acc[4][4] = {};
  int pr[4], pc16[4];
  #pragma unroll
  for (int q = 0; q < 4; ++q){
    int P = (w*4 + q)*1024 + lane*16;
    int r = P >> 7;
    pr[q] = r;
    pc16[q] = ((P & 127) ^ ((r & 7) << 4)) >> 4;
  }
  for (int kt = 0; kt < 16; ++kt){
    __syncthreads();
    #pragma unroll
    for (int q = 0; q < 4; ++q){
      gload16(A  + (size_t)(Mb + pr[q])*HID  + kt*64 + pc16[q]*8,
              smem + (w*4 + q)*1024);
      gload16(Bt + (size_t)(Nb + pr[q])*2048 + kt*64 + pc16[q]*8,
              smem + 16384 + (w*4 + q)*1024);
    }
    __syncthreads();
    #pragma unroll
    for (int kk = 0; kk < 64; kk += 32){
      f16x8 av[4], bv[4];
      #pragma unroll
      for (int m = 0; m < 4; ++m){
        int r = wm*64 + m*16 + la;
        av[m] = *reinterpret_cast<const f16x8*>(
            smem + r*128 + (((kk + lk)*2) ^ ((r & 7) << 4)));
      }
      #pragma unroll
      for (int n = 0; n < 4; ++n){
        int r = wn*64 + n*16 + la;
        bv[n] = *reinterpret_cast<const f16x8*>(
            smem + 16384 + r*128 + (((kk + lk)*2) ^ ((r & 7) << 4)));
      }
      #pragma unroll
      for (int m = 0; m < 4; ++m)
        #pragma unroll
        for (int n = 0; n < 4; ++n)
          acc[m][n] = mfma16(av[m], bv[n], acc[m][n]);
    }
  }
  for (int mi = 0; mi < 4; ++mi) for (int ni = 0; ni < 4; ++ni){
    int col = Nb + wn*64 + ni*16 + la;
    float bb = bias[col];
    for (int i = 0; i < 4; ++i){
      int row = Mb + wm*64 + mi*16 + (lane >> 4)*4 + i;
      outb[(size_t)row * 3072 + col] = (f16)(acc[mi][ni][i] + bb);
    }
  }
}

// ---- h-zero rows: h = (1-z)*n, straight from xi (no GEMM) ----
__global__ __launch_bounds__(256)
void k_h0(const int* __restrict__ znum, const int* __restrict__ zlist,
          const f16* __restrict__ xi, const float* __restrict__ bhn_p,
          f16* __restrict__ y, float* __restrict__ hout){
  int nz = *znum;
  int tid = threadIdx.x;
  for (int ridx = blockIdx.x; ridx < nz; ridx += gridDim.x){
    int tb = zlist[ridx];
    int t = tb >> 7, b = tb & 127;
    size_t rb = ((size_t)t*BB + b) * 3072;
    int c0 = tid * 4;
    f16x4 xr = *reinterpret_cast<const f16x4*>(xi + rb + c0);
    f16x4 xz = *reinterpret_cast<const f16x4*>(xi + rb + 1024 + c0);
    f16x4 xn = *reinterpret_cast<const f16x4*>(xi + rb + 2048 + c0);
    f16x4 o;
    #pragma unroll
    for (int u = 0; u < 4; ++u){
      float r = 1.f / (1.f + expf(-(float)xr[u]));
      float z = 1.f / (1.f + expf(-(float)xz[u]));
      float n = tanhf((float)xn[u] + r * bhn_p[c0 + u]);
      float h = (1.f - z) * n;
      o[u] = (f16)h;
      if (t == TT - 1) hout[(size_t)b*HID + c0 + u] = h;
    }
    *reinterpret_cast<f16x4*>(y + ((size_t)t*BB + b)*HID + c0) = o;
  }
}

// ---- depth-j GRU step: h_prev @ Wh, K=1024; gates from xi in epilogue ----
__global__ __launch_bounds__(512)
void k_depth(int j, const int* __restrict__ off, const int* __restrict__ rowlist,
             const f16* __restrict__ xi, const f16* __restrict__ bt2,
             const float* __restrict__ bhn_p, const float* __restrict__ hidden0,
             f16* __restrict__ y, float* __restrict__ hout){
  __shared__ __attribute__((aligned(16))) char smem[32768];   // 128 x 128 f16, swizzled
  const int base = off[j];
  const int count = off[j+1] - base;
  if (count <= 0) return;
  const int tid = threadIdx.x;
  const int lane = tid & 63;
  const int w = tid >> 6;                    // 8 waves
  const int wm = w >> 2, wn = w & 3;         // 2m x 4n
  const int nb = blockIdx.x & 15;
  const int st = blockIdx.x >> 4;            // 64 M-strides
  const int la = lane & 15, lk = (lane >> 4) * 8;
  const int hcolw = nb*64 + wn*16;           // wave's hcol base
  const f16* Bg0 = bt2 + (size_t)(          hcolw + la) * 2048 + 1024 + lk;
  const f16* Bg1 = bt2 + (size_t)(1024 +    hcolw + la) * 2048 + 1024 + lk;
  const f16* Bg2 = bt2 + (size_t)(2048 +    hcolw + la) * 2048 + 1024 + lk;
  const int ntiles = (count + 127) >> 7;

  for (int tile = st; tile < ntiles; tile += 64){
    const char* hptr[4]; int hmode[4]; int sq[4]; int dby[4];
    #pragma unroll
    for (int q = 0; q < 4; ++q){
      int idx = tid + q*512;
      int r = idx >> 4; sq[q] = idx & 15;
      dby[q] = (r*256 + sq[q]*16) ^ ((r & 7) << 4);
      int ridx = tile*128 + r;
      int tb = (ridx < count) ? rowlist[base + ridx] : -1;
      hmode[q] = 0; hptr[q] = nullptr;
      if (tb >= 0){
        int t = tb >> 7, b = tb & 127;
        if (j > 0){ hmode[q] = 1; hptr[q] = (const char*)(y + ((size_t)(t-1)*BB + b)*HID); }
        else      { hmode[q] = 2; hptr[q] = (const char*)(hidden0 + (size_t)b*HID); }
      }
    }
    auto loadch = [&](int ch, float4* dst){
      #pragma unroll
      for (int q = 0; q < 4; ++q){
        float4 v = {0.f, 0.f, 0.f, 0.f};
        if (hmode[q] == 1){
          v = *reinterpret_cast<const float4*>((const f16*)hptr[q] + ch*128 + sq[q]*8);
        } else if (hmode[q] == 2){
          const float* s = (const float*)hptr[q] + ch*128 + sq[q]*8;
          float4 a0 = *reinterpret_cast<const float4*>(s);
          float4 a1 = *reinterpret_cast<const float4*>(s + 4);
          f16 h8[8] = {(f16)a0.x,(f16)a0.y,(f16)a0.z,(f16)a0.w,
                       (f16)a1.x,(f16)a1.y,(f16)a1.z,(f16)a1.w};
          v = *reinterpret_cast<float4*>(h8);
        }
        dst[q] = v;
      }
    };
    f32x4 ar[4] = {}, az[4] = {}, ahn[4] = {};
    float4 hv[4];
    loadch(0, hv);
    #pragma unroll 1
    for (int ch = 0; ch < 8; ++ch){
      __syncthreads();
      #pragma unroll
      for (int q = 0; q < 4; ++q)
        *reinterpret_cast<float4*>(smem + dby[q]) = hv[q];
      float4 hv2[4];
      if (ch < 7) loadch(ch+1, hv2);
      __syncthreads();
      const int kbase = ch*128;
      #pragma unroll
      for (int kk = 0; kk < 128; kk += 32){
        f16x8 av[4];
        #pragma unroll
        for (int m = 0; m < 4; ++m){
          int r = wm*64 + m*16 + la;
          av[m] = *reinterpret_cast<const f16x8*>(
              smem + ((r*256 + (kk + lk)*2) ^ ((r & 7) << 4)));
        }
        f16x8 b0 = *reinterpret_cast<const f16x8*>(Bg0 + kbase + kk);
        f16x8 b1 = *reinterpret_cast<const f16x8*>(Bg1 + kbase + kk);
        f16x8 b2 = *reinterpret_cast<const f16x8*>(Bg2 + kbase + kk);
        #pragma unroll
        for (int m = 0; m < 4; ++m){
          ar[m]  = mfma16(av[m], b0, ar[m]);
          az[m]  = mfma16(av[m], b1, az[m]);
          ahn[m] = mfma16(av[m], b2, ahn[m]);
        }
      }
      #pragma unroll
      for (int q = 0; q < 4; ++q) hv[q] = hv2[q];
    }
    {
      int hcol = hcolw + la;
      float bh = bhn_p[hcol];
      #pragma unroll
      for (int m = 0; m < 4; ++m){
        #pragma unroll
        for (int i = 0; i < 4; ++i){
          int lr = wm*64 + m*16 + (lane >> 4)*4 + i;
          int ridx = tile*128 + lr;
          if (ridx >= count) continue;
          int tb = rowlist[base + ridx];
          int t = tb >> 7, b = tb & 127;
          size_t rb = ((size_t)t*BB + b)*3072 + hcol;
          float hold;
          if (j > 0) hold = (float)y[((size_t)(t-1)*BB + b)*HID + hcol];
          else       hold = hidden0[(size_t)b*HID + hcol];
          float r = 1.f / (1.f + expf(-((float)xi[rb]        + ar[m][i])));
          float z = 1.f / (1.f + expf(-((float)xi[rb + 1024] + az[m][i])));
          float n = tanhf((float)xi[rb + 2048] + r * (ahn[m][i] + bh));
          float hnew = (1.f - z) * n + z * hold;
          y[((size_t)t*BB + b)*HID + hcol] = (f16)hnew;
          if (t == TT - 1) hout[(size_t)b*HID + hcol] = hnew;
        }
      }
    }
  }
}

// ---- sequential tail for chains longer than DPAR (empty for this seed) ----
__global__ __launch_bounds__(256)
void k_tail(const int* __restrict__ ntail, const int* __restrict__ chains,
            const f16* __restrict__ xi, const f16* __restrict__ bt2,
            const float* __restrict__ bhn_p, f16* __restrict__ y,
            float* __restrict__ hout){
  int n = *ntail;
  __shared__ f16 hs[1024];
  int tid = threadIdx.x;
  for (int c = blockIdx.x; c < n; c += gridDim.x){
    int b = chains[c*3], t0 = chains[c*3+1], len = chains[c*3+2];
    for (int i = tid; i < 1024; i += 256)
      hs[i] = y[((size_t)(t0 + DPAR - 1)*BB + b)*HID + i];
    __syncthreads();
    for (int t = t0 + DPAR; t < t0 + len; ++t){
      float tmp[4];
      #pragma unroll
      for (int u = 0; u < 4; ++u){
        int col = tid*4 + u;
        float s_r = 0.f, s_z = 0.f, s_hn = 0.f;
        const f16* wr = bt2 + (size_t)col*2048 + 1024;
        const f16* wz = bt2 + (size_t)(1024+col)*2048 + 1024;
        const f16* wn = bt2 + (size_t)(2048+col)*2048 + 1024;
        for (int q = 0; q < 128; ++q){
          f16x8 hv = *reinterpret_cast<const f16x8*>(&hs[q*8]);
          f16x8 wrh = *reinterpret_cast<const f16x8*>(wr + q*8);
          f16x8 wzh = *reinterpret_cast<const f16x8*>(wz + q*8);
          f16x8 wnh = *reinterpret_cast<const f16x8*>(wn + q*8);
          #pragma unroll
          for (int e = 0; e < 8; ++e){
            float hh = (float)hv[e];
            s_r  += hh*(float)wrh[e];
            s_z  += hh*(float)wzh[e];
            s_hn += hh*(float)wnh[e];
          }
        }
        size_t rb = ((size_t)t*BB + b)*3072 + col;
        float r = 1.f / (1.f + expf(-((float)xi[rb] + s_r)));
        float z = 1.f / (1.f + expf(-((float)xi[rb + 1024] + s_z)));
        float nn = tanhf((float)xi[rb + 2048] + r * (s_hn + bhn_p[col]));
        float hold = (float)hs[col];
        float hnew = (1.f - z) * nn + z * hold;
        y[((size_t)t*BB + b)*HID + col] = (f16)hnew;
        if (t == TT - 1) hout[(size_t)b*HID + col] = hnew;
        tmp[u] = hnew;
      }
      __syncthreads();
      #pragma unroll
      for (int u = 0; u < 4; ++u) hs[tid*4 + u] = (f16)tmp[u];
      __syncthreads();
    }
    __syncthreads();
  }
}

// ---- critic: m97 structure (global_load_lds, 128x128, BK=64) + value fusion ----
__global__ __launch_bounds__(256)
void k_critic(const f16* __restrict__ Y, const f16* __restrict__ Bt,
              const float* __restrict__ b1, const float* __restrict__ W2,
              float* __restrict__ vpart){
  __shared__ __attribute__((aligned(16))) char smem[32768];   // As[0:16K) Bs[16K:32K)
  int tid = threadIdx.x;
  int w = tid >> 6, lane = tid & 63;
  int wm = w >> 1, wn = w & 1;
  int bid = blockIdx.x;
  int vid = (bid & 7) * 128 + (bid >> 3);
  int Mb = (vid >> 3) * 128, Nb = (vid & 7) * 128;
  int la = lane & 15, lk = (lane >> 4) * 8;
  f32x4 acc[4][4] = {};
  int pr[4], pc16[4];
  #pragma unroll
  for (int q = 0; q < 4; ++q){
    int P = (w*4 + q)*1024 + lane*16;
    int r = P >> 7;
    pr[q] = r;
    pc16[q] = ((P & 127) ^ ((r & 7) << 4)) >> 4;
  }
  for (int kt = 0; kt < 16; ++kt){
    __syncthreads();
    #pragma unroll
    for (int q = 0; q < 4; ++q){
      gload16(Y  + (size_t)(Mb + pr[q])*HID + kt*64 + pc16[q]*8,
              smem + (w*4 + q)*1024);
      gload16(Bt + (size_t)(Nb + pr[q])*HID + kt*64 + pc16[q]*8,
              smem + 16384 + (w*4 + q)*1024);
    }
    __syncthreads();
    #pragma unroll
    for (int kk = 0; kk < 64; kk += 32){
      f16x8 av[4], bv[4];
      #pragma unroll
      for (int m = 0; m < 4; ++m){
        int r = wm*64 + m*16 + la;
        av[m] = *reinterpret_cast<const f16x8*>(
            smem + r*128 + (((kk + lk)*2) ^ ((r & 7) << 4)));
      }
      #pragma unroll
      for (int n = 0; n < 4; ++n){
        int r = wn*64 + n*16 + la;
        bv[n] = *reinterpret_cast<const f16x8*>(
            smem + 16384 + r*128 + (((kk + lk)*2) ^ ((r & 7) << 4)));
      }
      #pragma unroll
      for (int m = 0; m < 4; ++m)
        #pragma unroll
        for (int n = 0; n < 4; ++n)
          acc[m][n] = mfma16(av[m], bv[n], acc[m][n]);
    }
  }
  __syncthreads();                      // smem reads done before vs reuse below
  __shared__ float vs[2][64][2];
  float p[4][4];
  for (int mi = 0; mi < 4; ++mi) for (int i = 0; i < 4; ++i) p[mi][i] = 0.f;
  for (int ni = 0; ni < 4; ++ni){
    int col = Nb + wn*64 + ni*16 + la;
    float bb = b1[col], w2 = W2[col];
    for (int mi = 0; mi < 4; ++mi)
      for (int i = 0; i < 4; ++i){
        float c = acc[mi][ni][i] + bb;
        p[mi][i] += (c > 0.f ? c : 0.f) * w2;
      }
  }
  for (int mi = 0; mi < 4; ++mi) for (int i = 0; i < 4; ++i){
    float s = p[mi][i];
    s += __shfl_xor(s, 1); s += __shfl_xor(s, 2);
    s += __shfl_xor(s, 4); s += __shfl_xor(s, 8);
    p[mi][i] = s;
  }
  if (la == 0){
    int q = lane >> 4;
    for (int mi = 0; mi < 4; ++mi)
      for (int i = 0; i < 4; ++i)
        vs[wm][mi*16 + q*4 + i][wn] = p[mi][i];
  }
  __syncthreads();
  if (threadIdx.x < 128){
    int rw = threadIdx.x;
    float s = vs[rw >> 6][rw & 63][0] + vs[rw >> 6][rw & 63][1];
    vpart[(size_t)(Nb >> 7) * (TT*BB) + Mb + rw] = s;
  }
}

__global__ void k_vreduce(const float* __restrict__ vpart, const float* __restrict__ b2,
                          float* __restrict__ outv){
  int m = blockIdx.x * 256 + threadIdx.x;
  float s = b2[0];
  for (int nb = 0; nb < 8; ++nb) s += vpart[(size_t)nb * (TT*BB) + m];
  outv[m] = s;
}

extern "C" void kernel_launch(void* const* d_in, const int* in_sizes, int n_in,
                              void* d_out, int out_size, void* d_ws, size_t ws_size,
                              hipStream_t stream){
  const float* hidden = (const float*)d_in[0];
  const float* world  = (const float*)d_in[1];
  const int*   dones  = (const int*)d_in[2];
  const float* W_emb  = (const float*)d_in[3];
  const float* b_emb  = (const float*)d_in[4];
  const float* Wi     = (const float*)d_in[5];
  const float* bi     = (const float*)d_in[6];
  const float* Wh     = (const float*)d_in[7];
  const float* bhn    = (const float*)d_in[8];
  const float* W1     = (const float*)d_in[9];
  const float* b1     = (const float*)d_in[10];
  const float* W2     = (const float*)d_in[11];
  const float* b2     = (const float*)d_in[12];
  float* out = (float*)d_out;

  char* p = (char*)d_ws;
  auto alloc = [&](size_t bytes) -> char* {
    char* r = p; p += (bytes + 255) & ~(size_t)255; return r;
  };
  f16*   ws16   = (f16*)alloc((size_t)TT*BB*OBSD*2);     // 16 MB
  f16*   wembt  = (f16*)alloc((size_t)HID*OBSD*2);       // 1 MB
  f16*   emb16  = (f16*)alloc((size_t)TT*BB*HID*2);      // 33.5 MB
  f16*   bt2    = (f16*)alloc((size_t)3072*2048*2);      // 12.6 MB
  f16*   w1t    = (f16*)alloc((size_t)HID*HID*2);        // 2 MB
  f16*   xi16   = (f16*)alloc((size_t)TT*BB*3072*2);     // 100.7 MB
  f16*   ybuf   = (f16*)alloc((size_t)TT*BB*HID*2);      // 33.5 MB
  float* vpart  = (float*)alloc((size_t)8*TT*BB*4);      // 0.5 MB
  int*   off    = (int*)alloc((DPAR + 1) * 4);
  int*   rowlist= (int*)alloc((size_t)(TT*BB + 128)*4);
  int*   znum   = (int*)alloc(4);
  int*   zlist  = (int*)alloc((size_t)(TT*BB + 128)*4);
  int*   ntail  = (int*)alloc(4);
  int*   chains = (int*)alloc((size_t)1024*3*4);
  if ((size_t)(p - (char*)d_ws) > ws_size) return;

  // preps (+ segmentation, depends only on dones)
  k_ws_to_f16<<<(TT*BB*OBSD/4 + 255)/256, 256, 0, stream>>>(world, ws16, TT*BB*OBSD/4);
  k_prep_bt<<<dim3(OBSD/64, HID/64), 256, 0, stream>>>(W_emb, 1024, wembt, OBSD);
  k_prep_bt2<<<dim3(2048/64, 3072/64), 256, 0, stream>>>(Wi, Wh, bt2);
  k_prep_bt<<<dim3(HID/64, HID/64), 256, 0, stream>>>(W1, 1024, w1t, HID);
  k_seg<<<1, 128, 0, stream>>>(dones, off, rowlist, znum, zlist, ntail, chains);

  // parallel GEMMs
  k_emb<<<1024, 256, 0, stream>>>(ws16, wembt, b_emb, emb16);
  k_xi<<<3072, 256, 0, stream>>>(emb16, bt2, bi, xi16);

  // h-zero rows (no GEMM) + depth-parallel GRU scan + tail
  k_h0<<<2048, 256, 0, stream>>>(znum, zlist, xi16, bhn, ybuf, out);
  for (int j = 0; j < DPAR; ++j)
    k_depth<<<1024, 512, 0, stream>>>(j, off, rowlist, xi16, bt2, bhn,
                                      hidden, ybuf, out);
  k_tail<<<128, 256, 0, stream>>>(ntail, chains, xi16, bt2, bhn, ybuf, out);

  // critic head + value
  k_critic<<<1024, 256, 0, stream>>>(ybuf, w1t, b1, W2, vpart);
  k_vreduce<<<TT*BB/256, 256, 0, stream>>>(vpart, b2, out + (size_t)BB*HID);
}

// Round 18
// 994.417 us; speedup vs baseline: 2.7392x; 1.1618x over previous
//
#include <hip/hip_runtime.h>
#include <stdint.h>

#define TT 128
#define BB 128
#define OBSD 512
#define HID 1024
#define DPAR 24

typedef _Float16 f16;
typedef _Float16 f16x8 __attribute__((ext_vector_type(8)));
typedef _Float16 f16x4 __attribute__((ext_vector_type(4)));
typedef float f32x4 __attribute__((ext_vector_type(4)));

__device__ __forceinline__ f32x4 mfma16(f16x8 a, f16x8 b, f32x4 c){
  return __builtin_amdgcn_mfma_f32_16x16x32_f16(a, b, c, 0, 0, 0);
}
__device__ __forceinline__ void gload16(const void* g, void* l){
  __builtin_amdgcn_global_load_lds(
      (const __attribute__((address_space(1))) unsigned int*)g,
      (__attribute__((address_space(3))) unsigned int*)l, 16, 0, 0);
}

// walk segments of one batch row: f(start, end) per segment (end exclusive)
template <typename F>
__device__ __forceinline__ void seg_walk(unsigned long long m0, unsigned long long m1, F f){
  int start = 0;
  unsigned long long w = m0;
  while (w){ int t = __builtin_ctzll(w); w &= w - 1; f(start, t); start = t; }
  w = m1;
  while (w){ int t = 64 + __builtin_ctzll(w); w &= w - 1; f(start, t); start = t; }
  f(start, TT);
}

// ---- prep: world_state f32 -> f16 ----
__global__ void k_ws_to_f16(const float* __restrict__ src, f16* __restrict__ dst, int n4){
  int i = blockIdx.x * blockDim.x + threadIdx.x;
  if (i < n4){
    float4 v = *reinterpret_cast<const float4*>(src + (size_t)i * 4);
    dst[(size_t)i*4 + 0] = (f16)v.x; dst[(size_t)i*4 + 1] = (f16)v.y;
    dst[(size_t)i*4 + 2] = (f16)v.z; dst[(size_t)i*4 + 3] = (f16)v.w;
  }
}

// ---- prep: transpose f32 [KD][C] (row stride srcStride) -> f16 dst[C][KD] ----
__global__ void k_prep_bt(const float* __restrict__ s0, int srcStride,
                          f16* __restrict__ dst, int KD){
  __shared__ f16 sm[64][65];
  int k0 = blockIdx.x * 64, c0 = blockIdx.y * 64;
  for (int it = 0; it < 16; ++it){
    int idx = it * 256 + threadIdx.x;
    int kr = idx >> 6, cc = idx & 63;
    sm[kr][cc] = (f16)s0[(size_t)(k0 + kr) * srcStride + (c0 + cc)];
  }
  __syncthreads();
  for (int it = 0; it < 16; ++it){
    int idx = it * 256 + threadIdx.x;
    int cr = idx >> 6, kc = idx & 63;
    dst[(size_t)(c0 + cr) * KD + (k0 + kc)] = sm[kc][cr];
  }
}

// ---- prep: bt2[c][k] = k<1024 ? Wi[k][c] : Wh[k-1024][c]; c<3072, k<2048 ----
__global__ void k_prep_bt2(const float* __restrict__ wi, const float* __restrict__ wh,
                           f16* __restrict__ dst){
  __shared__ f16 sm[64][65];
  int k0 = blockIdx.x * 64, c0 = blockIdx.y * 64;
  const float* src = (k0 < 1024) ? wi : wh;
  int kb = (k0 < 1024) ? k0 : k0 - 1024;
  for (int it = 0; it < 16; ++it){
    int idx = it * 256 + threadIdx.x;
    int kr = idx >> 6, cc = idx & 63;
    sm[kr][cc] = (f16)src[(size_t)(kb + kr) * 3072 + (c0 + cc)];
  }
  __syncthreads();
  for (int it = 0; it < 16; ++it){
    int idx = it * 256 + threadIdx.x;
    int cr = idx >> 6, kc = idx & 63;
    dst[(size_t)(c0 + cr) * 2048 + (k0 + kc)] = sm[kc][cr];
  }
}

// ---- segmentation v4: register cursors, uniform-d loops, ctz segment walks ----
__global__ void k_seg(const int* __restrict__ dones, int* __restrict__ off,
                      int* __restrict__ rowlist, int* __restrict__ znum,
                      int* __restrict__ zlist, int* __restrict__ ntail,
                      int* __restrict__ chains){
  __shared__ int lhist[128][25];
  __shared__ int lbase[128][25];
  __shared__ int tot[25];
  __shared__ int soff[25];
  int tid = threadIdx.x, b = tid;       // 128 threads, one per batch row
  unsigned long long m0 = 0, m1 = 0;
  #pragma unroll 16
  for (int t = 1; t < 64; ++t)
    m0 |= (unsigned long long)(dones[t*BB + b] != 0) << t;
  #pragma unroll 16
  for (int t = 64; t < 128; ++t)
    m1 |= (unsigned long long)(dones[t*BB + b] != 0) << (t - 64);
  const bool d0 = (dones[b] != 0);
  if (tid == 0) *ntail = 0;
  __syncthreads();
  // counts per bucket (register accumulators; lhist written once)
  for (int d = 0; d < DPAR; ++d){
    int cnt = 0;
    seg_walk(m0, m1, [&](int s, int e){
      if (d == 0) cnt += (s == 0 && !d0) ? 1 : 0;
      else        cnt += (e - s > d) ? 1 : 0;
    });
    lhist[tid][d] = cnt;
  }
  {
    int zc = 0;
    seg_walk(m0, m1, [&](int s, int e){
      if (!(s == 0 && !d0)) zc++;
      if (e - s > DPAR){
        int c = atomicAdd(ntail, 1);
        chains[c*3+0] = b; chains[c*3+1] = s; chains[c*3+2] = e - s;
      }
    });
    lhist[tid][24] = zc;
  }
  __syncthreads();
  if (tid < 25){                        // per-bucket exclusive prefix over threads
    int s = 0;
    for (int i = 0; i < 128; ++i){ lbase[i][tid] = s; s += lhist[i][tid]; }
    tot[tid] = s;
  }
  __syncthreads();
  if (tid == 0){
    int s = 0;
    for (int d = 0; d < DPAR; ++d){ soff[d] = s; off[d] = s; s += tot[d]; }
    off[DPAR] = s;
    *znum = tot[24];
  }
  __syncthreads();
  // placement (register cursors)
  for (int d = 0; d < DPAR; ++d){
    int cur = soff[d] + lbase[tid][d];
    seg_walk(m0, m1, [&](int s, int e){
      if (d == 0){ if (s == 0 && !d0) rowlist[cur++] = b; }
      else if (e - s > d) rowlist[cur++] = ((s + d) << 7) | b;
    });
  }
  {
    int cur = lbase[tid][24];
    seg_walk(m0, m1, [&](int s, int e){
      if (!(s == 0 && !d0)) zlist[cur++] = (s << 7) | b;
    });
  }
}

// ---- emb = relu(ws @ W_emb + b_emb): m97 structure, K=512 (8 kt-steps) ----
__global__ __launch_bounds__(256)
void k_emb(const f16* __restrict__ A, const f16* __restrict__ Bt,
           const float* __restrict__ bias, f16* __restrict__ outb){
  __shared__ __attribute__((aligned(16))) char smem[32768];
  int tid = threadIdx.x;
  int w = tid >> 6, lane = tid & 63;
  int wm = w >> 1, wn = w & 1;
  int bid = blockIdx.x;                       // 1024 = 128 Mb x 8 Nb
  int vid = (bid & 7) * 128 + (bid >> 3);
  int Mb = (vid >> 3) * 128, Nb = (vid & 7) * 128;
  int la = lane & 15, lk = (lane >> 4) * 8;
  f32x4 acc[4][4] = {};
  int pr[4], pc16[4];
  #pragma unroll
  for (int q = 0; q < 4; ++q){
    int P = (w*4 + q)*1024 + lane*16;
    int r = P >> 7;
    pr[q] = r;
    pc16[q] = ((P & 127) ^ ((r & 7) << 4)) >> 4;
  }
  for (int kt = 0; kt < 8; ++kt){
    __syncthreads();
    #pragma unroll
    for (int q = 0; q < 4; ++q){
      gload16(A  + (size_t)(Mb + pr[q])*OBSD + kt*64 + pc16[q]*8,
              smem + (w*4 + q)*1024);
      gload16(Bt + (size_t)(Nb + pr[q])*OBSD + kt*64 + pc16[q]*8,
              smem + 16384 + (w*4 + q)*1024);
    }
    __syncthreads();
    #pragma unroll
    for (int kk = 0; kk < 64; kk += 32){
      f16x8 av[4], bv[4];
      #pragma unroll
      for (int m = 0; m < 4; ++m){
        int r = wm*64 + m*16 + la;
        av[m] = *reinterpret_cast<const f16x8*>(
            smem + r*128 + (((kk + lk)*2) ^ ((r & 7) << 4)));
      }
      #pragma unroll
      for (int n = 0; n < 4; ++n){
        int r = wn*64 + n*16 + la;
        bv[n] = *reinterpret_cast<const f16x8*>(
            smem + 16384 + r*128 + (((kk + lk)*2) ^ ((r & 7) << 4)));
      }
      #pragma unroll
      for (int m = 0; m < 4; ++m)
        #pragma unroll
        for (int n = 0; n < 4; ++n)
          acc[m][n] = mfma16(av[m], bv[n], acc[m][n]);
    }
  }
  for (int mi = 0; mi < 4; ++mi) for (int ni = 0; ni < 4; ++ni){
    int col = Nb + wn*64 + ni*16 + la;
    float bb = bias[col];
    for (int i = 0; i < 4; ++i){
      int row = Mb + wm*64 + mi*16 + (lane >> 4)*4 + i;
      float v = acc[mi][ni][i] + bb;
      outb[(size_t)row * HID + col] = (f16)(v > 0.f ? v : 0.f);
    }
  }
}

// ---- xi = emb @ Wi + bi: m97 structure (global_load_lds, 128x128, BK=64) ----
__global__ __launch_bounds__(256)
void k_xi(const f16* __restrict__ A, const f16* __restrict__ Bt,
          const float* __restrict__ bias, f16* __restrict__ outb){
  __shared__ __attribute__((aligned(16))) char smem[32768];
  int tid = threadIdx.x;
  int w = tid >> 6, lane = tid & 63;
  int wm = w >> 1, wn = w & 1;
  int bid = blockIdx.x;                       // 3072 = 128 Mb x 24 Nb
  int vid = (bid & 7) * 384 + (bid >> 3);
  int Mb = (vid / 24) * 128, Nb = (vid % 24) * 128;
  int la = lane & 15, lk = (lane >> 4) * 8;
  f32x4 acc[4][4] = {};
  int pr[4], pc16[4];
  #pragma unroll
  for (int q = 0; q < 4; ++q){
    int P = (w*4 + q)*1024 + lane*16;
    int r = P >> 7;
    pr[q] = r;
    pc16[q] = ((P & 127) ^ ((r & 7) << 4)) >> 4;
  }
  for (int kt = 0; kt < 16; ++kt){
    __syncthreads();
    #pragma unroll
    for (int q = 0; q < 4; ++q){
      gload16(A  + (size_t)(Mb + pr[q])*HID  + kt*64 + pc16[q]*8,
              smem + (w*4 + q)*1024);
      gload16(Bt + (size_t)(Nb + pr[q])*2048 + kt*64 + pc16[q]*8,
              smem + 16384 + (w*4 + q)*1024);
    }
    __syncthreads();
    #pragma unroll
    for (int kk = 0; kk < 64; kk += 32){
      f16x8 av[4], bv[4];
      #pragma unroll
      for (int m = 0; m < 4; ++m){
        int r = wm*64 + m*16 + la;
        av[m] = *reinterpret_cast<const f16x8*>(
            smem + r*128 + (((kk + lk)*2) ^ ((r & 7) << 4)));
      }
      #pragma unroll
      for (int n = 0; n < 4; ++n){
        int r = wn*64 + n*16 + la;
        bv[n] = *reinterpret_cast<const f16x8*>(
            smem + 16384 + r*128 + (((kk + lk)*2) ^ ((r & 7) << 4)));
      }
      #pragma unroll
      for (int m = 0; m < 4; ++m)
        #pragma unroll
        for (int n = 0; n < 4; ++n)
          acc[m][n] = mfma16(av[m], bv[n], acc[m][n]);
    }
  }
  for (int mi = 0; mi < 4; ++mi) for (int ni = 0; ni < 4; ++ni){
    int col = Nb + wn*64 + ni*16 + la;
    float bb = bias[col];
    for (int i = 0; i < 4; ++i){
      int row = Mb + wm*64 + mi*16 + (lane >> 4)*4 + i;
      outb[(size_t)row * 3072 + col] = (f16)(acc[mi][ni][i] + bb);
    }
  }
}

// ---- h-zero rows: h = (1-z)*n, straight from xi (no GEMM) ----
__global__ __launch_bounds__(256)
void k_h0(const int* __restrict__ znum, const int* __restrict__ zlist,
          const f16* __restrict__ xi, const float* __restrict__ bhn_p,
          f16* __restrict__ y, float* __restrict__ hout){
  int nz = *znum;
  int tid = threadIdx.x;
  for (int ridx = blockIdx.x; ridx < nz; ridx += gridDim.x){
    int tb = zlist[ridx];
    int t = tb >> 7, b = tb & 127;
    size_t rb = ((size_t)t*BB + b) * 3072;
    int c0 = tid * 4;
    f16x4 xr = *reinterpret_cast<const f16x4*>(xi + rb + c0);
    f16x4 xz = *reinterpret_cast<const f16x4*>(xi + rb + 1024 + c0);
    f16x4 xn = *reinterpret_cast<const f16x4*>(xi + rb + 2048 + c0);
    f16x4 o;
    #pragma unroll
    for (int u = 0; u < 4; ++u){
      float r = 1.f / (1.f + expf(-(float)xr[u]));
      float z = 1.f / (1.f + expf(-(float)xz[u]));
      float n = tanhf((float)xn[u] + r * bhn_p[c0 + u]);
      float h = (1.f - z) * n;
      o[u] = (f16)h;
      if (t == TT - 1) hout[(size_t)b*HID + c0 + u] = h;
    }
    *reinterpret_cast<f16x4*>(y + ((size_t)t*BB + b)*HID + c0) = o;
  }
}

// ---- depth-j GRU step: h_prev @ Wh, K=1024; gates from xi in epilogue ----
// big path (count>1024): BM=128 x BN=192, reg-staged pipeline (round 17).
// small path (count<=1024): 16 rows x 32 hcols/block, 8 waves = 2 cs x 4 kq,
// LDS-staged h + cross-wave reduce (round-8 proven skeleton).
__global__ __launch_bounds__(512)
void k_depth(int j, const int* __restrict__ off, const int* __restrict__ rowlist,
             const f16* __restrict__ xi, const f16* __restrict__ bt2,
             const float* __restrict__ bhn_p, const float* __restrict__ hidden0,
             f16* __restrict__ y, float* __restrict__ hout){
  __shared__ __attribute__((aligned(16))) char smem[32768];
  const int base = off[j];
  const int count = off[j+1] - base;
  if (count <= 0) return;
  const int tid = threadIdx.x;
  const int lane = tid & 63;
  const int w = tid >> 6;                    // 8 waves
  const int bid = blockIdx.x;
  const int la = lane & 15, lk = (lane >> 4) * 8;

  if (count <= 1024){
    // ---------- small path ----------
    float* red = (float*)smem;               // [2][4][3][64][5] = 30720 B
    const int vid = (bid & 7) * 128 + (bid >> 3);
    const int cs2 = vid >> 5;                // [0,32): 32 hcols
    const int rgs = vid & 31;                // rowgroup stride start
    const int cg = w >> 2, kq = w & 3;       // colslice, K-chunk
    const f16* Bq0 = bt2 + (size_t)(          cs2*32 + cg*16 + la)*2048 + 1024 + kq*256 + lk;
    const f16* Bq1 = bt2 + (size_t)(1024 +    cs2*32 + cg*16 + la)*2048 + 1024 + kq*256 + lk;
    const f16* Bq2 = bt2 + (size_t)(2048 +    cs2*32 + cg*16 + la)*2048 + 1024 + kq*256 + lk;
    const int es = tid >> 8, ei = (tid >> 6) & 3, elane = tid & 63;
    const int erow_l = ((elane >> 4) << 2) + ei;
    const int ecol = cs2*32 + es*16 + (elane & 15);
    const float bh = bhn_p[ecol];
    const int nrg = (count + 15) >> 4;
    for (int rg = rgs; rg < nrg; rg += 32){
      __syncthreads();                       // prior red reads done
      #pragma unroll
      for (int it = 0; it < 4; ++it){        // 512 thr x 4 = 2048 = 16 rows x 128 parts
        int idx = tid + it*512;
        int r = idx >> 7, part = idx & 127;
        int ridx = rg*16 + r;
        int tb = (ridx < count) ? rowlist[base + ridx] : -1;
        float4 v = {0.f, 0.f, 0.f, 0.f};
        if (tb >= 0){
          int t = tb >> 7, bb_ = tb & 127;
          if (j > 0){
            v = *reinterpret_cast<const float4*>(y + ((size_t)(t-1)*BB + bb_)*HID + part*8);
          } else {
            const float* s = hidden0 + (size_t)bb_*HID + part*8;
            float4 a0 = *reinterpret_cast<const float4*>(s);
            float4 a1 = *reinterpret_cast<const float4*>(s + 4);
            f16 h8[8] = {(f16)a0.x,(f16)a0.y,(f16)a0.z,(f16)a0.w,
                         (f16)a1.x,(f16)a1.y,(f16)a1.z,(f16)a1.w};
            v = *reinterpret_cast<float4*>(h8);
          }
        }
        *reinterpret_cast<float4*>(smem + ((r*2048 + part*16) ^ ((r & 7) << 4))) = v;
      }
      __syncthreads();
      f32x4 a0 = {}, a1 = {}, a2 = {};
      #pragma unroll
      for (int kk = 0; kk < 256; kk += 32){
        int k = kq*256 + kk + lk;
        f16x8 av = *reinterpret_cast<const f16x8*>(
            smem + ((la*2048 + k*2) ^ ((la & 7) << 4)));
        a0 = mfma16(av, *reinterpret_cast<const f16x8*>(Bq0 + kk), a0);
        a1 = mfma16(av, *reinterpret_cast<const f16x8*>(Bq1 + kk), a1);
        a2 = mfma16(av, *reinterpret_cast<const f16x8*>(Bq2 + kk), a2);
      }
      __syncthreads();                       // A-frag reads done; smem -> red
      #pragma unroll
      for (int i = 0; i < 4; ++i){
        red[((((cg*4 + kq)*3 + 0)*64 + lane)*5) + i] = a0[i];
        red[((((cg*4 + kq)*3 + 1)*64 + lane)*5) + i] = a1[i];
        red[((((cg*4 + kq)*3 + 2)*64 + lane)*5) + i] = a2[i];
      }
      __syncthreads();
      int ridx = rg*16 + erow_l;
      if (ridx < count){
        int tb = rowlist[base + ridx];
        int t = tb >> 7, bb_ = tb & 127;
        float hr = 0.f, hz = 0.f, hn = 0.f;
        #pragma unroll
        for (int kq2 = 0; kq2 < 4; ++kq2){
          hr += red[((((es*4 + kq2)*3 + 0)*64 + elane)*5) + ei];
          hz += red[((((es*4 + kq2)*3 + 1)*64 + elane)*5) + ei];
          hn += red[((((es*4 + kq2)*3 + 2)*64 + elane)*5) + ei];
        }
        size_t rb = ((size_t)t*BB + bb_)*3072 + ecol;
        float hold;
        if (j > 0) hold = (float)y[((size_t)(t-1)*BB + bb_)*HID + ecol];
        else       hold = hidden0[(size_t)bb_*HID + ecol];
        float r = 1.f / (1.f + expf(-((float)xi[rb]        + hr)));
        float z = 1.f / (1.f + expf(-((float)xi[rb + 1024] + hz)));
        float n = tanhf((float)xi[rb + 2048] + r * (hn + bh));
        float hnew = (1.f - z) * n + z * hold;
        y[((size_t)t*BB + bb_)*HID + ecol] = (f16)hnew;
        if (t == TT - 1) hout[(size_t)bb_*HID + ecol] = hnew;
      }
    }
    return;
  }

  // ---------- big path (round 17, unchanged) ----------
  const int wm = w >> 2, wn = w & 3;         // 2m x 4n
  const int nb = bid & 15;
  const int st = bid >> 4;                   // 64 M-strides
  const int hcolw = nb*64 + wn*16;
  const f16* Bg0 = bt2 + (size_t)(          hcolw + la) * 2048 + 1024 + lk;
  const f16* Bg1 = bt2 + (size_t)(1024 +    hcolw + la) * 2048 + 1024 + lk;
  const f16* Bg2 = bt2 + (size_t)(2048 +    hcolw + la) * 2048 + 1024 + lk;
  const int ntiles = (count + 127) >> 7;

  for (int tile = st; tile < ntiles; tile += 64){
    const char* hptr[4]; int hmode[4]; int sq[4]; int dby[4];
    #pragma unroll
    for (int q = 0; q < 4; ++q){
      int idx = tid + q*512;
      int r = idx >> 4; sq[q] = idx & 15;
      dby[q] = (r*256 + sq[q]*16) ^ ((r & 7) << 4);
      int ridx = tile*128 + r;
      int tb = (ridx < count) ? rowlist[base + ridx] : -1;
      hmode[q] = 0; hptr[q] = nullptr;
      if (tb >= 0){
        int t = tb >> 7, b = tb & 127;
        if (j > 0){ hmode[q] = 1; hptr[q] = (const char*)(y + ((size_t)(t-1)*BB + b)*HID); }
        else      { hmode[q] = 2; hptr[q] = (const char*)(hidden0 + (size_t)b*HID); }
      }
    }
    auto loadch = [&](int ch, float4* dst){
      #pragma unroll
      for (int q = 0; q < 4; ++q){
        float4 v = {0.f, 0.f, 0.f, 0.f};
        if (hmode[q] == 1){
          v = *reinterpret_cast<const float4*>((const f16*)hptr[q] + ch*128 + sq[q]*8);
        } else if (hmode[q] == 2){
          const float* s = (const float*)hptr[q] + ch*128 + sq[q]*8;
          float4 a0 = *reinterpret_cast<const float4*>(s);
          float4 a1 = *reinterpret_cast<const float4*>(s + 4);
          f16 h8[8] = {(f16)a0.x,(f16)a0.y,(f16)a0.z,(f16)a0.w,
                       (f16)a1.x,(f16)a1.y,(f16)a1.z,(f16)a1.w};
          v = *reinterpret_cast<float4*>(h8);
        }
        dst[q] = v;
      }
    };
    f32x4 ar[4] = {}, az[4] = {}, ahn[4] = {};
    float4 hv[4];
    loadch(0, hv);
    #pragma unroll 1
    for (int ch = 0; ch < 8; ++ch){
      __syncthreads();
      #pragma unroll
      for (int q = 0; q < 4; ++q)
        *reinterpret_cast<float4*>(smem + dby[q]) = hv[q];
      float4 hv2[4];
      if (ch < 7) loadch(ch+1, hv2);
      __syncthreads();
      const int kbase = ch*128;
      #pragma unroll
      for (int kk = 0; kk < 128; kk += 32){
        f16x8 av[4];
        #pragma unroll
        for (int m = 0; m < 4; ++m){
          int r = wm*64 + m*16 + la;
          av[m] = *reinterpret_cast<const f16x8*>(
              smem + ((r*256 + (kk + lk)*2) ^ ((r & 7) << 4)));
        }
        f16x8 b0 = *reinterpret_cast<const f16x8*>(Bg0 + kbase + kk);
        f16x8 b1 = *reinterpret_cast<const f16x8*>(Bg1 + kbase + kk);
        f16x8 b2 = *reinterpret_cast<const f16x8*>(Bg2 + kbase + kk);
        #pragma unroll
        for (int m = 0; m < 4; ++m){
          ar[m]  = mfma16(av[m], b0, ar[m]);
          az[m]  = mfma16(av[m], b1, az[m]);
          ahn[m] = mfma16(av[m], b2, ahn[m]);
        }
      }
      #pragma unroll
      for (int q = 0; q < 4; ++q) hv[q] = hv2[q];
    }
    {
      int hcol = hcolw + la;
      float bh = bhn_p[hcol];
      #pragma unroll
      for (int m = 0; m < 4; ++m){
        #pragma unroll
        for (int i = 0; i < 4; ++i){
          int lr = wm*64 + m*16 + (lane >> 4)*4 + i;
          int ridx = tile*128 + lr;
          if (ridx >= count) continue;
          int tb = rowlist[base + ridx];
          int t = tb >> 7, b = tb & 127;
          size_t rb = ((size_t)t*BB + b)*3072 + hcol;
          float hold;
          if (j > 0) hold = (float)y[((size_t)(t-1)*BB + b)*HID + hcol];
          else       hold = hidden0[(size_t)b*HID + hcol];
          float r = 1.f / (1.f + expf(-((float)xi[rb]        + ar[m][i])));
          float z = 1.f / (1.f + expf(-((float)xi[rb + 1024] + az[m][i])));
          float n = tanhf((float)xi[rb + 2048] + r * (ahn[m][i] + bh));
          float hnew = (1.f - z) * n + z * hold;
          y[((size_t)t*BB + b)*HID + hcol] = (f16)hnew;
          if (t == TT - 1) hout[(size_t)b*HID + hcol] = hnew;
        }
      }
    }
  }
}

// ---- sequential tail for chains longer than DPAR (empty for this seed) ----
__global__ __launch_bounds__(256)
void k_tail(const int* __restrict__ ntail, const int* __restrict__ chains,
            const f16* __restrict__ xi, const f16* __restrict__ bt2,
            const float* __restrict__ bhn_p, f16* __restrict__ y,
            float* __restrict__ hout){
  int n = *ntail;
  __shared__ f16 hs[1024];
  int tid = threadIdx.x;
  for (int c = blockIdx.x; c < n; c += gridDim.x){
    int b = chains[c*3], t0 = chains[c*3+1], len = chains[c*3+2];
    for (int i = tid; i < 1024; i += 256)
      hs[i] = y[((size_t)(t0 + DPAR - 1)*BB + b)*HID + i];
    __syncthreads();
    for (int t = t0 + DPAR; t < t0 + len; ++t){
      float tmp[4];
      #pragma unroll
      for (int u = 0; u < 4; ++u){
        int col = tid*4 + u;
        float s_r = 0.f, s_z = 0.f, s_hn = 0.f;
        const f16* wr = bt2 + (size_t)col*2048 + 1024;
        const f16* wz = bt2 + (size_t)(1024+col)*2048 + 1024;
        const f16* wn = bt2 + (size_t)(2048+col)*2048 + 1024;
        for (int q = 0; q < 128; ++q){
          f16x8 hv = *reinterpret_cast<const f16x8*>(&hs[q*8]);
          f16x8 wrh = *reinterpret_cast<const f16x8*>(wr + q*8);
          f16x8 wzh = *reinterpret_cast<const f16x8*>(wz + q*8);
          f16x8 wnh = *reinterpret_cast<const f16x8*>(wn + q*8);
          #pragma unroll
          for (int e = 0; e < 8; ++e){
            float hh = (float)hv[e];
            s_r  += hh*(float)wrh[e];
            s_z  += hh*(float)wzh[e];
            s_hn += hh*(float)wnh[e];
          }
        }
        size_t rb = ((size_t)t*BB + b)*3072 + col;
        float r = 1.f / (1.f + expf(-((float)xi[rb] + s_r)));
        float z = 1.f / (1.f + expf(-((float)xi[rb + 1024] + s_z)));
        float nn = tanhf((float)xi[rb + 2048] + r * (s_hn + bhn_p[col]));
        float hold = (float)hs[col];
        float hnew = (1.f - z) * nn + z * hold;
        y[((size_t)t*BB + b)*HID + col] = (f16)hnew;
        if (t == TT - 1) hout[(size_t)b*HID + col] = hnew;
        tmp[u] = hnew;
      }
      __syncthreads();
      #pragma unroll
      for (int u = 0; u < 4; ++u) hs[tid*4 + u] = (f16)tmp[u];
      __syncthreads();
    }
    __syncthreads();
  }
}

// ---- critic: m97 structure (global_load_lds, 128x128, BK=64) + value fusion ----
__global__ __launch_bounds__(256)
void k_critic(const f16* __restrict__ Y, const f16* __restrict__ Bt,
              const float* __restrict__ b1, const float* __restrict__ W2,
              float* __restrict__ vpart){
  __shared__ __attribute__((aligned(16))) char smem[32768];
  int tid = threadIdx.x;
  int w = tid >> 6, lane = tid & 63;
  int wm = w >> 1, wn = w & 1;
  int bid = blockIdx.x;
  int vid = (bid & 7) * 128 + (bid >> 3);
  int Mb = (vid >> 3) * 128, Nb = (vid & 7) * 128;
  int la = lane & 15, lk = (lane >> 4) * 8;
  f32x4 acc[4][4] = {};
  int pr[4], pc16[4];
  #pragma unroll
  for (int q = 0; q < 4; ++q){
    int P = (w*4 + q)*1024 + lane*16;
    int r = P >> 7;
    pr[q] = r;
    pc16[q] = ((P & 127) ^ ((r & 7) << 4)) >> 4;
  }
  for (int kt = 0; kt < 16; ++kt){
    __syncthreads();
    #pragma unroll
    for (int q = 0; q < 4; ++q){
      gload16(Y  + (size_t)(Mb + pr[q])*HID + kt*64 + pc16[q]*8,
              smem + (w*4 + q)*1024);
      gload16(Bt + (size_t)(Nb + pr[q])*HID + kt*64 + pc16[q]*8,
              smem + 16384 + (w*4 + q)*1024);
    }
    __syncthreads();
    #pragma unroll
    for (int kk = 0; kk < 64; kk += 32){
      f16x8 av[4], bv[4];
      #pragma unroll
      for (int m = 0; m < 4; ++m){
        int r = wm*64 + m*16 + la;
        av[m] = *reinterpret_cast<const f16x8*>(
            smem + r*128 + (((kk + lk)*2) ^ ((r & 7) << 4)));
      }
      #pragma unroll
      for (int n = 0; n < 4; ++n){
        int r = wn*64 + n*16 + la;
        bv[n] = *reinterpret_cast<const f16x8*>(
            smem + 16384 + r*128 + (((kk + lk)*2) ^ ((r & 7) << 4)));
      }
      #pragma unroll
      for (int m = 0; m < 4; ++m)
        #pragma unroll
        for (int n = 0; n < 4; ++n)
          acc[m][n] = mfma16(av[m], bv[n], acc[m][n]);
    }
  }
  __syncthreads();
  __shared__ float vs[2][64][2];
  float p[4][4];
  for (int mi = 0; mi < 4; ++mi) for (int i = 0; i < 4; ++i) p[mi][i] = 0.f;
  for (int ni = 0; ni < 4; ++ni){
    int col = Nb + wn*64 + ni*16 + la;
    float bb = b1[col], w2 = W2[col];
    for (int mi = 0; mi < 4; ++mi)
      for (int i = 0; i < 4; ++i){
        float c = acc[mi][ni][i] + bb;
        p[mi][i] += (c > 0.f ? c : 0.f) * w2;
      }
  }
  for (int mi = 0; mi < 4; ++mi) for (int i = 0; i < 4; ++i){
    float s = p[mi][i];
    s += __shfl_xor(s, 1); s += __shfl_xor(s, 2);
    s += __shfl_xor(s, 4); s += __shfl_xor(s, 8);
    p[mi][i] = s;
  }
  if (la == 0){
    int q = lane >> 4;
    for (int mi = 0; mi < 4; ++mi)
      for (int i = 0; i < 4; ++i)
        vs[wm][mi*16 + q*4 + i][wn] = p[mi][i];
  }
  __syncthreads();
  if (threadIdx.x < 128){
    int rw = threadIdx.x;
    float s = vs[rw >> 6][rw & 63][0] + vs[rw >> 6][rw & 63][1];
    vpart[(size_t)(Nb >> 7) * (TT*BB) + Mb + rw] = s;
  }
}

__global__ void k_vreduce(const float* __restrict__ vpart, const float* __restrict__ b2,
                          float* __restrict__ outv){
  int m = blockIdx.x * 256 + threadIdx.x;
  float s = b2[0];
  for (int nb = 0; nb < 8; ++nb) s += vpart[(size_t)nb * (TT*BB) + m];
  outv[m] = s;
}

extern "C" void kernel_launch(void* const* d_in, const int* in_sizes, int n_in,
                              void* d_out, int out_size, void* d_ws, size_t ws_size,
                              hipStream_t stream){
  const float* hidden = (const float*)d_in[0];
  const float* world  = (const float*)d_in[1];
  const int*   dones  = (const int*)d_in[2];
  const float* W_emb  = (const float*)d_in[3];
  const float* b_emb  = (const float*)d_in[4];
  const float* Wi     = (const float*)d_in[5];
  const float* bi     = (const float*)d_in[6];
  const float* Wh     = (const float*)d_in[7];
  const float* bhn    = (const float*)d_in[8];
  const float* W1     = (const float*)d_in[9];
  const float* b1     = (const float*)d_in[10];
  const float* W2     = (const float*)d_in[11];
  const float* b2     = (const float*)d_in[12];
  float* out = (float*)d_out;

  char* p = (char*)d_ws;
  auto alloc = [&](size_t bytes) -> char* {
    char* r = p; p += (bytes + 255) & ~(size_t)255; return r;
  };
  f16*   ws16   = (f16*)alloc((size_t)TT*BB*OBSD*2);     // 16 MB
  f16*   wembt  = (f16*)alloc((size_t)HID*OBSD*2);       // 1 MB
  f16*   emb16  = (f16*)alloc((size_t)TT*BB*HID*2);      // 33.5 MB
  f16*   bt2    = (f16*)alloc((size_t)3072*2048*2);      // 12.6 MB
  f16*   w1t    = (f16*)alloc((size_t)HID*HID*2);        // 2 MB
  f16*   xi16   = (f16*)alloc((size_t)TT*BB*3072*2);     // 100.7 MB
  f16*   ybuf   = (f16*)alloc((size_t)TT*BB*HID*2);      // 33.5 MB
  float* vpart  = (float*)alloc((size_t)8*TT*BB*4);      // 0.5 MB
  int*   off    = (int*)alloc((DPAR + 1) * 4);
  int*   rowlist= (int*)alloc((size_t)(TT*BB + 128)*4);
  int*   znum   = (int*)alloc(4);
  int*   zlist  = (int*)alloc((size_t)(TT*BB + 128)*4);
  int*   ntail  = (int*)alloc(4);
  int*   chains = (int*)alloc((size_t)1024*3*4);
  if ((size_t)(p - (char*)d_ws) > ws_size) return;

  // preps (+ segmentation, depends only on dones)
  k_ws_to_f16<<<(TT*BB*OBSD/4 + 255)/256, 256, 0, stream>>>(world, ws16, TT*BB*OBSD/4);
  k_prep_bt<<<dim3(OBSD/64, HID/64), 256, 0, stream>>>(W_emb, 1024, wembt, OBSD);
  k_prep_bt2<<<dim3(2048/64, 3072/64), 256, 0, stream>>>(Wi, Wh, bt2);
  k_prep_bt<<<dim3(HID/64, HID/64), 256, 0, stream>>>(W1, 1024, w1t, HID);
  k_seg<<<1, 128, 0, stream>>>(dones, off, rowlist, znum, zlist, ntail, chains);

  // parallel GEMMs
  k_emb<<<1024, 256, 0, stream>>>(ws16, wembt, b_emb, emb16);
  k_xi<<<3072, 256, 0, stream>>>(emb16, bt2, bi, xi16);

  // h-zero rows (no GEMM) + depth-parallel GRU scan + tail
  k_h0<<<2048, 256, 0, stream>>>(znum, zlist, xi16, bhn, ybuf, out);
  for (int j = 0; j < DPAR; ++j)
    k_depth<<<1024, 512, 0, stream>>>(j, off, rowlist, xi16, bt2, bhn,
                                      hidden, ybuf, out);
  k_tail<<<128, 256, 0, stream>>>(ntail, chains, xi16, bt2, bhn, ybuf, out);

  // critic head + value
  k_critic<<<1024, 256, 0, stream>>>(ybuf, w1t, b1, W2, vpart);
  k_vreduce<<<TT*BB/256, 256, 0, stream>>>(vpart, b2, out + (size_t)BB*HID);
}

// Round 19
// 841.721 us; speedup vs baseline: 3.2361x; 1.1814x over previous
//
#include <hip/hip_runtime.h>
#include <stdint.h>

#define TT 128
#define BB 128
#define OBSD 512
#define HID 1024
#define DPAR 24
#define BUCKCAP 16384

typedef _Float16 f16;
typedef _Float16 f16x8 __attribute__((ext_vector_type(8)));
typedef _Float16 f16x4 __attribute__((ext_vector_type(4)));
typedef float f32x4 __attribute__((ext_vector_type(4)));

__device__ __forceinline__ f32x4 mfma16(f16x8 a, f16x8 b, f32x4 c){
  return __builtin_amdgcn_mfma_f32_16x16x32_f16(a, b, c, 0, 0, 0);
}
__device__ __forceinline__ void gload16(const void* g, void* l){
  __builtin_amdgcn_global_load_lds(
      (const __attribute__((address_space(1))) unsigned int*)g,
      (__attribute__((address_space(3))) unsigned int*)l, 16, 0, 0);
}

// ---- prep: world_state f32 -> f16 ----
__global__ void k_ws_to_f16(const float* __restrict__ src, f16* __restrict__ dst, int n4){
  int i = blockIdx.x * blockDim.x + threadIdx.x;
  if (i < n4){
    float4 v = *reinterpret_cast<const float4*>(src + (size_t)i * 4);
    dst[(size_t)i*4 + 0] = (f16)v.x; dst[(size_t)i*4 + 1] = (f16)v.y;
    dst[(size_t)i*4 + 2] = (f16)v.z; dst[(size_t)i*4 + 3] = (f16)v.w;
  }
}

// ---- prep: transpose f32 [KD][C] (row stride srcStride) -> f16 dst[C][KD] ----
__global__ void k_prep_bt(const float* __restrict__ s0, int srcStride,
                          f16* __restrict__ dst, int KD){
  __shared__ f16 sm[64][65];
  int k0 = blockIdx.x * 64, c0 = blockIdx.y * 64;
  for (int it = 0; it < 16; ++it){
    int idx = it * 256 + threadIdx.x;
    int kr = idx >> 6, cc = idx & 63;
    sm[kr][cc] = (f16)s0[(size_t)(k0 + kr) * srcStride + (c0 + cc)];
  }
  __syncthreads();
  for (int it = 0; it < 16; ++it){
    int idx = it * 256 + threadIdx.x;
    int cr = idx >> 6, kc = idx & 63;
    dst[(size_t)(c0 + cr) * KD + (k0 + kc)] = sm[kc][cr];
  }
}

// ---- prep: bt2[c][k] = k<1024 ? Wi[k][c] : Wh[k-1024][c]; c<3072, k<2048 ----
__global__ void k_prep_bt2(const float* __restrict__ wi, const float* __restrict__ wh,
                           f16* __restrict__ dst){
  __shared__ f16 sm[64][65];
  int k0 = blockIdx.x * 64, c0 = blockIdx.y * 64;
  const float* src = (k0 < 1024) ? wi : wh;
  int kb = (k0 < 1024) ? k0 : k0 - 1024;
  for (int it = 0; it < 16; ++it){
    int idx = it * 256 + threadIdx.x;
    int kr = idx >> 6, cc = idx & 63;
    sm[kr][cc] = (f16)src[(size_t)(kb + kr) * 3072 + (c0 + cc)];
  }
  __syncthreads();
  for (int it = 0; it < 16; ++it){
    int idx = it * 256 + threadIdx.x;
    int cr = idx >> 6, kc = idx & 63;
    dst[(size_t)(c0 + cr) * 2048 + (k0 + kc)] = sm[kc][cr];
  }
}

// ---- segmentation v5: fixed-stride buckets + global-atomic slot alloc ----
// cnt[0..23]=bucket counts, cnt[24]=zlist count, cnt[25]=chain count.
// rowlist[d*BUCKCAP + slot]; bucket order irrelevant (gather lists).
__global__ void k_seg(const int* __restrict__ dones, int* __restrict__ cnt,
                      int* __restrict__ rowlist, int* __restrict__ zlist,
                      int* __restrict__ chains){
  int b = threadIdx.x;                 // 128 threads, one per batch row
  unsigned long long m0 = 0, m1 = 0;
  #pragma unroll 16
  for (int t = 1; t < 64; ++t)
    m0 |= (unsigned long long)(dones[t*BB + b] != 0) << t;
  #pragma unroll 16
  for (int t = 64; t < 128; ++t)
    m1 |= (unsigned long long)(dones[t*BB + b] != 0) << (t - 64);
  const bool d0 = (dones[b] != 0);
  unsigned long long w0 = m0, w1 = m1;
  int start = 0;
  while (true){
    int t;
    if (w0){ t = __builtin_ctzll(w0); w0 &= w0 - 1; }
    else if (w1){ t = 64 + __builtin_ctzll(w1); w1 &= w1 - 1; }
    else t = TT;
    int len = t - start;
    if (start == 0 && !d0){
      int pos = atomicAdd(&cnt[0], 1);
      rowlist[pos] = b;                                  // (t=0)<<7 | b
    } else {
      int pos = atomicAdd(&cnt[24], 1);
      zlist[pos] = (start << 7) | b;
    }
    int nb = len < DPAR ? len : DPAR;
    for (int d = 1; d < nb; ++d){
      int pos = atomicAdd(&cnt[d], 1);
      rowlist[d*BUCKCAP + pos] = ((start + d) << 7) | b;
    }
    if (len > DPAR){
      int c = atomicAdd(&cnt[25], 1);
      chains[c*3+0] = b; chains[c*3+1] = start; chains[c*3+2] = len;
    }
    if (t == TT) break;
    start = t;
  }
}

// ---- emb = relu(ws @ W_emb + b_emb): m97 structure, K=512 (8 kt-steps) ----
__global__ __launch_bounds__(256)
void k_emb(const f16* __restrict__ A, const f16* __restrict__ Bt,
           const float* __restrict__ bias, f16* __restrict__ outb){
  __shared__ __attribute__((aligned(16))) char smem[32768];
  int tid = threadIdx.x;
  int w = tid >> 6, lane = tid & 63;
  int wm = w >> 1, wn = w & 1;
  int bid = blockIdx.x;                       // 1024 = 128 Mb x 8 Nb
  int vid = (bid & 7) * 128 + (bid >> 3);
  int Mb = (vid >> 3) * 128, Nb = (vid & 7) * 128;
  int la = lane & 15, lk = (lane >> 4) * 8;
  f32x4 acc[4][4] = {};
  int pr[4], pc16[4];
  #pragma unroll
  for (int q = 0; q < 4; ++q){
    int P = (w*4 + q)*1024 + lane*16;
    int r = P >> 7;
    pr[q] = r;
    pc16[q] = ((P & 127) ^ ((r & 7) << 4)) >> 4;
  }
  for (int kt = 0; kt < 8; ++kt){
    __syncthreads();
    #pragma unroll
    for (int q = 0; q < 4; ++q){
      gload16(A  + (size_t)(Mb + pr[q])*OBSD + kt*64 + pc16[q]*8,
              smem + (w*4 + q)*1024);
      gload16(Bt + (size_t)(Nb + pr[q])*OBSD + kt*64 + pc16[q]*8,
              smem + 16384 + (w*4 + q)*1024);
    }
    __syncthreads();
    #pragma unroll
    for (int kk = 0; kk < 64; kk += 32){
      f16x8 av[4], bv[4];
      #pragma unroll
      for (int m = 0; m < 4; ++m){
        int r = wm*64 + m*16 + la;
        av[m] = *reinterpret_cast<const f16x8*>(
            smem + r*128 + (((kk + lk)*2) ^ ((r & 7) << 4)));
      }
      #pragma unroll
      for (int n = 0; n < 4; ++n){
        int r = wn*64 + n*16 + la;
        bv[n] = *reinterpret_cast<const f16x8*>(
            smem + 16384 + r*128 + (((kk + lk)*2) ^ ((r & 7) << 4)));
      }
      #pragma unroll
      for (int m = 0; m < 4; ++m)
        #pragma unroll
        for (int n = 0; n < 4; ++n)
          acc[m][n] = mfma16(av[m], bv[n], acc[m][n]);
    }
  }
  for (int mi = 0; mi < 4; ++mi) for (int ni = 0; ni < 4; ++ni){
    int col = Nb + wn*64 + ni*16 + la;
    float bb = bias[col];
    for (int i = 0; i < 4; ++i){
      int row = Mb + wm*64 + mi*16 + (lane >> 4)*4 + i;
      float v = acc[mi][ni][i] + bb;
      outb[(size_t)row * HID + col] = (f16)(v > 0.f ? v : 0.f);
    }
  }
}

// ---- xi = emb @ Wi + bi: m97 structure (global_load_lds, 128x128, BK=64) ----
__global__ __launch_bounds__(256)
void k_xi(const f16* __restrict__ A, const f16* __restrict__ Bt,
          const float* __restrict__ bias, f16* __restrict__ outb){
  __shared__ __attribute__((aligned(16))) char smem[32768];
  int tid = threadIdx.x;
  int w = tid >> 6, lane = tid & 63;
  int wm = w >> 1, wn = w & 1;
  int bid = blockIdx.x;                       // 3072 = 128 Mb x 24 Nb
  int vid = (bid & 7) * 384 + (bid >> 3);
  int Mb = (vid / 24) * 128, Nb = (vid % 24) * 128;
  int la = lane & 15, lk = (lane >> 4) * 8;
  f32x4 acc[4][4] = {};
  int pr[4], pc16[4];
  #pragma unroll
  for (int q = 0; q < 4; ++q){
    int P = (w*4 + q)*1024 + lane*16;
    int r = P >> 7;
    pr[q] = r;
    pc16[q] = ((P & 127) ^ ((r & 7) << 4)) >> 4;
  }
  for (int kt = 0; kt < 16; ++kt){
    __syncthreads();
    #pragma unroll
    for (int q = 0; q < 4; ++q){
      gload16(A  + (size_t)(Mb + pr[q])*HID  + kt*64 + pc16[q]*8,
              smem + (w*4 + q)*1024);
      gload16(Bt + (size_t)(Nb + pr[q])*2048 + kt*64 + pc16[q]*8,
              smem + 16384 + (w*4 + q)*1024);
    }
    __syncthreads();
    #pragma unroll
    for (int kk = 0; kk < 64; kk += 32){
      f16x8 av[4], bv[4];
      #pragma unroll
      for (int m = 0; m < 4; ++m){
        int r = wm*64 + m*16 + la;
        av[m] = *reinterpret_cast<const f16x8*>(
            smem + r*128 + (((kk + lk)*2) ^ ((r & 7) << 4)));
      }
      #pragma unroll
      for (int n = 0; n < 4; ++n){
        int r = wn*64 + n*16 + la;
        bv[n] = *reinterpret_cast<const f16x8*>(
            smem + 16384 + r*128 + (((kk + lk)*2) ^ ((r & 7) << 4)));
      }
      #pragma unroll
      for (int m = 0; m < 4; ++m)
        #pragma unroll
        for (int n = 0; n < 4; ++n)
          acc[m][n] = mfma16(av[m], bv[n], acc[m][n]);
    }
  }
  for (int mi = 0; mi < 4; ++mi) for (int ni = 0; ni < 4; ++ni){
    int col = Nb + wn*64 + ni*16 + la;
    float bb = bias[col];
    for (int i = 0; i < 4; ++i){
      int row = Mb + wm*64 + mi*16 + (lane >> 4)*4 + i;
      outb[(size_t)row * 3072 + col] = (f16)(acc[mi][ni][i] + bb);
    }
  }
}

// ---- h-zero rows: h = (1-z)*n, straight from xi (no GEMM) ----
__global__ __launch_bounds__(256)
void k_h0(const int* __restrict__ cnt, const int* __restrict__ zlist,
          const f16* __restrict__ xi, const float* __restrict__ bhn_p,
          f16* __restrict__ y, float* __restrict__ hout){
  int nz = cnt[24];
  int tid = threadIdx.x;
  for (int ridx = blockIdx.x; ridx < nz; ridx += gridDim.x){
    int tb = zlist[ridx];
    int t = tb >> 7, b = tb & 127;
    size_t rb = ((size_t)t*BB + b) * 3072;
    int c0 = tid * 4;
    f16x4 xr = *reinterpret_cast<const f16x4*>(xi + rb + c0);
    f16x4 xz = *reinterpret_cast<const f16x4*>(xi + rb + 1024 + c0);
    f16x4 xn = *reinterpret_cast<const f16x4*>(xi + rb + 2048 + c0);
    f16x4 o;
    #pragma unroll
    for (int u = 0; u < 4; ++u){
      float r = 1.f / (1.f + expf(-(float)xr[u]));
      float z = 1.f / (1.f + expf(-(float)xz[u]));
      float n = tanhf((float)xn[u] + r * bhn_p[c0 + u]);
      float h = (1.f - z) * n;
      o[u] = (f16)h;
      if (t == TT - 1) hout[(size_t)b*HID + c0 + u] = h;
    }
    *reinterpret_cast<f16x4*>(y + ((size_t)t*BB + b)*HID + c0) = o;
  }
}

// ---- depth-j GRU step: h_prev @ Wh, K=1024; gates from xi in epilogue ----
// big path (count>1024): BM=128 x BN=192, reg-staged pipeline.
// small path (count<=1024): 16 rows x 32 hcols/block, 8 waves = 2 cs x 4 kq.
__global__ __launch_bounds__(512)
void k_depth(int j, const int* __restrict__ cnt, const int* __restrict__ rowlist_g,
             const f16* __restrict__ xi, const f16* __restrict__ bt2,
             const float* __restrict__ bhn_p, const float* __restrict__ hidden0,
             f16* __restrict__ y, float* __restrict__ hout){
  __shared__ __attribute__((aligned(16))) char smem[32768];
  const int count = cnt[j];
  if (count <= 0) return;
  const int* rowlist = rowlist_g + (size_t)j * BUCKCAP;
  const int tid = threadIdx.x;
  const int lane = tid & 63;
  const int w = tid >> 6;                    // 8 waves
  const int bid = blockIdx.x;
  const int la = lane & 15, lk = (lane >> 4) * 8;

  if (count <= 1024){
    // ---------- small path ----------
    float* red = (float*)smem;               // [2][4][3][64][5] = 30720 B
    const int vid = (bid & 7) * 128 + (bid >> 3);
    const int cs2 = vid >> 5;                // [0,32): 32 hcols
    const int rgs = vid & 31;                // rowgroup stride start
    const int cg = w >> 2, kq = w & 3;       // colslice, K-chunk
    const f16* Bq0 = bt2 + (size_t)(          cs2*32 + cg*16 + la)*2048 + 1024 + kq*256 + lk;
    const f16* Bq1 = bt2 + (size_t)(1024 +    cs2*32 + cg*16 + la)*2048 + 1024 + kq*256 + lk;
    const f16* Bq2 = bt2 + (size_t)(2048 +    cs2*32 + cg*16 + la)*2048 + 1024 + kq*256 + lk;
    const int es = tid >> 8, ei = (tid >> 6) & 3, elane = tid & 63;
    const int erow_l = ((elane >> 4) << 2) + ei;
    const int ecol = cs2*32 + es*16 + (elane & 15);
    const float bh = bhn_p[ecol];
    const int nrg = (count + 15) >> 4;
    for (int rg = rgs; rg < nrg; rg += 32){
      __syncthreads();
      #pragma unroll
      for (int it = 0; it < 4; ++it){        // 512 thr x 4 = 16 rows x 128 parts
        int idx = tid + it*512;
        int r = idx >> 7, part = idx & 127;
        int ridx = rg*16 + r;
        int tb = (ridx < count) ? rowlist[ridx] : -1;
        float4 v = {0.f, 0.f, 0.f, 0.f};
        if (tb >= 0){
          int t = tb >> 7, bb_ = tb & 127;
          if (j > 0){
            v = *reinterpret_cast<const float4*>(y + ((size_t)(t-1)*BB + bb_)*HID + part*8);
          } else {
            const float* s = hidden0 + (size_t)bb_*HID + part*8;
            float4 a0 = *reinterpret_cast<const float4*>(s);
            float4 a1 = *reinterpret_cast<const float4*>(s + 4);
            f16 h8[8] = {(f16)a0.x,(f16)a0.y,(f16)a0.z,(f16)a0.w,
                         (f16)a1.x,(f16)a1.y,(f16)a1.z,(f16)a1.w};
            v = *reinterpret_cast<float4*>(h8);
          }
        }
        *reinterpret_cast<float4*>(smem + ((r*2048 + part*16) ^ ((r & 7) << 4))) = v;
      }
      __syncthreads();
      f32x4 a0 = {}, a1 = {}, a2 = {};
      #pragma unroll
      for (int kk = 0; kk < 256; kk += 32){
        int k = kq*256 + kk + lk;
        f16x8 av = *reinterpret_cast<const f16x8*>(
            smem + ((la*2048 + k*2) ^ ((la & 7) << 4)));
        a0 = mfma16(av, *reinterpret_cast<const f16x8*>(Bq0 + kk), a0);
        a1 = mfma16(av, *reinterpret_cast<const f16x8*>(Bq1 + kk), a1);
        a2 = mfma16(av, *reinterpret_cast<const f16x8*>(Bq2 + kk), a2);
      }
      __syncthreads();
      #pragma unroll
      for (int i = 0; i < 4; ++i){
        red[((((cg*4 + kq)*3 + 0)*64 + lane)*5) + i] = a0[i];
        red[((((cg*4 + kq)*3 + 1)*64 + lane)*5) + i] = a1[i];
        red[((((cg*4 + kq)*3 + 2)*64 + lane)*5) + i] = a2[i];
      }
      __syncthreads();
      int ridx = rg*16 + erow_l;
      if (ridx < count){
        int tb = rowlist[ridx];
        int t = tb >> 7, bb_ = tb & 127;
        float hr = 0.f, hz = 0.f, hn = 0.f;
        #pragma unroll
        for (int kq2 = 0; kq2 < 4; ++kq2){
          hr += red[((((es*4 + kq2)*3 + 0)*64 + elane)*5) + ei];
          hz += red[((((es*4 + kq2)*3 + 1)*64 + elane)*5) + ei];
          hn += red[((((es*4 + kq2)*3 + 2)*64 + elane)*5) + ei];
        }
        size_t rb = ((size_t)t*BB + bb_)*3072 + ecol;
        float hold;
        if (j > 0) hold = (float)y[((size_t)(t-1)*BB + bb_)*HID + ecol];
        else       hold = hidden0[(size_t)bb_*HID + ecol];
        float r = 1.f / (1.f + expf(-((float)xi[rb]        + hr)));
        float z = 1.f / (1.f + expf(-((float)xi[rb + 1024] + hz)));
        float n = tanhf((float)xi[rb + 2048] + r * (hn + bh));
        float hnew = (1.f - z) * n + z * hold;
        y[((size_t)t*BB + bb_)*HID + ecol] = (f16)hnew;
        if (t == TT - 1) hout[(size_t)bb_*HID + ecol] = hnew;
      }
    }
    return;
  }

  // ---------- big path ----------
  const int wm = w >> 2, wn = w & 3;         // 2m x 4n
  const int nb = bid & 15;
  const int st = bid >> 4;                   // 64 M-strides
  const int hcolw = nb*64 + wn*16;
  const f16* Bg0 = bt2 + (size_t)(          hcolw + la) * 2048 + 1024 + lk;
  const f16* Bg1 = bt2 + (size_t)(1024 +    hcolw + la) * 2048 + 1024 + lk;
  const f16* Bg2 = bt2 + (size_t)(2048 +    hcolw + la) * 2048 + 1024 + lk;
  const int ntiles = (count + 127) >> 7;

  for (int tile = st; tile < ntiles; tile += 64){
    const char* hptr[4]; int hmode[4]; int sq[4]; int dby[4];
    #pragma unroll
    for (int q = 0; q < 4; ++q){
      int idx = tid + q*512;
      int r = idx >> 4; sq[q] = idx & 15;
      dby[q] = (r*256 + sq[q]*16) ^ ((r & 7) << 4);
      int ridx = tile*128 + r;
      int tb = (ridx < count) ? rowlist[ridx] : -1;
      hmode[q] = 0; hptr[q] = nullptr;
      if (tb >= 0){
        int t = tb >> 7, b = tb & 127;
        if (j > 0){ hmode[q] = 1; hptr[q] = (const char*)(y + ((size_t)(t-1)*BB + b)*HID); }
        else      { hmode[q] = 2; hptr[q] = (const char*)(hidden0 + (size_t)b*HID); }
      }
    }
    auto loadch = [&](int ch, float4* dst){
      #pragma unroll
      for (int q = 0; q < 4; ++q){
        float4 v = {0.f, 0.f, 0.f, 0.f};
        if (hmode[q] == 1){
          v = *reinterpret_cast<const float4*>((const f16*)hptr[q] + ch*128 + sq[q]*8);
        } else if (hmode[q] == 2){
          const float* s = (const float*)hptr[q] + ch*128 + sq[q]*8;
          float4 a0 = *reinterpret_cast<const float4*>(s);
          float4 a1 = *reinterpret_cast<const float4*>(s + 4);
          f16 h8[8] = {(f16)a0.x,(f16)a0.y,(f16)a0.z,(f16)a0.w,
                       (f16)a1.x,(f16)a1.y,(f16)a1.z,(f16)a1.w};
          v = *reinterpret_cast<float4*>(h8);
        }
        dst[q] = v;
      }
    };
    f32x4 ar[4] = {}, az[4] = {}, ahn[4] = {};
    float4 hv[4];
    loadch(0, hv);
    #pragma unroll 1
    for (int ch = 0; ch < 8; ++ch){
      __syncthreads();
      #pragma unroll
      for (int q = 0; q < 4; ++q)
        *reinterpret_cast<float4*>(smem + dby[q]) = hv[q];
      float4 hv2[4];
      if (ch < 7) loadch(ch+1, hv2);
      __syncthreads();
      const int kbase = ch*128;
      #pragma unroll
      for (int kk = 0; kk < 128; kk += 32){
        f16x8 av[4];
        #pragma unroll
        for (int m = 0; m < 4; ++m){
          int r = wm*64 + m*16 + la;
          av[m] = *reinterpret_cast<const f16x8*>(
              smem + ((r*256 + (kk + lk)*2) ^ ((r & 7) << 4)));
        }
        f16x8 b0 = *reinterpret_cast<const f16x8*>(Bg0 + kbase + kk);
        f16x8 b1 = *reinterpret_cast<const f16x8*>(Bg1 + kbase + kk);
        f16x8 b2 = *reinterpret_cast<const f16x8*>(Bg2 + kbase + kk);
        #pragma unroll
        for (int m = 0; m < 4; ++m){
          ar[m]  = mfma16(av[m], b0, ar[m]);
          az[m]  = mfma16(av[m], b1, az[m]);
          ahn[m] = mfma16(av[m], b2, ahn[m]);
        }
      }
      #pragma unroll
      for (int q = 0; q < 4; ++q) hv[q] = hv2[q];
    }
    {
      int hcol = hcolw + la;
      float bh = bhn_p[hcol];
      #pragma unroll
      for (int m = 0; m < 4; ++m){
        #pragma unroll
        for (int i = 0; i < 4; ++i){
          int lr = wm*64 + m*16 + (lane >> 4)*4 + i;
          int ridx = tile*128 + lr;
          if (ridx >= count) continue;
          int tb = rowlist[ridx];
          int t = tb >> 7, b = tb & 127;
          size_t rb = ((size_t)t*BB + b)*3072 + hcol;
          float hold;
          if (j > 0) hold = (float)y[((size_t)(t-1)*BB + b)*HID + hcol];
          else       hold = hidden0[(size_t)b*HID + hcol];
          float r = 1.f / (1.f + expf(-((float)xi[rb]        + ar[m][i])));
          float z = 1.f / (1.f + expf(-((float)xi[rb + 1024] + az[m][i])));
          float n = tanhf((float)xi[rb + 2048] + r * (ahn[m][i] + bh));
          float hnew = (1.f - z) * n + z * hold;
          y[((size_t)t*BB + b)*HID + hcol] = (f16)hnew;
          if (t == TT - 1) hout[(size_t)b*HID + hcol] = hnew;
        }
      }
    }
  }
}

// ---- sequential tail for chains longer than DPAR (empty for this seed) ----
__global__ __launch_bounds__(256)
void k_tail(const int* __restrict__ cnt, const int* __restrict__ chains,
            const f16* __restrict__ xi, const f16* __restrict__ bt2,
            const float* __restrict__ bhn_p, f16* __restrict__ y,
            float* __restrict__ hout){
  int n = cnt[25];
  __shared__ f16 hs[1024];
  int tid = threadIdx.x;
  for (int c = blockIdx.x; c < n; c += gridDim.x){
    int b = chains[c*3], t0 = chains[c*3+1], len = chains[c*3+2];
    for (int i = tid; i < 1024; i += 256)
      hs[i] = y[((size_t)(t0 + DPAR - 1)*BB + b)*HID + i];
    __syncthreads();
    for (int t = t0 + DPAR; t < t0 + len; ++t){
      float tmp[4];
      #pragma unroll
      for (int u = 0; u < 4; ++u){
        int col = tid*4 + u;
        float s_r = 0.f, s_z = 0.f, s_hn = 0.f;
        const f16* wr = bt2 + (size_t)col*2048 + 1024;
        const f16* wz = bt2 + (size_t)(1024+col)*2048 + 1024;
        const f16* wn = bt2 + (size_t)(2048+col)*2048 + 1024;
        for (int q = 0; q < 128; ++q){
          f16x8 hv = *reinterpret_cast<const f16x8*>(&hs[q*8]);
          f16x8 wrh = *reinterpret_cast<const f16x8*>(wr + q*8);
          f16x8 wzh = *reinterpret_cast<const f16x8*>(wz + q*8);
          f16x8 wnh = *reinterpret_cast<const f16x8*>(wn + q*8);
          #pragma unroll
          for (int e = 0; e < 8; ++e){
            float hh = (float)hv[e];
            s_r  += hh*(float)wrh[e];
            s_z  += hh*(float)wzh[e];
            s_hn += hh*(float)wnh[e];
          }
        }
        size_t rb = ((size_t)t*BB + b)*3072 + col;
        float r = 1.f / (1.f + expf(-((float)xi[rb] + s_r)));
        float z = 1.f / (1.f + expf(-((float)xi[rb + 1024] + s_z)));
        float nn = tanhf((float)xi[rb + 2048] + r * (s_hn + bhn_p[col]));
        float hold = (float)hs[col];
        float hnew = (1.f - z) * nn + z * hold;
        y[((size_t)t*BB + b)*HID + col] = (f16)hnew;
        if (t == TT - 1) hout[(size_t)b*HID + col] = hnew;
        tmp[u] = hnew;
      }
      __syncthreads();
      #pragma unroll
      for (int u = 0; u < 4; ++u) hs[tid*4 + u] = (f16)tmp[u];
      __syncthreads();
    }
    __syncthreads();
  }
}

// ---- critic: m97 structure (global_load_lds, 128x128, BK=64) + value fusion ----
__global__ __launch_bounds__(256)
void k_critic(const f16* __restrict__ Y, const f16* __restrict__ Bt,
              const float* __restrict__ b1, const float* __restrict__ W2,
              float* __restrict__ vpart){
  __shared__ __attribute__((aligned(16))) char smem[32768];
  int tid = threadIdx.x;
  int w = tid >> 6, lane = tid & 63;
  int wm = w >> 1, wn = w & 1;
  int bid = blockIdx.x;
  int vid = (bid & 7) * 128 + (bid >> 3);
  int Mb = (vid >> 3) * 128, Nb = (vid & 7) * 128;
  int la = lane & 15, lk = (lane >> 4) * 8;
  f32x4 acc[4][4] = {};
  int pr[4], pc16[4];
  #pragma unroll
  for (int q = 0; q < 4; ++q){
    int P = (w*4 + q)*1024 + lane*16;
    int r = P >> 7;
    pr[q] = r;
    pc16[q] = ((P & 127) ^ ((r & 7) << 4)) >> 4;
  }
  for (int kt = 0; kt < 16; ++kt){
    __syncthreads();
    #pragma unroll
    for (int q = 0; q < 4; ++q){
      gload16(Y  + (size_t)(Mb + pr[q])*HID + kt*64 + pc16[q]*8,
              smem + (w*4 + q)*1024);
      gload16(Bt + (size_t)(Nb + pr[q])*HID + kt*64 + pc16[q]*8,
              smem + 16384 + (w*4 + q)*1024);
    }
    __syncthreads();
    #pragma unroll
    for (int kk = 0; kk < 64; kk += 32){
      f16x8 av[4], bv[4];
      #pragma unroll
      for (int m = 0; m < 4; ++m){
        int r = wm*64 + m*16 + la;
        av[m] = *reinterpret_cast<const f16x8*>(
            smem + r*128 + (((kk + lk)*2) ^ ((r & 7) << 4)));
      }
      #pragma unroll
      for (int n = 0; n < 4; ++n){
        int r = wn*64 + n*16 + la;
        bv[n] = *reinterpret_cast<const f16x8*>(
            smem + 16384 + r*128 + (((kk + lk)*2) ^ ((r & 7) << 4)));
      }
      #pragma unroll
      for (int m = 0; m < 4; ++m)
        #pragma unroll
        for (int n = 0; n < 4; ++n)
          acc[m][n] = mfma16(av[m], bv[n], acc[m][n]);
    }
  }
  __syncthreads();
  __shared__ float vs[2][64][2];
  float p[4][4];
  for (int mi = 0; mi < 4; ++mi) for (int i = 0; i < 4; ++i) p[mi][i] = 0.f;
  for (int ni = 0; ni < 4; ++ni){
    int col = Nb + wn*64 + ni*16 + la;
    float bb = b1[col], w2 = W2[col];
    for (int mi = 0; mi < 4; ++mi)
      for (int i = 0; i < 4; ++i){
        float c = acc[mi][ni][i] + bb;
        p[mi][i] += (c > 0.f ? c : 0.f) * w2;
      }
  }
  for (int mi = 0; mi < 4; ++mi) for (int i = 0; i < 4; ++i){
    float s = p[mi][i];
    s += __shfl_xor(s, 1); s += __shfl_xor(s, 2);
    s += __shfl_xor(s, 4); s += __shfl_xor(s, 8);
    p[mi][i] = s;
  }
  if (la == 0){
    int q = lane >> 4;
    for (int mi = 0; mi < 4; ++mi)
      for (int i = 0; i < 4; ++i)
        vs[wm][mi*16 + q*4 + i][wn] = p[mi][i];
  }
  __syncthreads();
  if (threadIdx.x < 128){
    int rw = threadIdx.x;
    float s = vs[rw >> 6][rw & 63][0] + vs[rw >> 6][rw & 63][1];
    vpart[(size_t)(Nb >> 7) * (TT*BB) + Mb + rw] = s;
  }
}

__global__ void k_vreduce(const float* __restrict__ vpart, const float* __restrict__ b2,
                          float* __restrict__ outv){
  int m = blockIdx.x * 256 + threadIdx.x;
  float s = b2[0];
  for (int nb = 0; nb < 8; ++nb) s += vpart[(size_t)nb * (TT*BB) + m];
  outv[m] = s;
}

extern "C" void kernel_launch(void* const* d_in, const int* in_sizes, int n_in,
                              void* d_out, int out_size, void* d_ws, size_t ws_size,
                              hipStream_t stream){
  const float* hidden = (const float*)d_in[0];
  const float* world  = (const float*)d_in[1];
  const int*   dones  = (const int*)d_in[2];
  const float* W_emb  = (const float*)d_in[3];
  const float* b_emb  = (const float*)d_in[4];
  const float* Wi     = (const float*)d_in[5];
  const float* bi     = (const float*)d_in[6];
  const float* Wh     = (const float*)d_in[7];
  const float* bhn    = (const float*)d_in[8];
  const float* W1     = (const float*)d_in[9];
  const float* b1     = (const float*)d_in[10];
  const float* W2     = (const float*)d_in[11];
  const float* b2     = (const float*)d_in[12];
  float* out = (float*)d_out;

  char* p = (char*)d_ws;
  auto alloc = [&](size_t bytes) -> char* {
    char* r = p; p += (bytes + 255) & ~(size_t)255; return r;
  };
  f16*   ws16   = (f16*)alloc((size_t)TT*BB*OBSD*2);     // 16 MB
  f16*   wembt  = (f16*)alloc((size_t)HID*OBSD*2);       // 1 MB
  f16*   emb16  = (f16*)alloc((size_t)TT*BB*HID*2);      // 33.5 MB
  f16*   bt2    = (f16*)alloc((size_t)3072*2048*2);      // 12.6 MB
  f16*   w1t    = (f16*)alloc((size_t)HID*HID*2);        // 2 MB
  f16*   xi16   = (f16*)alloc((size_t)TT*BB*3072*2);     // 100.7 MB
  f16*   ybuf   = (f16*)alloc((size_t)TT*BB*HID*2);      // 33.5 MB
  float* vpart  = (float*)alloc((size_t)8*TT*BB*4);      // 0.5 MB
  int*   cnt    = (int*)alloc(26*4);
  int*   rowlist= (int*)alloc((size_t)DPAR*BUCKCAP*4);   // 1.57 MB
  int*   zlist  = (int*)alloc((size_t)BUCKCAP*4);
  int*   chains = (int*)alloc((size_t)1024*3*4);
  if ((size_t)(p - (char*)d_ws) > ws_size) return;

  hipMemsetAsync(cnt, 0, 26*4, stream);

  // preps (+ segmentation, depends only on dones)
  k_ws_to_f16<<<(TT*BB*OBSD/4 + 255)/256, 256, 0, stream>>>(world, ws16, TT*BB*OBSD/4);
  k_prep_bt<<<dim3(OBSD/64, HID/64), 256, 0, stream>>>(W_emb, 1024, wembt, OBSD);
  k_prep_bt2<<<dim3(2048/64, 3072/64), 256, 0, stream>>>(Wi, Wh, bt2);
  k_prep_bt<<<dim3(HID/64, HID/64), 256, 0, stream>>>(W1, 1024, w1t, HID);
  k_seg<<<1, 128, 0, stream>>>(dones, cnt, rowlist, zlist, chains);

  // parallel GEMMs
  k_emb<<<1024, 256, 0, stream>>>(ws16, wembt, b_emb, emb16);
  k_xi<<<3072, 256, 0, stream>>>(emb16, bt2, bi, xi16);

  // h-zero rows (no GEMM) + depth-parallel GRU scan + tail
  k_h0<<<2048, 256, 0, stream>>>(cnt, zlist, xi16, bhn, ybuf, out);
  for (int j = 0; j < DPAR; ++j)
    k_depth<<<1024, 512, 0, stream>>>(j, cnt, rowlist, xi16, bt2, bhn,
                                      hidden, ybuf, out);
  k_tail<<<128, 256, 0, stream>>>(cnt, chains, xi16, bt2, bhn, ybuf, out);

  // critic head + value
  k_critic<<<1024, 256, 0, stream>>>(ybuf, w1t, b1, W2, vpart);
  k_vreduce<<<TT*BB/256, 256, 0, stream>>>(vpart, b2, out + (size_t)BB*HID);
}

// Round 20
// 675.622 us; speedup vs baseline: 4.0317x; 1.2458x over previous
//
#include <hip/hip_runtime.h>
#include <stdint.h>

#define TT 128
#define BB 128
#define OBSD 512
#define HID 1024
#define DPAR 24
#define BUCKCAP 16384

typedef _Float16 f16;
typedef _Float16 f16x8 __attribute__((ext_vector_type(8)));
typedef _Float16 f16x4 __attribute__((ext_vector_type(4)));
typedef float f32x4 __attribute__((ext_vector_type(4)));

__device__ __forceinline__ f32x4 mfma16(f16x8 a, f16x8 b, f32x4 c){
  return __builtin_amdgcn_mfma_f32_16x16x32_f16(a, b, c, 0, 0, 0);
}
__device__ __forceinline__ void gload16(const void* g, void* l){
  __builtin_amdgcn_global_load_lds(
      (const __attribute__((address_space(1))) unsigned int*)g,
      (__attribute__((address_space(3))) unsigned int*)l, 16, 0, 0);
}

// ---- prep: world_state f32 -> f16 ----
__global__ void k_ws_to_f16(const float* __restrict__ src, f16* __restrict__ dst, int n4){
  int i = blockIdx.x * blockDim.x + threadIdx.x;
  if (i < n4){
    float4 v = *reinterpret_cast<const float4*>(src + (size_t)i * 4);
    dst[(size_t)i*4 + 0] = (f16)v.x; dst[(size_t)i*4 + 1] = (f16)v.y;
    dst[(size_t)i*4 + 2] = (f16)v.z; dst[(size_t)i*4 + 3] = (f16)v.w;
  }
}

// ---- prep: transpose f32 [KD][C] (row stride srcStride) -> f16 dst[C][KD] ----
__global__ void k_prep_bt(const float* __restrict__ s0, int srcStride,
                          f16* __restrict__ dst, int KD){
  __shared__ f16 sm[64][65];
  int k0 = blockIdx.x * 64, c0 = blockIdx.y * 64;
  for (int it = 0; it < 16; ++it){
    int idx = it * 256 + threadIdx.x;
    int kr = idx >> 6, cc = idx & 63;
    sm[kr][cc] = (f16)s0[(size_t)(k0 + kr) * srcStride + (c0 + cc)];
  }
  __syncthreads();
  for (int it = 0; it < 16; ++it){
    int idx = it * 256 + threadIdx.x;
    int cr = idx >> 6, kc = idx & 63;
    dst[(size_t)(c0 + cr) * KD + (k0 + kc)] = sm[kc][cr];
  }
}

// ---- prep: bt2[c][k] = k<1024 ? Wi[k][c] : Wh[k-1024][c]; c<3072, k<2048 ----
__global__ void k_prep_bt2(const float* __restrict__ wi, const float* __restrict__ wh,
                           f16* __restrict__ dst){
  __shared__ f16 sm[64][65];
  int k0 = blockIdx.x * 64, c0 = blockIdx.y * 64;
  const float* src = (k0 < 1024) ? wi : wh;
  int kb = (k0 < 1024) ? k0 : k0 - 1024;
  for (int it = 0; it < 16; ++it){
    int idx = it * 256 + threadIdx.x;
    int kr = idx >> 6, cc = idx & 63;
    sm[kr][cc] = (f16)src[(size_t)(kb + kr) * 3072 + (c0 + cc)];
  }
  __syncthreads();
  for (int it = 0; it < 16; ++it){
    int idx = it * 256 + threadIdx.x;
    int cr = idx >> 6, kc = idx & 63;
    dst[(size_t)(c0 + cr) * 2048 + (k0 + kc)] = sm[kc][cr];
  }
}

// ---- segmentation v6: (t,b)-parallel, O(1)/thread bit math, ballot ranks ----
// 128 blocks (one per b) x 128 threads (one per t). Buckets: 0..23 rowlist,
// 24 zlist, 25 chains. One atomicAdd per (block, nonempty bucket).
__global__ void k_seg(const int* __restrict__ dones, int* __restrict__ cnt,
                      int* __restrict__ rowlist, int* __restrict__ zlist,
                      int* __restrict__ chains){
  __shared__ unsigned long long sm_m[2];
  __shared__ int cntw[2][26];
  __shared__ int lbase[26];
  const int b = blockIdx.x, t = threadIdx.x;
  const int wv = t >> 6, lane = t & 63;
  bool pred = (t >= 1) && (dones[t*BB + b] != 0);
  unsigned long long bal = __ballot(pred);
  if (lane == 0) sm_m[wv] = bal;
  __syncthreads();
  const unsigned long long m0 = sm_m[0], m1 = sm_m[1];
  const bool d0 = (dones[b] != 0);
  // segment start s (highest boundary bit <= t, else 0), end e (next > t, else TT)
  int s, e;
  if (t < 64){
    unsigned long long msk = (t == 63) ? ~0ull : ((1ull << (t+1)) - 1);
    unsigned long long lo = m0 & msk;
    s = lo ? 63 - __builtin_clzll(lo) : 0;
    unsigned long long rem = m0 & ~msk;
    if (rem) e = __builtin_ctzll(rem);
    else if (m1) e = 64 + __builtin_ctzll(m1);
    else e = TT;
  } else {
    int u = t - 64;
    unsigned long long msk = (u == 63) ? ~0ull : ((1ull << (u+1)) - 1);
    unsigned long long hi = m1 & msk;
    if (hi) s = 64 + 63 - __builtin_clzll(hi);
    else s = m0 ? 63 - __builtin_clzll(m0) : 0;
    unsigned long long rem = m1 & ~msk;
    e = rem ? 64 + __builtin_ctzll(rem) : TT;
  }
  const int d = t - s;
  int my_d;
  if (d == 0)            my_d = (s == 0 && !d0) ? 0 : 24;
  else if (d < DPAR)     my_d = d;
  else if (d == DPAR)    my_d = 25;           // unique chain registrar
  else                   my_d = 26;           // tail-covered, no bucket
  // intra-block rank per bucket via uniform ballot rounds
  int my_rank = 0;
  for (int d2 = 0; d2 < 26; ++d2){
    unsigned long long mk = __ballot(my_d == d2);
    if (my_d == d2) my_rank = __popcll(mk & ((1ull << lane) - 1));
    if (lane == 0) cntw[wv][d2] = __popcll(mk);
  }
  __syncthreads();
  if (wv == 1 && my_d < 26) my_rank += cntw[0][my_d];
  if (t < 26){
    int tot = cntw[0][t] + cntw[1][t];
    lbase[t] = tot ? atomicAdd(&cnt[t], tot) : 0;
  }
  __syncthreads();
  if (my_d < 24){
    rowlist[my_d*BUCKCAP + lbase[my_d] + my_rank] = (t << 7) | b;
  } else if (my_d == 24){
    zlist[lbase[24] + my_rank] = (t << 7) | b;     // t == s for d==0 rows
  } else if (my_d == 25){
    int c = lbase[25] + my_rank;
    chains[c*3+0] = b; chains[c*3+1] = s; chains[c*3+2] = e - s;
  }
}

// ---- emb = relu(ws @ W_emb + b_emb): m97 structure, K=512 (8 kt-steps) ----
__global__ __launch_bounds__(256)
void k_emb(const f16* __restrict__ A, const f16* __restrict__ Bt,
           const float* __restrict__ bias, f16* __restrict__ outb){
  __shared__ __attribute__((aligned(16))) char smem[32768];
  int tid = threadIdx.x;
  int w = tid >> 6, lane = tid & 63;
  int wm = w >> 1, wn = w & 1;
  int bid = blockIdx.x;                       // 1024 = 128 Mb x 8 Nb
  int vid = (bid & 7) * 128 + (bid >> 3);
  int Mb = (vid >> 3) * 128, Nb = (vid & 7) * 128;
  int la = lane & 15, lk = (lane >> 4) * 8;
  f32x4 acc[4][4] = {};
  int pr[4], pc16[4];
  #pragma unroll
  for (int q = 0; q < 4; ++q){
    int P = (w*4 + q)*1024 + lane*16;
    int r = P >> 7;
    pr[q] = r;
    pc16[q] = ((P & 127) ^ ((r & 7) << 4)) >> 4;
  }
  for (int kt = 0; kt < 8; ++kt){
    __syncthreads();
    #pragma unroll
    for (int q = 0; q < 4; ++q){
      gload16(A  + (size_t)(Mb + pr[q])*OBSD + kt*64 + pc16[q]*8,
              smem + (w*4 + q)*1024);
      gload16(Bt + (size_t)(Nb + pr[q])*OBSD + kt*64 + pc16[q]*8,
              smem + 16384 + (w*4 + q)*1024);
    }
    __syncthreads();
    #pragma unroll
    for (int kk = 0; kk < 64; kk += 32){
      f16x8 av[4], bv[4];
      #pragma unroll
      for (int m = 0; m < 4; ++m){
        int r = wm*64 + m*16 + la;
        av[m] = *reinterpret_cast<const f16x8*>(
            smem + r*128 + (((kk + lk)*2) ^ ((r & 7) << 4)));
      }
      #pragma unroll
      for (int n = 0; n < 4; ++n){
        int r = wn*64 + n*16 + la;
        bv[n] = *reinterpret_cast<const f16x8*>(
            smem + 16384 + r*128 + (((kk + lk)*2) ^ ((r & 7) << 4)));
      }
      #pragma unroll
      for (int m = 0; m < 4; ++m)
        #pragma unroll
        for (int n = 0; n < 4; ++n)
          acc[m][n] = mfma16(av[m], bv[n], acc[m][n]);
    }
  }
  for (int mi = 0; mi < 4; ++mi) for (int ni = 0; ni < 4; ++ni){
    int col = Nb + wn*64 + ni*16 + la;
    float bb = bias[col];
    for (int i = 0; i < 4; ++i){
      int row = Mb + wm*64 + mi*16 + (lane >> 4)*4 + i;
      float v = acc[mi][ni][i] + bb;
      outb[(size_t)row * HID + col] = (f16)(v > 0.f ? v : 0.f);
    }
  }
}

// ---- xi = emb @ Wi + bi: m97 structure (global_load_lds, 128x128, BK=64) ----
__global__ __launch_bounds__(256)
void k_xi(const f16* __restrict__ A, const f16* __restrict__ Bt,
          const float* __restrict__ bias, f16* __restrict__ outb){
  __shared__ __attribute__((aligned(16))) char smem[32768];
  int tid = threadIdx.x;
  int w = tid >> 6, lane = tid & 63;
  int wm = w >> 1, wn = w & 1;
  int bid = blockIdx.x;                       // 3072 = 128 Mb x 24 Nb
  int vid = (bid & 7) * 384 + (bid >> 3);
  int Mb = (vid / 24) * 128, Nb = (vid % 24) * 128;
  int la = lane & 15, lk = (lane >> 4) * 8;
  f32x4 acc[4][4] = {};
  int pr[4], pc16[4];
  #pragma unroll
  for (int q = 0; q < 4; ++q){
    int P = (w*4 + q)*1024 + lane*16;
    int r = P >> 7;
    pr[q] = r;
    pc16[q] = ((P & 127) ^ ((r & 7) << 4)) >> 4;
  }
  for (int kt = 0; kt < 16; ++kt){
    __syncthreads();
    #pragma unroll
    for (int q = 0; q < 4; ++q){
      gload16(A  + (size_t)(Mb + pr[q])*HID  + kt*64 + pc16[q]*8,
              smem + (w*4 + q)*1024);
      gload16(Bt + (size_t)(Nb + pr[q])*2048 + kt*64 + pc16[q]*8,
              smem + 16384 + (w*4 + q)*1024);
    }
    __syncthreads();
    #pragma unroll
    for (int kk = 0; kk < 64; kk += 32){
      f16x8 av[4], bv[4];
      #pragma unroll
      for (int m = 0; m < 4; ++m){
        int r = wm*64 + m*16 + la;
        av[m] = *reinterpret_cast<const f16x8*>(
            smem + r*128 + (((kk + lk)*2) ^ ((r & 7) << 4)));
      }
      #pragma unroll
      for (int n = 0; n < 4; ++n){
        int r = wn*64 + n*16 + la;
        bv[n] = *reinterpret_cast<const f16x8*>(
            smem + 16384 + r*128 + (((kk + lk)*2) ^ ((r & 7) << 4)));
      }
      #pragma unroll
      for (int m = 0; m < 4; ++m)
        #pragma unroll
        for (int n = 0; n < 4; ++n)
          acc[m][n] = mfma16(av[m], bv[n], acc[m][n]);
    }
  }
  for (int mi = 0; mi < 4; ++mi) for (int ni = 0; ni < 4; ++ni){
    int col = Nb + wn*64 + ni*16 + la;
    float bb = bias[col];
    for (int i = 0; i < 4; ++i){
      int row = Mb + wm*64 + mi*16 + (lane >> 4)*4 + i;
      outb[(size_t)row * 3072 + col] = (f16)(acc[mi][ni][i] + bb);
    }
  }
}

// ---- h-zero rows: h = (1-z)*n, straight from xi (no GEMM) ----
__global__ __launch_bounds__(256)
void k_h0(const int* __restrict__ cnt, const int* __restrict__ zlist,
          const f16* __restrict__ xi, const float* __restrict__ bhn_p,
          f16* __restrict__ y, float* __restrict__ hout){
  int nz = cnt[24];
  int tid = threadIdx.x;
  for (int ridx = blockIdx.x; ridx < nz; ridx += gridDim.x){
    int tb = zlist[ridx];
    int t = tb >> 7, b = tb & 127;
    size_t rb = ((size_t)t*BB + b) * 3072;
    int c0 = tid * 4;
    f16x4 xr = *reinterpret_cast<const f16x4*>(xi + rb + c0);
    f16x4 xz = *reinterpret_cast<const f16x4*>(xi + rb + 1024 + c0);
    f16x4 xn = *reinterpret_cast<const f16x4*>(xi + rb + 2048 + c0);
    f16x4 o;
    #pragma unroll
    for (int u = 0; u < 4; ++u){
      float r = 1.f / (1.f + expf(-(float)xr[u]));
      float z = 1.f / (1.f + expf(-(float)xz[u]));
      float n = tanhf((float)xn[u] + r * bhn_p[c0 + u]);
      float h = (1.f - z) * n;
      o[u] = (f16)h;
      if (t == TT - 1) hout[(size_t)b*HID + c0 + u] = h;
    }
    *reinterpret_cast<f16x4*>(y + ((size_t)t*BB + b)*HID + c0) = o;
  }
}

// ---- depth-j GRU step: h_prev @ Wh, K=1024; gates from xi in epilogue ----
// big path (count>1024): BM=128 x BN=192, reg-staged pipeline.
// small path (count<=1024): 16 rows x 32 hcols/block, 8 waves = 2 cs x 4 kq.
__global__ __launch_bounds__(512)
void k_depth(int j, const int* __restrict__ cnt, const int* __restrict__ rowlist_g,
             const f16* __restrict__ xi, const f16* __restrict__ bt2,
             const float* __restrict__ bhn_p, const float* __restrict__ hidden0,
             f16* __restrict__ y, float* __restrict__ hout){
  __shared__ __attribute__((aligned(16))) char smem[32768];
  const int count = cnt[j];
  if (count <= 0) return;
  const int* rowlist = rowlist_g + (size_t)j * BUCKCAP;
  const int tid = threadIdx.x;
  const int lane = tid & 63;
  const int w = tid >> 6;                    // 8 waves
  const int bid = blockIdx.x;
  const int la = lane & 15, lk = (lane >> 4) * 8;

  if (count <= 1024){
    // ---------- small path ----------
    float* red = (float*)smem;               // [2][4][3][64][5] = 30720 B
    const int vid = (bid & 7) * 128 + (bid >> 3);
    const int cs2 = vid >> 5;                // [0,32): 32 hcols
    const int rgs = vid & 31;                // rowgroup stride start
    const int cg = w >> 2, kq = w & 3;       // colslice, K-chunk
    const f16* Bq0 = bt2 + (size_t)(          cs2*32 + cg*16 + la)*2048 + 1024 + kq*256 + lk;
    const f16* Bq1 = bt2 + (size_t)(1024 +    cs2*32 + cg*16 + la)*2048 + 1024 + kq*256 + lk;
    const f16* Bq2 = bt2 + (size_t)(2048 +    cs2*32 + cg*16 + la)*2048 + 1024 + kq*256 + lk;
    const int es = tid >> 8, ei = (tid >> 6) & 3, elane = tid & 63;
    const int erow_l = ((elane >> 4) << 2) + ei;
    const int ecol = cs2*32 + es*16 + (elane & 15);
    const float bh = bhn_p[ecol];
    const int nrg = (count + 15) >> 4;
    for (int rg = rgs; rg < nrg; rg += 32){
      __syncthreads();
      #pragma unroll
      for (int it = 0; it < 4; ++it){        // 512 thr x 4 = 16 rows x 128 parts
        int idx = tid + it*512;
        int r = idx >> 7, part = idx & 127;
        int ridx = rg*16 + r;
        int tb = (ridx < count) ? rowlist[ridx] : -1;
        float4 v = {0.f, 0.f, 0.f, 0.f};
        if (tb >= 0){
          int t = tb >> 7, bb_ = tb & 127;
          if (j > 0){
            v = *reinterpret_cast<const float4*>(y + ((size_t)(t-1)*BB + bb_)*HID + part*8);
          } else {
            const float* s = hidden0 + (size_t)bb_*HID + part*8;
            float4 a0 = *reinterpret_cast<const float4*>(s);
            float4 a1 = *reinterpret_cast<const float4*>(s + 4);
            f16 h8[8] = {(f16)a0.x,(f16)a0.y,(f16)a0.z,(f16)a0.w,
                         (f16)a1.x,(f16)a1.y,(f16)a1.z,(f16)a1.w};
            v = *reinterpret_cast<float4*>(h8);
          }
        }
        *reinterpret_cast<float4*>(smem + ((r*2048 + part*16) ^ ((r & 7) << 4))) = v;
      }
      __syncthreads();
      f32x4 a0 = {}, a1 = {}, a2 = {};
      #pragma unroll
      for (int kk = 0; kk < 256; kk += 32){
        int k = kq*256 + kk + lk;
        f16x8 av = *reinterpret_cast<const f16x8*>(
            smem + ((la*2048 + k*2) ^ ((la & 7) << 4)));
        a0 = mfma16(av, *reinterpret_cast<const f16x8*>(Bq0 + kk), a0);
        a1 = mfma16(av, *reinterpret_cast<const f16x8*>(Bq1 + kk), a1);
        a2 = mfma16(av, *reinterpret_cast<const f16x8*>(Bq2 + kk), a2);
      }
      __syncthreads();
      #pragma unroll
      for (int i = 0; i < 4; ++i){
        red[((((cg*4 + kq)*3 + 0)*64 + lane)*5) + i] = a0[i];
        red[((((cg*4 + kq)*3 + 1)*64 + lane)*5) + i] = a1[i];
        red[((((cg*4 + kq)*3 + 2)*64 + lane)*5) + i] = a2[i];
      }
      __syncthreads();
      int ridx = rg*16 + erow_l;
      if (ridx < count){
        int tb = rowlist[ridx];
        int t = tb >> 7, bb_ = tb & 127;
        float hr = 0.f, hz = 0.f, hn = 0.f;
        #pragma unroll
        for (int kq2 = 0; kq2 < 4; ++kq2){
          hr += red[((((es*4 + kq2)*3 + 0)*64 + elane)*5) + ei];
          hz += red[((((es*4 + kq2)*3 + 1)*64 + elane)*5) + ei];
          hn += red[((((es*4 + kq2)*3 + 2)*64 + elane)*5) + ei];
        }
        size_t rb = ((size_t)t*BB + bb_)*3072 + ecol;
        float hold;
        if (j > 0) hold = (float)y[((size_t)(t-1)*BB + bb_)*HID + ecol];
        else       hold = hidden0[(size_t)bb_*HID + ecol];
        float r = 1.f / (1.f + expf(-((float)xi[rb]        + hr)));
        float z = 1.f / (1.f + expf(-((float)xi[rb + 1024] + hz)));
        float n = tanhf((float)xi[rb + 2048] + r * (hn + bh));
        float hnew = (1.f - z) * n + z * hold;
        y[((size_t)t*BB + bb_)*HID + ecol] = (f16)hnew;
        if (t == TT - 1) hout[(size_t)bb_*HID + ecol] = hnew;
      }
    }
    return;
  }

  // ---------- big path ----------
  const int wm = w >> 2, wn = w & 3;         // 2m x 4n
  const int nb = bid & 15;
  const int st = bid >> 4;                   // 64 M-strides
  const int hcolw = nb*64 + wn*16;
  const f16* Bg0 = bt2 + (size_t)(          hcolw + la) * 2048 + 1024 + lk;
  const f16* Bg1 = bt2 + (size_t)(1024 +    hcolw + la) * 2048 + 1024 + lk;
  const f16* Bg2 = bt2 + (size_t)(2048 +    hcolw + la) * 2048 + 1024 + lk;
  const int ntiles = (count + 127) >> 7;

  for (int tile = st; tile < ntiles; tile += 64){
    const char* hptr[4]; int hmode[4]; int sq[4]; int dby[4];
    #pragma unroll
    for (int q = 0; q < 4; ++q){
      int idx = tid + q*512;
      int r = idx >> 4; sq[q] = idx & 15;
      dby[q] = (r*256 + sq[q]*16) ^ ((r & 7) << 4);
      int ridx = tile*128 + r;
      int tb = (ridx < count) ? rowlist[ridx] : -1;
      hmode[q] = 0; hptr[q] = nullptr;
      if (tb >= 0){
        int t = tb >> 7, b = tb & 127;
        if (j > 0){ hmode[q] = 1; hptr[q] = (const char*)(y + ((size_t)(t-1)*BB + b)*HID); }
        else      { hmode[q] = 2; hptr[q] = (const char*)(hidden0 + (size_t)b*HID); }
      }
    }
    auto loadch = [&](int ch, float4* dst){
      #pragma unroll
      for (int q = 0; q < 4; ++q){
        float4 v = {0.f, 0.f, 0.f, 0.f};
        if (hmode[q] == 1){
          v = *reinterpret_cast<const float4*>((const f16*)hptr[q] + ch*128 + sq[q]*8);
        } else if (hmode[q] == 2){
          const float* s = (const float*)hptr[q] + ch*128 + sq[q]*8;
          float4 a0 = *reinterpret_cast<const float4*>(s);
          float4 a1 = *reinterpret_cast<const float4*>(s + 4);
          f16 h8[8] = {(f16)a0.x,(f16)a0.y,(f16)a0.z,(f16)a0.w,
                       (f16)a1.x,(f16)a1.y,(f16)a1.z,(f16)a1.w};
          v = *reinterpret_cast<float4*>(h8);
        }
        dst[q] = v;
      }
    };
    f32x4 ar[4] = {}, az[4] = {}, ahn[4] = {};
    float4 hv[4];
    loadch(0, hv);
    #pragma unroll 1
    for (int ch = 0; ch < 8; ++ch){
      __syncthreads();
      #pragma unroll
      for (int q = 0; q < 4; ++q)
        *reinterpret_cast<float4*>(smem + dby[q]) = hv[q];
      float4 hv2[4];
      if (ch < 7) loadch(ch+1, hv2);
      __syncthreads();
      const int kbase = ch*128;
      #pragma unroll
      for (int kk = 0; kk < 128; kk += 32){
        f16x8 av[4];
        #pragma unroll
        for (int m = 0; m < 4; ++m){
          int r = wm*64 + m*16 + la;
          av[m] = *reinterpret_cast<const f16x8*>(
              smem + ((r*256 + (kk + lk)*2) ^ ((r & 7) << 4)));
        }
        f16x8 b0 = *reinterpret_cast<const f16x8*>(Bg0 + kbase + kk);
        f16x8 b1 = *reinterpret_cast<const f16x8*>(Bg1 + kbase + kk);
        f16x8 b2 = *reinterpret_cast<const f16x8*>(Bg2 + kbase + kk);
        #pragma unroll
        for (int m = 0; m < 4; ++m){
          ar[m]  = mfma16(av[m], b0, ar[m]);
          az[m]  = mfma16(av[m], b1, az[m]);
          ahn[m] = mfma16(av[m], b2, ahn[m]);
        }
      }
      #pragma unroll
      for (int q = 0; q < 4; ++q) hv[q] = hv2[q];
    }
    {
      int hcol = hcolw + la;
      float bh = bhn_p[hcol];
      #pragma unroll
      for (int m = 0; m < 4; ++m){
        #pragma unroll
        for (int i = 0; i < 4; ++i){
          int lr = wm*64 + m*16 + (lane >> 4)*4 + i;
          int ridx = tile*128 + lr;
          if (ridx >= count) continue;
          int tb = rowlist[ridx];
          int t = tb >> 7, b = tb & 127;
          size_t rb = ((size_t)t*BB + b)*3072 + hcol;
          float hold;
          if (j > 0) hold = (float)y[((size_t)(t-1)*BB + b)*HID + hcol];
          else       hold = hidden0[(size_t)b*HID + hcol];
          float r = 1.f / (1.f + expf(-((float)xi[rb]        + ar[m][i])));
          float z = 1.f / (1.f + expf(-((float)xi[rb + 1024] + az[m][i])));
          float n = tanhf((float)xi[rb + 2048] + r * (ahn[m][i] + bh));
          float hnew = (1.f - z) * n + z * hold;
          y[((size_t)t*BB + b)*HID + hcol] = (f16)hnew;
          if (t == TT - 1) hout[(size_t)b*HID + hcol] = hnew;
        }
      }
    }
  }
}

// ---- sequential tail for chains longer than DPAR (empty for this seed) ----
__global__ __launch_bounds__(256)
void k_tail(const int* __restrict__ cnt, const int* __restrict__ chains,
            const f16* __restrict__ xi, const f16* __restrict__ bt2,
            const float* __restrict__ bhn_p, f16* __restrict__ y,
            float* __restrict__ hout){
  int n = cnt[25];
  __shared__ f16 hs[1024];
  int tid = threadIdx.x;
  for (int c = blockIdx.x; c < n; c += gridDim.x){
    int b = chains[c*3], t0 = chains[c*3+1], len = chains[c*3+2];
    for (int i = tid; i < 1024; i += 256)
      hs[i] = y[((size_t)(t0 + DPAR - 1)*BB + b)*HID + i];
    __syncthreads();
    for (int t = t0 + DPAR; t < t0 + len; ++t){
      float tmp[4];
      #pragma unroll
      for (int u = 0; u < 4; ++u){
        int col = tid*4 + u;
        float s_r = 0.f, s_z = 0.f, s_hn = 0.f;
        const f16* wr = bt2 + (size_t)col*2048 + 1024;
        const f16* wz = bt2 + (size_t)(1024+col)*2048 + 1024;
        const f16* wn = bt2 + (size_t)(2048+col)*2048 + 1024;
        for (int q = 0; q < 128; ++q){
          f16x8 hv = *reinterpret_cast<const f16x8*>(&hs[q*8]);
          f16x8 wrh = *reinterpret_cast<const f16x8*>(wr + q*8);
          f16x8 wzh = *reinterpret_cast<const f16x8*>(wz + q*8);
          f16x8 wnh = *reinterpret_cast<const f16x8*>(wn + q*8);
          #pragma unroll
          for (int e = 0; e < 8; ++e){
            float hh = (float)hv[e];
            s_r  += hh*(float)wrh[e];
            s_z  += hh*(float)wzh[e];
            s_hn += hh*(float)wnh[e];
          }
        }
        size_t rb = ((size_t)t*BB + b)*3072 + col;
        float r = 1.f / (1.f + expf(-((float)xi[rb] + s_r)));
        float z = 1.f / (1.f + expf(-((float)xi[rb + 1024] + s_z)));
        float nn = tanhf((float)xi[rb + 2048] + r * (s_hn + bhn_p[col]));
        float hold = (float)hs[col];
        float hnew = (1.f - z) * nn + z * hold;
        y[((size_t)t*BB + b)*HID + col] = (f16)hnew;
        if (t == TT - 1) hout[(size_t)b*HID + col] = hnew;
        tmp[u] = hnew;
      }
      __syncthreads();
      #pragma unroll
      for (int u = 0; u < 4; ++u) hs[tid*4 + u] = (f16)tmp[u];
      __syncthreads();
    }
    __syncthreads();
  }
}

// ---- critic: m97 structure (global_load_lds, 128x128, BK=64) + value fusion ----
__global__ __launch_bounds__(256)
void k_critic(const f16* __restrict__ Y, const f16* __restrict__ Bt,
              const float* __restrict__ b1, const float* __restrict__ W2,
              float* __restrict__ vpart){
  __shared__ __attribute__((aligned(16))) char smem[32768];
  int tid = threadIdx.x;
  int w = tid >> 6, lane = tid & 63;
  int wm = w >> 1, wn = w & 1;
  int bid = blockIdx.x;
  int vid = (bid & 7) * 128 + (bid >> 3);
  int Mb = (vid >> 3) * 128, Nb = (vid & 7) * 128;
  int la = lane & 15, lk = (lane >> 4) * 8;
  f32x4 acc[4][4] = {};
  int pr[4], pc16[4];
  #pragma unroll
  for (int q = 0; q < 4; ++q){
    int P = (w*4 + q)*1024 + lane*16;
    int r = P >> 7;
    pr[q] = r;
    pc16[q] = ((P & 127) ^ ((r & 7) << 4)) >> 4;
  }
  for (int kt = 0; kt < 16; ++kt){
    __syncthreads();
    #pragma unroll
    for (int q = 0; q < 4; ++q){
      gload16(Y  + (size_t)(Mb + pr[q])*HID + kt*64 + pc16[q]*8,
              smem + (w*4 + q)*1024);
      gload16(Bt + (size_t)(Nb + pr[q])*HID + kt*64 + pc16[q]*8,
              smem + 16384 + (w*4 + q)*1024);
    }
    __syncthreads();
    #pragma unroll
    for (int kk = 0; kk < 64; kk += 32){
      f16x8 av[4], bv[4];
      #pragma unroll
      for (int m = 0; m < 4; ++m){
        int r = wm*64 + m*16 + la;
        av[m] = *reinterpret_cast<const f16x8*>(
            smem + r*128 + (((kk + lk)*2) ^ ((r & 7) << 4)));
      }
      #pragma unroll
      for (int n = 0; n < 4; ++n){
        int r = wn*64 + n*16 + la;
        bv[n] = *reinterpret_cast<const f16x8*>(
            smem + 16384 + r*128 + (((kk + lk)*2) ^ ((r & 7) << 4)));
      }
      #pragma unroll
      for (int m = 0; m < 4; ++m)
        #pragma unroll
        for (int n = 0; n < 4; ++n)
          acc[m][n] = mfma16(av[m], bv[n], acc[m][n]);
    }
  }
  __syncthreads();
  __shared__ float vs[2][64][2];
  float p[4][4];
  for (int mi = 0; mi < 4; ++mi) for (int i = 0; i < 4; ++i) p[mi][i] = 0.f;
  for (int ni = 0; ni < 4; ++ni){
    int col = Nb + wn*64 + ni*16 + la;
    float bb = b1[col], w2 = W2[col];
    for (int mi = 0; mi < 4; ++mi)
      for (int i = 0; i < 4; ++i){
        float c = acc[mi][ni][i] + bb;
        p[mi][i] += (c > 0.f ? c : 0.f) * w2;
      }
  }
  for (int mi = 0; mi < 4; ++mi) for (int i = 0; i < 4; ++i){
    float s = p[mi][i];
    s += __shfl_xor(s, 1); s += __shfl_xor(s, 2);
    s += __shfl_xor(s, 4); s += __shfl_xor(s, 8);
    p[mi][i] = s;
  }
  if (la == 0){
    int q = lane >> 4;
    for (int mi = 0; mi < 4; ++mi)
      for (int i = 0; i < 4; ++i)
        vs[wm][mi*16 + q*4 + i][wn] = p[mi][i];
  }
  __syncthreads();
  if (threadIdx.x < 128){
    int rw = threadIdx.x;
    float s = vs[rw >> 6][rw & 63][0] + vs[rw >> 6][rw & 63][1];
    vpart[(size_t)(Nb >> 7) * (TT*BB) + Mb + rw] = s;
  }
}

__global__ void k_vreduce(const float* __restrict__ vpart, const float* __restrict__ b2,
                          float* __restrict__ outv){
  int m = blockIdx.x * 256 + threadIdx.x;
  float s = b2[0];
  for (int nb = 0; nb < 8; ++nb) s += vpart[(size_t)nb * (TT*BB) + m];
  outv[m] = s;
}

extern "C" void kernel_launch(void* const* d_in, const int* in_sizes, int n_in,
                              void* d_out, int out_size, void* d_ws, size_t ws_size,
                              hipStream_t stream){
  const float* hidden = (const float*)d_in[0];
  const float* world  = (const float*)d_in[1];
  const int*   dones  = (const int*)d_in[2];
  const float* W_emb  = (const float*)d_in[3];
  const float* b_emb  = (const float*)d_in[4];
  const float* Wi     = (const float*)d_in[5];
  const float* bi     = (const float*)d_in[6];
  const float* Wh     = (const float*)d_in[7];
  const float* bhn    = (const float*)d_in[8];
  const float* W1     = (const float*)d_in[9];
  const float* b1     = (const float*)d_in[10];
  const float* W2     = (const float*)d_in[11];
  const float* b2     = (const float*)d_in[12];
  float* out = (float*)d_out;

  char* p = (char*)d_ws;
  auto alloc = [&](size_t bytes) -> char* {
    char* r = p; p += (bytes + 255) & ~(size_t)255; return r;
  };
  f16*   ws16   = (f16*)alloc((size_t)TT*BB*OBSD*2);     // 16 MB
  f16*   wembt  = (f16*)alloc((size_t)HID*OBSD*2);       // 1 MB
  f16*   emb16  = (f16*)alloc((size_t)TT*BB*HID*2);      // 33.5 MB
  f16*   bt2    = (f16*)alloc((size_t)3072*2048*2);      // 12.6 MB
  f16*   w1t    = (f16*)alloc((size_t)HID*HID*2);        // 2 MB
  f16*   xi16   = (f16*)alloc((size_t)TT*BB*3072*2);     // 100.7 MB
  f16*   ybuf   = (f16*)alloc((size_t)TT*BB*HID*2);      // 33.5 MB
  float* vpart  = (float*)alloc((size_t)8*TT*BB*4);      // 0.5 MB
  int*   cnt    = (int*)alloc(26*4);
  int*   rowlist= (int*)alloc((size_t)DPAR*BUCKCAP*4);   // 1.57 MB
  int*   zlist  = (int*)alloc((size_t)BUCKCAP*4);
  int*   chains = (int*)alloc((size_t)1024*3*4);
  if ((size_t)(p - (char*)d_ws) > ws_size) return;

  hipMemsetAsync(cnt, 0, 26*4, stream);

  // preps (+ segmentation, depends only on dones)
  k_ws_to_f16<<<(TT*BB*OBSD/4 + 255)/256, 256, 0, stream>>>(world, ws16, TT*BB*OBSD/4);
  k_prep_bt<<<dim3(OBSD/64, HID/64), 256, 0, stream>>>(W_emb, 1024, wembt, OBSD);
  k_prep_bt2<<<dim3(2048/64, 3072/64), 256, 0, stream>>>(Wi, Wh, bt2);
  k_prep_bt<<<dim3(HID/64, HID/64), 256, 0, stream>>>(W1, 1024, w1t, HID);
  k_seg<<<128, 128, 0, stream>>>(dones, cnt, rowlist, zlist, chains);

  // parallel GEMMs
  k_emb<<<1024, 256, 0, stream>>>(ws16, wembt, b_emb, emb16);
  k_xi<<<3072, 256, 0, stream>>>(emb16, bt2, bi, xi16);

  // h-zero rows (no GEMM) + depth-parallel GRU scan + tail
  k_h0<<<2048, 256, 0, stream>>>(cnt, zlist, xi16, bhn, ybuf, out);
  for (int j = 0; j < DPAR; ++j)
    k_depth<<<1024, 512, 0, stream>>>(j, cnt, rowlist, xi16, bt2, bhn,
                                      hidden, ybuf, out);
  k_tail<<<128, 256, 0, stream>>>(cnt, chains, xi16, bt2, bhn, ybuf, out);

  // critic head + value
  k_critic<<<1024, 256, 0, stream>>>(ybuf, w1t, b1, W2, vpart);
  k_vreduce<<<TT*BB/256, 256, 0, stream>>>(vpart, b2, out + (size_t)BB*HID);
}

// Round 21
// 662.909 us; speedup vs baseline: 4.1090x; 1.0192x over previous
//
#include <hip/hip_runtime.h>
#include <stdint.h>

#define TT 128
#define BB 128
#define OBSD 512
#define HID 1024
#define DPAR 24
#define BUCKCAP 16384

typedef _Float16 f16;
typedef _Float16 f16x8 __attribute__((ext_vector_type(8)));
typedef _Float16 f16x4 __attribute__((ext_vector_type(4)));
typedef float f32x4 __attribute__((ext_vector_type(4)));

__device__ __forceinline__ f32x4 mfma16(f16x8 a, f16x8 b, f32x4 c){
  return __builtin_amdgcn_mfma_f32_16x16x32_f16(a, b, c, 0, 0, 0);
}
__device__ __forceinline__ void gload16(const void* g, void* l){
  __builtin_amdgcn_global_load_lds(
      (const __attribute__((address_space(1))) unsigned int*)g,
      (__attribute__((address_space(3))) unsigned int*)l, 16, 0, 0);
}

// ---- prep: world_state f32 -> f16 ----
__global__ void k_ws_to_f16(const float* __restrict__ src, f16* __restrict__ dst, int n4){
  int i = blockIdx.x * blockDim.x + threadIdx.x;
  if (i < n4){
    float4 v = *reinterpret_cast<const float4*>(src + (size_t)i * 4);
    dst[(size_t)i*4 + 0] = (f16)v.x; dst[(size_t)i*4 + 1] = (f16)v.y;
    dst[(size_t)i*4 + 2] = (f16)v.z; dst[(size_t)i*4 + 3] = (f16)v.w;
  }
}

// ---- prep: transpose f32 [KD][C] (row stride srcStride) -> f16 dst[C][KD] ----
__global__ void k_prep_bt(const float* __restrict__ s0, int srcStride,
                          f16* __restrict__ dst, int KD){
  __shared__ f16 sm[64][65];
  int k0 = blockIdx.x * 64, c0 = blockIdx.y * 64;
  for (int it = 0; it < 16; ++it){
    int idx = it * 256 + threadIdx.x;
    int kr = idx >> 6, cc = idx & 63;
    sm[kr][cc] = (f16)s0[(size_t)(k0 + kr) * srcStride + (c0 + cc)];
  }
  __syncthreads();
  for (int it = 0; it < 16; ++it){
    int idx = it * 256 + threadIdx.x;
    int cr = idx >> 6, kc = idx & 63;
    dst[(size_t)(c0 + cr) * KD + (k0 + kc)] = sm[kc][cr];
  }
}

// ---- prep: bt2[c][k] = k<1024 ? Wi[k][c] : Wh[k-1024][c]; c<3072, k<2048 ----
__global__ void k_prep_bt2(const float* __restrict__ wi, const float* __restrict__ wh,
                           f16* __restrict__ dst){
  __shared__ f16 sm[64][65];
  int k0 = blockIdx.x * 64, c0 = blockIdx.y * 64;
  const float* src = (k0 < 1024) ? wi : wh;
  int kb = (k0 < 1024) ? k0 : k0 - 1024;
  for (int it = 0; it < 16; ++it){
    int idx = it * 256 + threadIdx.x;
    int kr = idx >> 6, cc = idx & 63;
    sm[kr][cc] = (f16)src[(size_t)(kb + kr) * 3072 + (c0 + cc)];
  }
  __syncthreads();
  for (int it = 0; it < 16; ++it){
    int idx = it * 256 + threadIdx.x;
    int cr = idx >> 6, kc = idx & 63;
    dst[(size_t)(c0 + cr) * 2048 + (k0 + kc)] = sm[kc][cr];
  }
}

// ---- segmentation v6: (t,b)-parallel, O(1)/thread bit math, ballot ranks ----
__global__ void k_seg(const int* __restrict__ dones, int* __restrict__ cnt,
                      int* __restrict__ rowlist, int* __restrict__ zlist,
                      int* __restrict__ chains){
  __shared__ unsigned long long sm_m[2];
  __shared__ int cntw[2][26];
  __shared__ int lbase[26];
  const int b = blockIdx.x, t = threadIdx.x;
  const int wv = t >> 6, lane = t & 63;
  bool pred = (t >= 1) && (dones[t*BB + b] != 0);
  unsigned long long bal = __ballot(pred);
  if (lane == 0) sm_m[wv] = bal;
  __syncthreads();
  const unsigned long long m0 = sm_m[0], m1 = sm_m[1];
  const bool d0 = (dones[b] != 0);
  int s, e;
  if (t < 64){
    unsigned long long msk = (t == 63) ? ~0ull : ((1ull << (t+1)) - 1);
    unsigned long long lo = m0 & msk;
    s = lo ? 63 - __builtin_clzll(lo) : 0;
    unsigned long long rem = m0 & ~msk;
    if (rem) e = __builtin_ctzll(rem);
    else if (m1) e = 64 + __builtin_ctzll(m1);
    else e = TT;
  } else {
    int u = t - 64;
    unsigned long long msk = (u == 63) ? ~0ull : ((1ull << (u+1)) - 1);
    unsigned long long hi = m1 & msk;
    if (hi) s = 64 + 63 - __builtin_clzll(hi);
    else s = m0 ? 63 - __builtin_clzll(m0) : 0;
    unsigned long long rem = m1 & ~msk;
    e = rem ? 64 + __builtin_ctzll(rem) : TT;
  }
  const int d = t - s;
  int my_d;
  if (d == 0)            my_d = (s == 0 && !d0) ? 0 : 24;
  else if (d < DPAR)     my_d = d;
  else if (d == DPAR)    my_d = 25;
  else                   my_d = 26;
  int my_rank = 0;
  for (int d2 = 0; d2 < 26; ++d2){
    unsigned long long mk = __ballot(my_d == d2);
    if (my_d == d2) my_rank = __popcll(mk & ((1ull << lane) - 1));
    if (lane == 0) cntw[wv][d2] = __popcll(mk);
  }
  __syncthreads();
  if (wv == 1 && my_d < 26) my_rank += cntw[0][my_d];
  if (t < 26){
    int tot = cntw[0][t] + cntw[1][t];
    lbase[t] = tot ? atomicAdd(&cnt[t], tot) : 0;
  }
  __syncthreads();
  if (my_d < 24){
    rowlist[my_d*BUCKCAP + lbase[my_d] + my_rank] = (t << 7) | b;
  } else if (my_d == 24){
    zlist[lbase[24] + my_rank] = (t << 7) | b;
  } else if (my_d == 25){
    int c = lbase[25] + my_rank;
    chains[c*3+0] = b; chains[c*3+1] = s; chains[c*3+2] = e - s;
  }
}

// ---- emb = relu(ws @ W_emb + b_emb): m97 + 2-phase dbuf, K=512 (8 kt) ----
__global__ __launch_bounds__(256)
void k_emb(const f16* __restrict__ A, const f16* __restrict__ Bt,
           const float* __restrict__ bias, f16* __restrict__ outb){
  __shared__ __attribute__((aligned(16))) char smem[65536];   // 2 x (As 16K | Bs 16K)
  int tid = threadIdx.x;
  int w = tid >> 6, lane = tid & 63;
  int wm = w >> 1, wn = w & 1;
  int bid = blockIdx.x;                       // 1024 = 128 Mb x 8 Nb
  int vid = (bid & 7) * 128 + (bid >> 3);
  int Mb = (vid >> 3) * 128, Nb = (vid & 7) * 128;
  int la = lane & 15, lk = (lane >> 4) * 8;
  f32x4 acc[4][4] = {};
  int pr[4], pc16[4];
  #pragma unroll
  for (int q = 0; q < 4; ++q){
    int P = (w*4 + q)*1024 + lane*16;
    int r = P >> 7;
    pr[q] = r;
    pc16[q] = ((P & 127) ^ ((r & 7) << 4)) >> 4;
  }
  #pragma unroll
  for (int q = 0; q < 4; ++q){                // prologue: stage kt=0 -> buf0
    gload16(A  + (size_t)(Mb + pr[q])*OBSD + pc16[q]*8, smem + (w*4 + q)*1024);
    gload16(Bt + (size_t)(Nb + pr[q])*OBSD + pc16[q]*8, smem + 16384 + (w*4 + q)*1024);
  }
  __syncthreads();
  for (int kt = 0; kt < 8; ++kt){
    const int cb = (kt & 1) * 32768;
    if (kt + 1 < 8){
      const int pb = ((kt + 1) & 1) * 32768;
      #pragma unroll
      for (int q = 0; q < 4; ++q){
        gload16(A  + (size_t)(Mb + pr[q])*OBSD + (kt+1)*64 + pc16[q]*8,
                smem + pb + (w*4 + q)*1024);
        gload16(Bt + (size_t)(Nb + pr[q])*OBSD + (kt+1)*64 + pc16[q]*8,
                smem + pb + 16384 + (w*4 + q)*1024);
      }
    }
    #pragma unroll
    for (int kk = 0; kk < 64; kk += 32){
      f16x8 av[4], bv[4];
      #pragma unroll
      for (int m = 0; m < 4; ++m){
        int r = wm*64 + m*16 + la;
        av[m] = *reinterpret_cast<const f16x8*>(
            smem + cb + r*128 + (((kk + lk)*2) ^ ((r & 7) << 4)));
      }
      #pragma unroll
      for (int n = 0; n < 4; ++n){
        int r = wn*64 + n*16 + la;
        bv[n] = *reinterpret_cast<const f16x8*>(
            smem + cb + 16384 + r*128 + (((kk + lk)*2) ^ ((r & 7) << 4)));
      }
      #pragma unroll
      for (int m = 0; m < 4; ++m)
        #pragma unroll
        for (int n = 0; n < 4; ++n)
          acc[m][n] = mfma16(av[m], bv[n], acc[m][n]);
    }
    __syncthreads();                          // drains vmcnt: next buf ready; cur reads done
  }
  for (int mi = 0; mi < 4; ++mi) for (int ni = 0; ni < 4; ++ni){
    int col = Nb + wn*64 + ni*16 + la;
    float bb = bias[col];
    for (int i = 0; i < 4; ++i){
      int row = Mb + wm*64 + mi*16 + (lane >> 4)*4 + i;
      float v = acc[mi][ni][i] + bb;
      outb[(size_t)row * HID + col] = (f16)(v > 0.f ? v : 0.f);
    }
  }
}

// ---- xi = emb @ Wi + bi: m97 + 2-phase dbuf (128x128, BK=64, 16 kt) ----
__global__ __launch_bounds__(256)
void k_xi(const f16* __restrict__ A, const f16* __restrict__ Bt,
          const float* __restrict__ bias, f16* __restrict__ outb){
  __shared__ __attribute__((aligned(16))) char smem[65536];   // 2 x (As 16K | Bs 16K)
  int tid = threadIdx.x;
  int w = tid >> 6, lane = tid & 63;
  int wm = w >> 1, wn = w & 1;
  int bid = blockIdx.x;                       // 3072 = 128 Mb x 24 Nb
  int vid = (bid & 7) * 384 + (bid >> 3);
  int Mb = (vid / 24) * 128, Nb = (vid % 24) * 128;
  int la = lane & 15, lk = (lane >> 4) * 8;
  f32x4 acc[4][4] = {};
  int pr[4], pc16[4];
  #pragma unroll
  for (int q = 0; q < 4; ++q){
    int P = (w*4 + q)*1024 + lane*16;
    int r = P >> 7;
    pr[q] = r;
    pc16[q] = ((P & 127) ^ ((r & 7) << 4)) >> 4;
  }
  #pragma unroll
  for (int q = 0; q < 4; ++q){                // prologue: stage kt=0 -> buf0
    gload16(A  + (size_t)(Mb + pr[q])*HID  + pc16[q]*8, smem + (w*4 + q)*1024);
    gload16(Bt + (size_t)(Nb + pr[q])*2048 + pc16[q]*8, smem + 16384 + (w*4 + q)*1024);
  }
  __syncthreads();
  for (int kt = 0; kt < 16; ++kt){
    const int cb = (kt & 1) * 32768;
    if (kt + 1 < 16){
      const int pb = ((kt + 1) & 1) * 32768;
      #pragma unroll
      for (int q = 0; q < 4; ++q){
        gload16(A  + (size_t)(Mb + pr[q])*HID  + (kt+1)*64 + pc16[q]*8,
                smem + pb + (w*4 + q)*1024);
        gload16(Bt + (size_t)(Nb + pr[q])*2048 + (kt+1)*64 + pc16[q]*8,
                smem + pb + 16384 + (w*4 + q)*1024);
      }
    }
    #pragma unroll
    for (int kk = 0; kk < 64; kk += 32){
      f16x8 av[4], bv[4];
      #pragma unroll
      for (int m = 0; m < 4; ++m){
        int r = wm*64 + m*16 + la;
        av[m] = *reinterpret_cast<const f16x8*>(
            smem + cb + r*128 + (((kk + lk)*2) ^ ((r & 7) << 4)));
      }
      #pragma unroll
      for (int n = 0; n < 4; ++n){
        int r = wn*64 + n*16 + la;
        bv[n] = *reinterpret_cast<const f16x8*>(
            smem + cb + 16384 + r*128 + (((kk + lk)*2) ^ ((r & 7) << 4)));
      }
      #pragma unroll
      for (int m = 0; m < 4; ++m)
        #pragma unroll
        for (int n = 0; n < 4; ++n)
          acc[m][n] = mfma16(av[m], bv[n], acc[m][n]);
    }
    __syncthreads();
  }
  for (int mi = 0; mi < 4; ++mi) for (int ni = 0; ni < 4; ++ni){
    int col = Nb + wn*64 + ni*16 + la;
    float bb = bias[col];
    for (int i = 0; i < 4; ++i){
      int row = Mb + wm*64 + mi*16 + (lane >> 4)*4 + i;
      outb[(size_t)row * 3072 + col] = (f16)(acc[mi][ni][i] + bb);
    }
  }
}

// ---- h-zero rows: h = (1-z)*n, straight from xi (no GEMM) ----
__global__ __launch_bounds__(256)
void k_h0(const int* __restrict__ cnt, const int* __restrict__ zlist,
          const f16* __restrict__ xi, const float* __restrict__ bhn_p,
          f16* __restrict__ y, float* __restrict__ hout){
  int nz = cnt[24];
  int tid = threadIdx.x;
  for (int ridx = blockIdx.x; ridx < nz; ridx += gridDim.x){
    int tb = zlist[ridx];
    int t = tb >> 7, b = tb & 127;
    size_t rb = ((size_t)t*BB + b) * 3072;
    int c0 = tid * 4;
    f16x4 xr = *reinterpret_cast<const f16x4*>(xi + rb + c0);
    f16x4 xz = *reinterpret_cast<const f16x4*>(xi + rb + 1024 + c0);
    f16x4 xn = *reinterpret_cast<const f16x4*>(xi + rb + 2048 + c0);
    f16x4 o;
    #pragma unroll
    for (int u = 0; u < 4; ++u){
      float r = 1.f / (1.f + expf(-(float)xr[u]));
      float z = 1.f / (1.f + expf(-(float)xz[u]));
      float n = tanhf((float)xn[u] + r * bhn_p[c0 + u]);
      float h = (1.f - z) * n;
      o[u] = (f16)h;
      if (t == TT - 1) hout[(size_t)b*HID + c0 + u] = h;
    }
    *reinterpret_cast<f16x4*>(y + ((size_t)t*BB + b)*HID + c0) = o;
  }
}

// ---- depth-j GRU step: h_prev @ Wh, K=1024; gates from xi in epilogue ----
__global__ __launch_bounds__(512)
void k_depth(int j, const int* __restrict__ cnt, const int* __restrict__ rowlist_g,
             const f16* __restrict__ xi, const f16* __restrict__ bt2,
             const float* __restrict__ bhn_p, const float* __restrict__ hidden0,
             f16* __restrict__ y, float* __restrict__ hout){
  __shared__ __attribute__((aligned(16))) char smem[32768];
  const int count = cnt[j];
  if (count <= 0) return;
  const int* rowlist = rowlist_g + (size_t)j * BUCKCAP;
  const int tid = threadIdx.x;
  const int lane = tid & 63;
  const int w = tid >> 6;                    // 8 waves
  const int bid = blockIdx.x;
  const int la = lane & 15, lk = (lane >> 4) * 8;

  if (count <= 1024){
    // ---------- small path ----------
    float* red = (float*)smem;               // [2][4][3][64][5] = 30720 B
    const int vid = (bid & 7) * 128 + (bid >> 3);
    const int cs2 = vid >> 5;
    const int rgs = vid & 31;
    const int cg = w >> 2, kq = w & 3;
    const f16* Bq0 = bt2 + (size_t)(          cs2*32 + cg*16 + la)*2048 + 1024 + kq*256 + lk;
    const f16* Bq1 = bt2 + (size_t)(1024 +    cs2*32 + cg*16 + la)*2048 + 1024 + kq*256 + lk;
    const f16* Bq2 = bt2 + (size_t)(2048 +    cs2*32 + cg*16 + la)*2048 + 1024 + kq*256 + lk;
    const int es = tid >> 8, ei = (tid >> 6) & 3, elane = tid & 63;
    const int erow_l = ((elane >> 4) << 2) + ei;
    const int ecol = cs2*32 + es*16 + (elane & 15);
    const float bh = bhn_p[ecol];
    const int nrg = (count + 15) >> 4;
    for (int rg = rgs; rg < nrg; rg += 32){
      __syncthreads();
      #pragma unroll
      for (int it = 0; it < 4; ++it){
        int idx = tid + it*512;
        int r = idx >> 7, part = idx & 127;
        int ridx = rg*16 + r;
        int tb = (ridx < count) ? rowlist[ridx] : -1;
        float4 v = {0.f, 0.f, 0.f, 0.f};
        if (tb >= 0){
          int t = tb >> 7, bb_ = tb & 127;
          if (j > 0){
            v = *reinterpret_cast<const float4*>(y + ((size_t)(t-1)*BB + bb_)*HID + part*8);
          } else {
            const float* s = hidden0 + (size_t)bb_*HID + part*8;
            float4 a0 = *reinterpret_cast<const float4*>(s);
            float4 a1 = *reinterpret_cast<const float4*>(s + 4);
            f16 h8[8] = {(f16)a0.x,(f16)a0.y,(f16)a0.z,(f16)a0.w,
                         (f16)a1.x,(f16)a1.y,(f16)a1.z,(f16)a1.w};
            v = *reinterpret_cast<float4*>(h8);
          }
        }
        *reinterpret_cast<float4*>(smem + ((r*2048 + part*16) ^ ((r & 7) << 4))) = v;
      }
      __syncthreads();
      f32x4 a0 = {}, a1 = {}, a2 = {};
      #pragma unroll
      for (int kk = 0; kk < 256; kk += 32){
        int k = kq*256 + kk + lk;
        f16x8 av = *reinterpret_cast<const f16x8*>(
            smem + ((la*2048 + k*2) ^ ((la & 7) << 4)));
        a0 = mfma16(av, *reinterpret_cast<const f16x8*>(Bq0 + kk), a0);
        a1 = mfma16(av, *reinterpret_cast<const f16x8*>(Bq1 + kk), a1);
        a2 = mfma16(av, *reinterpret_cast<const f16x8*>(Bq2 + kk), a2);
      }
      __syncthreads();
      #pragma unroll
      for (int i = 0; i < 4; ++i){
        red[((((cg*4 + kq)*3 + 0)*64 + lane)*5) + i] = a0[i];
        red[((((cg*4 + kq)*3 + 1)*64 + lane)*5) + i] = a1[i];
        red[((((cg*4 + kq)*3 + 2)*64 + lane)*5) + i] = a2[i];
      }
      __syncthreads();
      int ridx = rg*16 + erow_l;
      if (ridx < count){
        int tb = rowlist[ridx];
        int t = tb >> 7, bb_ = tb & 127;
        float hr = 0.f, hz = 0.f, hn = 0.f;
        #pragma unroll
        for (int kq2 = 0; kq2 < 4; ++kq2){
          hr += red[((((es*4 + kq2)*3 + 0)*64 + elane)*5) + ei];
          hz += red[((((es*4 + kq2)*3 + 1)*64 + elane)*5) + ei];
          hn += red[((((es*4 + kq2)*3 + 2)*64 + elane)*5) + ei];
        }
        size_t rb = ((size_t)t*BB + bb_)*3072 + ecol;
        float hold;
        if (j > 0) hold = (float)y[((size_t)(t-1)*BB + bb_)*HID + ecol];
        else       hold = hidden0[(size_t)bb_*HID + ecol];
        float r = 1.f / (1.f + expf(-((float)xi[rb]        + hr)));
        float z = 1.f / (1.f + expf(-((float)xi[rb + 1024] + hz)));
        float n = tanhf((float)xi[rb + 2048] + r * (hn + bh));
        float hnew = (1.f - z) * n + z * hold;
        y[((size_t)t*BB + bb_)*HID + ecol] = (f16)hnew;
        if (t == TT - 1) hout[(size_t)bb_*HID + ecol] = hnew;
      }
    }
    return;
  }

  // ---------- big path ----------
  const int wm = w >> 2, wn = w & 3;
  const int nb = bid & 15;
  const int st = bid >> 4;
  const int hcolw = nb*64 + wn*16;
  const f16* Bg0 = bt2 + (size_t)(          hcolw + la) * 2048 + 1024 + lk;
  const f16* Bg1 = bt2 + (size_t)(1024 +    hcolw + la) * 2048 + 1024 + lk;
  const f16* Bg2 = bt2 + (size_t)(2048 +    hcolw + la) * 2048 + 1024 + lk;
  const int ntiles = (count + 127) >> 7;

  for (int tile = st; tile < ntiles; tile += 64){
    const char* hptr[4]; int hmode[4]; int sq[4]; int dby[4];
    #pragma unroll
    for (int q = 0; q < 4; ++q){
      int idx = tid + q*512;
      int r = idx >> 4; sq[q] = idx & 15;
      dby[q] = (r*256 + sq[q]*16) ^ ((r & 7) << 4);
      int ridx = tile*128 + r;
      int tb = (ridx < count) ? rowlist[ridx] : -1;
      hmode[q] = 0; hptr[q] = nullptr;
      if (tb >= 0){
        int t = tb >> 7, b = tb & 127;
        if (j > 0){ hmode[q] = 1; hptr[q] = (const char*)(y + ((size_t)(t-1)*BB + b)*HID); }
        else      { hmode[q] = 2; hptr[q] = (const char*)(hidden0 + (size_t)b*HID); }
      }
    }
    auto loadch = [&](int ch, float4* dst){
      #pragma unroll
      for (int q = 0; q < 4; ++q){
        float4 v = {0.f, 0.f, 0.f, 0.f};
        if (hmode[q] == 1){
          v = *reinterpret_cast<const float4*>((const f16*)hptr[q] + ch*128 + sq[q]*8);
        } else if (hmode[q] == 2){
          const float* s = (const float*)hptr[q] + ch*128 + sq[q]*8;
          float4 a0 = *reinterpret_cast<const float4*>(s);
          float4 a1 = *reinterpret_cast<const float4*>(s + 4);
          f16 h8[8] = {(f16)a0.x,(f16)a0.y,(f16)a0.z,(f16)a0.w,
                       (f16)a1.x,(f16)a1.y,(f16)a1.z,(f16)a1.w};
          v = *reinterpret_cast<float4*>(h8);
        }
        dst[q] = v;
      }
    };
    f32x4 ar[4] = {}, az[4] = {}, ahn[4] = {};
    float4 hv[4];
    loadch(0, hv);
    #pragma unroll 1
    for (int ch = 0; ch < 8; ++ch){
      __syncthreads();
      #pragma unroll
      for (int q = 0; q < 4; ++q)
        *reinterpret_cast<float4*>(smem + dby[q]) = hv[q];
      float4 hv2[4];
      if (ch < 7) loadch(ch+1, hv2);
      __syncthreads();
      const int kbase = ch*128;
      #pragma unroll
      for (int kk = 0; kk < 128; kk += 32){
        f16x8 av[4];
        #pragma unroll
        for (int m = 0; m < 4; ++m){
          int r = wm*64 + m*16 + la;
          av[m] = *reinterpret_cast<const f16x8*>(
              smem + ((r*256 + (kk + lk)*2) ^ ((r & 7) << 4)));
        }
        f16x8 b0 = *reinterpret_cast<const f16x8*>(Bg0 + kbase + kk);
        f16x8 b1 = *reinterpret_cast<const f16x8*>(Bg1 + kbase + kk);
        f16x8 b2 = *reinterpret_cast<const f16x8*>(Bg2 + kbase + kk);
        #pragma unroll
        for (int m = 0; m < 4; ++m){
          ar[m]  = mfma16(av[m], b0, ar[m]);
          az[m]  = mfma16(av[m], b1, az[m]);
          ahn[m] = mfma16(av[m], b2, ahn[m]);
        }
      }
      #pragma unroll
      for (int q = 0; q < 4; ++q) hv[q] = hv2[q];
    }
    {
      int hcol = hcolw + la;
      float bh = bhn_p[hcol];
      #pragma unroll
      for (int m = 0; m < 4; ++m){
        #pragma unroll
        for (int i = 0; i < 4; ++i){
          int lr = wm*64 + m*16 + (lane >> 4)*4 + i;
          int ridx = tile*128 + lr;
          if (ridx >= count) continue;
          int tb = rowlist[ridx];
          int t = tb >> 7, b = tb & 127;
          size_t rb = ((size_t)t*BB + b)*3072 + hcol;
          float hold;
          if (j > 0) hold = (float)y[((size_t)(t-1)*BB + b)*HID + hcol];
          else       hold = hidden0[(size_t)b*HID + hcol];
          float r = 1.f / (1.f + expf(-((float)xi[rb]        + ar[m][i])));
          float z = 1.f / (1.f + expf(-((float)xi[rb + 1024] + az[m][i])));
          float n = tanhf((float)xi[rb + 2048] + r * (ahn[m][i] + bh));
          float hnew = (1.f - z) * n + z * hold;
          y[((size_t)t*BB + b)*HID + hcol] = (f16)hnew;
          if (t == TT - 1) hout[(size_t)b*HID + hcol] = hnew;
        }
      }
    }
  }
}

// ---- sequential tail for chains longer than DPAR (empty for this seed) ----
__global__ __launch_bounds__(256)
void k_tail(const int* __restrict__ cnt, const int* __restrict__ chains,
            const f16* __restrict__ xi, const f16* __restrict__ bt2,
            const float* __restrict__ bhn_p, f16* __restrict__ y,
            float* __restrict__ hout){
  int n = cnt[25];
  __shared__ f16 hs[1024];
  int tid = threadIdx.x;
  for (int c = blockIdx.x; c < n; c += gridDim.x){
    int b = chains[c*3], t0 = chains[c*3+1], len = chains[c*3+2];
    for (int i = tid; i < 1024; i += 256)
      hs[i] = y[((size_t)(t0 + DPAR - 1)*BB + b)*HID + i];
    __syncthreads();
    for (int t = t0 + DPAR; t < t0 + len; ++t){
      float tmp[4];
      #pragma unroll
      for (int u = 0; u < 4; ++u){
        int col = tid*4 + u;
        float s_r = 0.f, s_z = 0.f, s_hn = 0.f;
        const f16* wr = bt2 + (size_t)col*2048 + 1024;
        const f16* wz = bt2 + (size_t)(1024+col)*2048 + 1024;
        const f16* wn = bt2 + (size_t)(2048+col)*2048 + 1024;
        for (int q = 0; q < 128; ++q){
          f16x8 hv = *reinterpret_cast<const f16x8*>(&hs[q*8]);
          f16x8 wrh = *reinterpret_cast<const f16x8*>(wr + q*8);
          f16x8 wzh = *reinterpret_cast<const f16x8*>(wz + q*8);
          f16x8 wnh = *reinterpret_cast<const f16x8*>(wn + q*8);
          #pragma unroll
          for (int e = 0; e < 8; ++e){
            float hh = (float)hv[e];
            s_r  += hh*(float)wrh[e];
            s_z  += hh*(float)wzh[e];
            s_hn += hh*(float)wnh[e];
          }
        }
        size_t rb = ((size_t)t*BB + b)*3072 + col;
        float r = 1.f / (1.f + expf(-((float)xi[rb] + s_r)));
        float z = 1.f / (1.f + expf(-((float)xi[rb + 1024] + s_z)));
        float nn = tanhf((float)xi[rb + 2048] + r * (s_hn + bhn_p[col]));
        float hold = (float)hs[col];
        float hnew = (1.f - z) * nn + z * hold;
        y[((size_t)t*BB + b)*HID + col] = (f16)hnew;
        if (t == TT - 1) hout[(size_t)b*HID + col] = hnew;
        tmp[u] = hnew;
      }
      __syncthreads();
      #pragma unroll
      for (int u = 0; u < 4; ++u) hs[tid*4 + u] = (f16)tmp[u];
      __syncthreads();
    }
    __syncthreads();
  }
}

// ---- critic: m97 + 2-phase dbuf (128x128, BK=64, 16 kt) + value fusion ----
__global__ __launch_bounds__(256)
void k_critic(const f16* __restrict__ Y, const f16* __restrict__ Bt,
              const float* __restrict__ b1, const float* __restrict__ W2,
              float* __restrict__ vpart){
  __shared__ __attribute__((aligned(16))) char smem[65536];   // 2 x (As 16K | Bs 16K)
  int tid = threadIdx.x;
  int w = tid >> 6, lane = tid & 63;
  int wm = w >> 1, wn = w & 1;
  int bid = blockIdx.x;
  int vid = (bid & 7) * 128 + (bid >> 3);
  int Mb = (vid >> 3) * 128, Nb = (vid & 7) * 128;
  int la = lane & 15, lk = (lane >> 4) * 8;
  f32x4 acc[4][4] = {};
  int pr[4], pc16[4];
  #pragma unroll
  for (int q = 0; q < 4; ++q){
    int P = (w*4 + q)*1024 + lane*16;
    int r = P >> 7;
    pr[q] = r;
    pc16[q] = ((P & 127) ^ ((r & 7) << 4)) >> 4;
  }
  #pragma unroll
  for (int q = 0; q < 4; ++q){                // prologue: stage kt=0 -> buf0
    gload16(Y  + (size_t)(Mb + pr[q])*HID + pc16[q]*8, smem + (w*4 + q)*1024);
    gload16(Bt + (size_t)(Nb + pr[q])*HID + pc16[q]*8, smem + 16384 + (w*4 + q)*1024);
  }
  __syncthreads();
  for (int kt = 0; kt < 16; ++kt){
    const int cb = (kt & 1) * 32768;
    if (kt + 1 < 16){
      const int pb = ((kt + 1) & 1) * 32768;
      #pragma unroll
      for (int q = 0; q < 4; ++q){
        gload16(Y  + (size_t)(Mb + pr[q])*HID + (kt+1)*64 + pc16[q]*8,
                smem + pb + (w*4 + q)*1024);
        gload16(Bt + (size_t)(Nb + pr[q])*HID + (kt+1)*64 + pc16[q]*8,
                smem + pb + 16384 + (w*4 + q)*1024);
      }
    }
    #pragma unroll
    for (int kk = 0; kk < 64; kk += 32){
      f16x8 av[4], bv[4];
      #pragma unroll
      for (int m = 0; m < 4; ++m){
        int r = wm*64 + m*16 + la;
        av[m] = *reinterpret_cast<const f16x8*>(
            smem + cb + r*128 + (((kk + lk)*2) ^ ((r & 7) << 4)));
      }
      #pragma unroll
      for (int n = 0; n < 4; ++n){
        int r = wn*64 + n*16 + la;
        bv[n] = *reinterpret_cast<const f16x8*>(
            smem + cb + 16384 + r*128 + (((kk + lk)*2) ^ ((r & 7) << 4)));
      }
      #pragma unroll
      for (int m = 0; m < 4; ++m)
        #pragma unroll
        for (int n = 0; n < 4; ++n)
          acc[m][n] = mfma16(av[m], bv[n], acc[m][n]);
    }
    __syncthreads();
  }
  __shared__ float vs[2][64][2];
  float p[4][4];
  for (int mi = 0; mi < 4; ++mi) for (int i = 0; i < 4; ++i) p[mi][i] = 0.f;
  for (int ni = 0; ni < 4; ++ni){
    int col = Nb + wn*64 + ni*16 + la;
    float bb = b1[col], w2 = W2[col];
    for (int mi = 0; mi < 4; ++mi)
      for (int i = 0; i < 4; ++i){
        float c = acc[mi][ni][i] + bb;
        p[mi][i] += (c > 0.f ? c : 0.f) * w2;
      }
  }
  for (int mi = 0; mi < 4; ++mi) for (int i = 0; i < 4; ++i){
    float s = p[mi][i];
    s += __shfl_xor(s, 1); s += __shfl_xor(s, 2);
    s += __shfl_xor(s, 4); s += __shfl_xor(s, 8);
    p[mi][i] = s;
  }
  if (la == 0){
    int q = lane >> 4;
    for (int mi = 0; mi < 4; ++mi)
      for (int i = 0; i < 4; ++i)
        vs[wm][mi*16 + q*4 + i][wn] = p[mi][i];
  }
  __syncthreads();
  if (threadIdx.x < 128){
    int rw = threadIdx.x;
    float s = vs[rw >> 6][rw & 63][0] + vs[rw >> 6][rw & 63][1];
    vpart[(size_t)(Nb >> 7) * (TT*BB) + Mb + rw] = s;
  }
}

__global__ void k_vreduce(const float* __restrict__ vpart, const float* __restrict__ b2,
                          float* __restrict__ outv){
  int m = blockIdx.x * 256 + threadIdx.x;
  float s = b2[0];
  for (int nb = 0; nb < 8; ++nb) s += vpart[(size_t)nb * (TT*BB) + m];
  outv[m] = s;
}

extern "C" void kernel_launch(void* const* d_in, const int* in_sizes, int n_in,
                              void* d_out, int out_size, void* d_ws, size_t ws_size,
                              hipStream_t stream){
  const float* hidden = (const float*)d_in[0];
  const float* world  = (const float*)d_in[1];
  const int*   dones  = (const int*)d_in[2];
  const float* W_emb  = (const float*)d_in[3];
  const float* b_emb  = (const float*)d_in[4];
  const float* Wi     = (const float*)d_in[5];
  const float* bi     = (const float*)d_in[6];
  const float* Wh     = (const float*)d_in[7];
  const float* bhn    = (const float*)d_in[8];
  const float* W1     = (const float*)d_in[9];
  const float* b1     = (const float*)d_in[10];
  const float* W2     = (const float*)d_in[11];
  const float* b2     = (const float*)d_in[12];
  float* out = (float*)d_out;

  char* p = (char*)d_ws;
  auto alloc = [&](size_t bytes) -> char* {
    char* r = p; p += (bytes + 255) & ~(size_t)255; return r;
  };
  f16*   ws16   = (f16*)alloc((size_t)TT*BB*OBSD*2);     // 16 MB
  f16*   wembt  = (f16*)alloc((size_t)HID*OBSD*2);       // 1 MB
  f16*   emb16  = (f16*)alloc((size_t)TT*BB*HID*2);      // 33.5 MB
  f16*   bt2    = (f16*)alloc((size_t)3072*2048*2);      // 12.6 MB
  f16*   w1t    = (f16*)alloc((size_t)HID*HID*2);        // 2 MB
  f16*   xi16   = (f16*)alloc((size_t)TT*BB*3072*2);     // 100.7 MB
  f16*   ybuf   = (f16*)alloc((size_t)TT*BB*HID*2);      // 33.5 MB
  float* vpart  = (float*)alloc((size_t)8*TT*BB*4);      // 0.5 MB
  int*   cnt    = (int*)alloc(26*4);
  int*   rowlist= (int*)alloc((size_t)DPAR*BUCKCAP*4);   // 1.57 MB
  int*   zlist  = (int*)alloc((size_t)BUCKCAP*4);
  int*   chains = (int*)alloc((size_t)1024*3*4);
  if ((size_t)(p - (char*)d_ws) > ws_size) return;

  hipMemsetAsync(cnt, 0, 26*4, stream);

  // preps (+ segmentation, depends only on dones)
  k_ws_to_f16<<<(TT*BB*OBSD/4 + 255)/256, 256, 0, stream>>>(world, ws16, TT*BB*OBSD/4);
  k_prep_bt<<<dim3(OBSD/64, HID/64), 256, 0, stream>>>(W_emb, 1024, wembt, OBSD);
  k_prep_bt2<<<dim3(2048/64, 3072/64), 256, 0, stream>>>(Wi, Wh, bt2);
  k_prep_bt<<<dim3(HID/64, HID/64), 256, 0, stream>>>(W1, 1024, w1t, HID);
  k_seg<<<128, 128, 0, stream>>>(dones, cnt, rowlist, zlist, chains);

  // parallel GEMMs
  k_emb<<<1024, 256, 0, stream>>>(ws16, wembt, b_emb, emb16);
  k_xi<<<3072, 256, 0, stream>>>(emb16, bt2, bi, xi16);

  // h-zero rows (no GEMM) + depth-parallel GRU scan + tail
  k_h0<<<2048, 256, 0, stream>>>(cnt, zlist, xi16, bhn, ybuf, out);
  for (int j = 0; j < DPAR; ++j)
    k_depth<<<1024, 512, 0, stream>>>(j, cnt, rowlist, xi16, bt2, bhn,
                                      hidden, ybuf, out);
  k_tail<<<128, 256, 0, stream>>>(cnt, chains, xi16, bt2, bhn, ybuf, out);

  // critic head + value
  k_critic<<<1024, 256, 0, stream>>>(ybuf, w1t, b1, W2, vpart);
  k_vreduce<<<TT*BB/256, 256, 0, stream>>>(vpart, b2, out + (size_t)BB*HID);
}